// Round 11
// baseline (1804.626 us; speedup 1.0000x reference)
//
#include <hip/hip_runtime.h>
#include <math.h>

// SRNN: S=16 steps, N=32768 nodes, E=131072 spatial edges.
// f16 MFMA gate GEMMs, B-resident weights. Numerics (kept, 7/7 stable):
//  - edge LSTM per-thread arithmetic = TR=64 form (absmax attractor 3.9e-3)
//  - CSR sorted ascending; agg as hi/lo f16 pair (K=192)
// NEW: node(t) and edge(t+1) are independent -> fused into ONE dispatch
// (block-role split) so the latency-bound edge kernel overlaps node compute.

#define S_LEN 16
#define NN 32768
#define EE 131072

typedef _Float16 f16;
typedef _Float16 f16x8 __attribute__((ext_vector_type(8)));
typedef float f32x4 __attribute__((ext_vector_type(4)));

__device__ __forceinline__ float fsigmoid(float x) {
    return __builtin_amdgcn_rcpf(1.0f + __builtin_amdgcn_exp2f(-1.44269504f * x));
}
__device__ __forceinline__ float ftanh(float x) {
    const float e = __builtin_amdgcn_exp2f(2.88539008f * x);
    return 1.0f - 2.0f * __builtin_amdgcn_rcpf(e + 1.0f);
}

__device__ __forceinline__ unsigned int pk2(float a, float b) {
    union { f16 h[2]; unsigned int u; } x;
    x.h[0] = (f16)a; x.h[1] = (f16)b;
    return x.u;
}

__device__ __forceinline__ f16x8 ld_frag16(const void* p) {
    union { uint4 v; f16x8 f; } x;
    x.v = *(const uint4*)p;
    return x.f;
}

// ---------------- edge LSTM body (H=64, TR=64, 256 threads) ----------------
// EXACTLY the r10 TR=64 per-thread arithmetic. tl in [0,256); Xls = 16 KB.
__device__ __forceinline__ void edge_lstm_body(
    const int tl, char* __restrict__ Xls, const int row0,
    const float* __restrict__ xf,
    const float* __restrict__ enc_w, const float* __restrict__ enc_b,
    const f16* __restrict__ Wt, const float* __restrict__ bias,
    f16* __restrict__ h, float* __restrict__ c)
{
    constexpr int H = 64, K = 128, KSTEPS = 4, ROWB = 256, TR = 64;
    constexpr int RTN = TR / 16;   // 4

    const int wv = tl >> 6, l = tl & 63;
    const int lane15 = l & 15, kgrp = l >> 4;
    const int col = wv * 16 + lane15;

    // B fragments: resident in VGPRs
    f16x8 bfrag[4][KSTEPS];
    #pragma unroll
    for (int q = 0; q < 4; ++q) {
        const int colq = q * H + col;
        const f16* bp = Wt + (size_t)colq * K + kgrp * 8;
        #pragma unroll
        for (int ks = 0; ks < KSTEPS; ++ks)
            bfrag[q][ks] = ld_frag16(bp + ks * 32);
    }

    // stage x-enc (cols 0..63)
    for (int i = tl; i < TR * (H / 2); i += 256) {
        const int r = i / (H / 2), j2 = (i % (H / 2)) * 2;
        const int grow = row0 + r;
        const float x0 = xf[grow * 2 + 0];
        const float x1 = xf[grow * 2 + 1];
        const float e0 = fmaxf(0.f, fmaf(x0, enc_w[j2],     fmaf(x1, enc_w[H + j2],     enc_b[j2])));
        const float e1 = fmaxf(0.f, fmaf(x0, enc_w[j2 + 1], fmaf(x1, enc_w[H + j2 + 1], enc_b[j2 + 1])));
        const int byte = r * ROWB + ((j2 * 2) ^ ((r & 7) << 4));
        *(unsigned int*)(Xls + byte) = pk2(e0, e1);
    }
    // stage h (cols 64..127)
    for (int i = tl; i < TR * (H / 4); i += 256) {
        const int r = i / (H / 4), j4 = (i % (H / 4)) * 4;
        const uint2 v = *(const uint2*)&h[(size_t)(row0 + r) * H + j4];
        const int byte = r * ROWB + ((H * 2 + j4 * 2) ^ ((r & 7) << 4));
        *(uint2*)(Xls + byte) = v;
    }
    __syncthreads();

    const float bi = bias[0 * H + col];
    const float bf = bias[1 * H + col];
    const float bg = bias[2 * H + col];
    const float bo = bias[3 * H + col];

    #pragma unroll
    for (int rt = 0; rt < RTN; ++rt) {
        const int arow = rt * 16 + lane15;
        const char* abase = Xls + arow * ROWB;
        f16x8 afrag[KSTEPS];
        #pragma unroll
        for (int ks = 0; ks < KSTEPS; ++ks) {
            const int byte = (ks * 64 + kgrp * 16) ^ ((arow & 7) << 4);
            afrag[ks] = ld_frag16(abase + byte);
        }
        f32x4 acc[4];
        #pragma unroll
        for (int q = 0; q < 4; ++q)
            #pragma unroll
            for (int r = 0; r < 4; ++r) acc[q][r] = 0.f;
        #pragma unroll
        for (int ks = 0; ks < KSTEPS; ++ks)
            #pragma unroll
            for (int q = 0; q < 4; ++q)
                acc[q] = __builtin_amdgcn_mfma_f32_16x16x32_f16(
                    afrag[ks], bfrag[q][ks], acc[q], 0, 0, 0);
        #pragma unroll
        for (int reg = 0; reg < 4; ++reg) {
            const int rl = rt * 16 + kgrp * 4 + reg;
            const int grow = row0 + rl;
            const size_t off = (size_t)grow * H + col;
            const float ig = fsigmoid(acc[0][reg] + bi);
            const float fg = fsigmoid(acc[1][reg] + bf);
            const float gg = ftanh(acc[2][reg] + bg);
            const float og = fsigmoid(acc[3][reg] + bo);
            const float c2 = fmaf(fg, c[off], ig * gg);
            c[off] = c2;
            h[off] = (f16)(og * ftanh(c2));
        }
    }
}

// ---------------- standalone edge dispatch (step 0), TR=64, 256 thr --------
__global__ __launch_bounds__(256) void edge_lstm_fused(
    const float* __restrict__ xT, const float* __restrict__ xS,
    const float* __restrict__ t_enc_w, const float* __restrict__ t_enc_b,
    const float* __restrict__ s_enc_w, const float* __restrict__ s_enc_b,
    const f16* __restrict__ WtT, const f16* __restrict__ WtS,
    const float* __restrict__ biasT, const float* __restrict__ biasS,
    f16* __restrict__ hT, float* __restrict__ cT,
    f16* __restrict__ hS, float* __restrict__ cS)
{
    __shared__ __align__(16) char Xls[64 * 256];   // 16 KB
    const int bT = NN / 64;   // 512
    const bool isT = (int)blockIdx.x < bT;
    const int row0 = (isT ? blockIdx.x : blockIdx.x - bT) * 64;
    edge_lstm_body(threadIdx.x, Xls, row0,
                   isT ? xT : xS,
                   isT ? t_enc_w : s_enc_w, isT ? t_enc_b : s_enc_b,
                   isT ? WtT : WtS, isT ? biasT : biasS,
                   isT ? hT : hS, isT ? cT : cS);
}

// ---------------- fused node(t) + edge(t+1), 512 thr ----------------
// blocks [0,nNode): node LSTM TR=128 + fused out projection (68 KB LDS).
// blocks [nNode,..): edge step t+1, 128 rows as TWO independent TR=64 halves
// (waves 0-3 / 4-7, separate 16 KB LDS panels) - per-thread math identical
// to the TR=64 standalone kernel.
__global__ __launch_bounds__(512) void node_edge_fused(
    // node args (step t)
    const f16* __restrict__ xin, const f16* __restrict__ Wt,
    const float* __restrict__ bias,
    const float* __restrict__ out_w, const float* __restrict__ out_b,
    f16* __restrict__ hn, float* __restrict__ cn, float* __restrict__ outp,
    // edge args (step t+1)
    const float* __restrict__ xT, const float* __restrict__ xS,
    const float* __restrict__ t_enc_w, const float* __restrict__ t_enc_b,
    const float* __restrict__ s_enc_w, const float* __restrict__ s_enc_b,
    const f16* __restrict__ WtT, const f16* __restrict__ WtS,
    const float* __restrict__ biasT, const float* __restrict__ biasS,
    f16* __restrict__ hT, float* __restrict__ cT,
    f16* __restrict__ hS, float* __restrict__ cS,
    const int nNode)
{
    __shared__ __align__(16) char pool[128 * 512 + 128 * 8 * 4];   // 68 KB

    if ((int)blockIdx.x < nNode) {
        // ---- node LSTM (H=128), TR=128, 8 waves + fused output projection --
        constexpr int H = 128, K = 256, KSTEPS = 8, ROWB = 512, TR = 128;
        constexpr int RTN = TR / 16;
        char* Xls = pool;                                  // 64 KB
        float (*out_part)[8] = (float(*)[8])(pool + TR * ROWB);   // 4 KB

        const int row0 = blockIdx.x * TR;
        const int t = threadIdx.x;
        const int wv = t >> 6, l = t & 63;
        const int lane15 = l & 15, kgrp = l >> 4;
        const int col = wv * 16 + lane15;

        f16x8 bfrag[4][KSTEPS];
        #pragma unroll
        for (int q = 0; q < 4; ++q) {
            const int colq = q * H + col;
            const f16* bp = Wt + (size_t)colq * K + kgrp * 8;
            #pragma unroll
            for (int ks = 0; ks < KSTEPS; ++ks)
                bfrag[q][ks] = ld_frag16(bp + ks * 32);
        }

        for (int i = t; i < TR * (H / 4); i += 512) {
            const int r = i / (H / 4), j4 = (i % (H / 4)) * 4;
            const uint2 v = *(const uint2*)&xin[(size_t)(row0 + r) * H + j4];
            const int byte = r * ROWB + ((j4 * 2) ^ ((r & 7) << 4));
            *(uint2*)(Xls + byte) = v;
        }
        for (int i = t; i < TR * (H / 4); i += 512) {
            const int r = i / (H / 4), j4 = (i % (H / 4)) * 4;
            const uint2 v = *(const uint2*)&hn[(size_t)(row0 + r) * H + j4];
            const int byte = r * ROWB + ((H * 2 + j4 * 2) ^ ((r & 7) << 4));
            *(uint2*)(Xls + byte) = v;
        }
        __syncthreads();

        const float bi = bias[0 * H + col];
        const float bf = bias[1 * H + col];
        const float bg = bias[2 * H + col];
        const float bo = bias[3 * H + col];
        const float wout = out_w[col];

        #pragma unroll
        for (int rt = 0; rt < RTN; ++rt) {
            const int arow = rt * 16 + lane15;
            const char* abase = Xls + arow * ROWB;
            f16x8 afrag[KSTEPS];
            #pragma unroll
            for (int ks = 0; ks < KSTEPS; ++ks) {
                const int byte = (ks * 64 + kgrp * 16) ^ ((arow & 7) << 4);
                afrag[ks] = ld_frag16(abase + byte);
            }
            f32x4 acc[4];
            #pragma unroll
            for (int q = 0; q < 4; ++q)
                #pragma unroll
                for (int r = 0; r < 4; ++r) acc[q][r] = 0.f;
            #pragma unroll
            for (int ks = 0; ks < KSTEPS; ++ks)
                #pragma unroll
                for (int q = 0; q < 4; ++q)
                    acc[q] = __builtin_amdgcn_mfma_f32_16x16x32_f16(
                        afrag[ks], bfrag[q][ks], acc[q], 0, 0, 0);
            #pragma unroll
            for (int reg = 0; reg < 4; ++reg) {
                const int rl = rt * 16 + kgrp * 4 + reg;
                const int grow = row0 + rl;
                const size_t off = (size_t)grow * H + col;
                const float ig = fsigmoid(acc[0][reg] + bi);
                const float fg = fsigmoid(acc[1][reg] + bf);
                const float gg = ftanh(acc[2][reg] + bg);
                const float og = fsigmoid(acc[3][reg] + bo);
                const float c2 = fmaf(fg, cn[off], ig * gg);
                const float h2 = og * ftanh(c2);
                cn[off] = c2;
                hn[off] = (f16)h2;
                float pv = h2 * wout;
                pv += __shfl_xor(pv, 1);
                pv += __shfl_xor(pv, 2);
                pv += __shfl_xor(pv, 4);
                pv += __shfl_xor(pv, 8);
                if (lane15 == 0) out_part[rl][wv] = pv;
            }
        }
        __syncthreads();
        if (t < TR) {
            float s = out_part[t][0];
            #pragma unroll
            for (int w = 1; w < 8; ++w) s += out_part[t][w];
            outp[row0 + t] = s + out_b[0];
        }
    } else {
        // ---- edge step t+1: two independent TR=64 halves ----
        const int ebid = blockIdx.x - nNode;
        const int half = threadIdx.x >> 8;        // 0 or 1
        const int tl   = threadIdx.x & 255;
        char* Xls = pool + half * (64 * 256);     // 16 KB per half
        const int gr0 = ebid * 128 + half * 64;   // global row over [0, NN+EE)
        const bool isT = gr0 < NN;
        const int row0 = isT ? gr0 : gr0 - NN;
        edge_lstm_body(tl, Xls, row0,
                       isT ? xT : xS,
                       isT ? t_enc_w : s_enc_w, isT ? t_enc_b : s_enc_b,
                       isT ? WtT : WtS, isT ? biasT : biasS,
                       isT ? hT : hS, isT ? cT : cS);
    }
}

// ---------------- gather + embed fused (K=192: ht | agg_hi | agg_lo) --------
__global__ __launch_bounds__(256) void gather_embed(
    const float* __restrict__ xn,
    const f16* __restrict__ ht, const f16* __restrict__ hs,
    const int* __restrict__ ptr, const int* __restrict__ rowidx,
    const float* __restrict__ n_enc_w, const float* __restrict__ n_enc_b,
    const f16* __restrict__ Wt_ee2,  // [64][192]
    const float* __restrict__ ee_b,
    f16* __restrict__ xnode)
{
    constexpr int TR = 64, K = 192, KSTEPS = 6, ROWB = 384;
    __shared__ __align__(16) char Xls[TR * ROWB];   // 24 KB
    const int row0 = blockIdx.x * TR;
    const int t = threadIdx.x;
    const int wv = t >> 6, l = t & 63;
    const int lane15 = l & 15, kgrp = l >> 4;

    const int col = wv * 16 + lane15;
    f16x8 bfrag[KSTEPS];
    {
        const f16* bp = Wt_ee2 + (size_t)col * K + kgrp * 8;
        #pragma unroll
        for (int ks = 0; ks < KSTEPS; ++ks) bfrag[ks] = ld_frag16(bp + ks * 32);
    }

    // stage ht -> K cols 0..63
    for (int i = t; i < TR * 16; i += 256) {
        const int r = i / 16, j4 = (i % 16) * 4;
        const uint2 v = *(const uint2*)&ht[(size_t)(row0 + r) * 64 + j4];
        const int byte = r * ROWB + ((j4 * 2) ^ ((r & 7) << 4));
        *(uint2*)(Xls + byte) = v;
    }

    // CSR gather -> K cols 64..127 (hi) and 128..191 (lo), sorted edge order.
    {
        const int r = t >> 2, q = t & 3;
        const int n = row0 + r;
        const int beg = ptr[n], end = ptr[n + 1];
        const unsigned int* hs32 = (const unsigned int*)hs;
        float acc[16];
        #pragma unroll
        for (int j = 0; j < 16; ++j) acc[j] = 0.f;
        for (int i = beg; i < end; ++i) {
            const int e = rowidx[i];
            const unsigned int* ep = hs32 + (size_t)e * 32 + q * 8;
            #pragma unroll
            for (int j = 0; j < 8; ++j) {
                union { unsigned int u; f16 h[2]; } v;
                v.u = ep[j];
                acc[2 * j]     += (float)v.h[0];
                acc[2 * j + 1] += (float)v.h[1];
            }
        }
        #pragma unroll
        for (int j = 0; j < 8; ++j) {
            const float a0 = acc[2 * j], a1 = acc[2 * j + 1];
            const f16 h0 = (f16)a0, h1 = (f16)a1;
            const f16 l0 = (f16)(a0 - (float)h0), l1 = (f16)(a1 - (float)h1);
            union { f16 h[2]; unsigned int u; } hi, lo;
            hi.h[0] = h0; hi.h[1] = h1;
            lo.h[0] = l0; lo.h[1] = l1;
            const int bhi = r * ROWB + ((128 + q * 32 + j * 4) ^ ((r & 7) << 4));
            const int blo = r * ROWB + ((256 + q * 32 + j * 4) ^ ((r & 7) << 4));
            *(unsigned int*)(Xls + bhi) = hi.u;
            *(unsigned int*)(Xls + blo) = lo.u;
        }
    }
    __syncthreads();

    const float bb = ee_b[col];
    #pragma unroll
    for (int rt = 0; rt < TR / 16; ++rt) {
        const int arow = rt * 16 + lane15;
        const char* abase = Xls + arow * ROWB;
        f16x8 afrag[KSTEPS];
        #pragma unroll
        for (int ks = 0; ks < KSTEPS; ++ks) {
            const int byte = (ks * 64 + kgrp * 16) ^ ((arow & 7) << 4);
            afrag[ks] = ld_frag16(abase + byte);
        }
        f32x4 acc;
        #pragma unroll
        for (int r = 0; r < 4; ++r) acc[r] = 0.f;
        #pragma unroll
        for (int ks = 0; ks < KSTEPS; ++ks)
            acc = __builtin_amdgcn_mfma_f32_16x16x32_f16(afrag[ks], bfrag[ks], acc, 0, 0, 0);
        #pragma unroll
        for (int reg = 0; reg < 4; ++reg) {
            const int grow = row0 + rt * 16 + kgrp * 4 + reg;
            xnode[(size_t)grow * 128 + 64 + col] = (f16)fmaxf(0.f, acc[reg] + bb);
        }
    }

    // encoder half: cols 0..63
    for (int i = t; i < TR * 32; i += 256) {
        const int r = i >> 5, j2 = (i & 31) * 2;
        const int grow = row0 + r;
        const float x = xn[grow];
        const float e0 = fmaxf(0.f, fmaf(x, n_enc_w[j2],     n_enc_b[j2]));
        const float e1 = fmaxf(0.f, fmaf(x, n_enc_w[j2 + 1], n_enc_b[j2 + 1]));
        *(unsigned int*)&xnode[(size_t)grow * 128 + j2] = pk2(e0, e1);
    }
}

// ---------------- CSR build (once; inc is step-invariant) ----------------
__global__ __launch_bounds__(256) void count_kernel(
    const int* __restrict__ inc, int* __restrict__ cnt)
{
    const int slot = blockIdx.x * 256 + threadIdx.x;
    atomicAdd(&cnt[inc[slot]], 1);
}

__global__ __launch_bounds__(1024) void scan_kernel(
    const int* __restrict__ cnt, int* __restrict__ ptr)
{
    __shared__ int sums[1024];
    const int t = threadIdx.x;
    const int base = t * 32;
    int local[32];
    int s = 0;
    #pragma unroll
    for (int i = 0; i < 32; ++i) { local[i] = s; s += cnt[base + i]; }
    sums[t] = s;
    __syncthreads();
    for (int off = 1; off < 1024; off <<= 1) {
        int v = 0;
        if (t >= off) v = sums[t - off];
        __syncthreads();
        sums[t] += v;
        __syncthreads();
    }
    const int excl = sums[t] - s;
    #pragma unroll
    for (int i = 0; i < 32; ++i) ptr[base + i] = excl + local[i];
    if (t == 1023) ptr[NN] = sums[1023];
}

__global__ __launch_bounds__(256) void fill_kernel(
    const int* __restrict__ inc, const int* __restrict__ ptr,
    int* __restrict__ cur, int* __restrict__ rowidx)
{
    const int slot = blockIdx.x * 256 + threadIdx.x;
    const int n = inc[slot];
    const int pos = atomicAdd(&cur[n], 1);
    rowidx[ptr[n] + pos] = slot >> 1;
}

// Sort each node's edge list ascending (deterministic; matches segment_sum).
__global__ __launch_bounds__(256) void sort_csr_kernel(
    const int* __restrict__ ptr, int* __restrict__ rowidx)
{
    const int n = blockIdx.x * 256 + threadIdx.x;
    if (n >= NN) return;
    const int beg = ptr[n], end = ptr[n + 1];
    for (int i = beg; i < end - 1; ++i) {
        int mi = i, mv = rowidx[i];
        for (int j = i + 1; j < end; ++j) {
            const int v = rowidx[j];
            if (v < mv) { mv = v; mi = j; }
        }
        if (mi != i) { rowidx[mi] = rowidx[i]; rowidx[i] = mv; }
    }
}

// ---------------- weight transpose+convert (once) ----------------
__global__ __launch_bounds__(256) void transpose_w_kernel(
    const float* __restrict__ Wih, const float* __restrict__ Whh,
    f16* __restrict__ dst, int Hk, int K, int fourH)
{
    const int tid = blockIdx.x * 256 + threadIdx.x;
    if (tid >= K * fourH) return;
    const int col = tid / K, k = tid % K;
    const float v = (k < Hk) ? Wih[(size_t)k * fourH + col]
                             : Whh[(size_t)(k - Hk) * fourH + col];
    dst[tid] = (f16)v;
}

// ee_w (128,64) -> Wt_ee2 [64][192]: k<128 -> row k; k>=128 -> row k-64.
__global__ __launch_bounds__(256) void transpose_ee2_kernel(
    const float* __restrict__ ee_w, f16* __restrict__ dst)
{
    const int tid = blockIdx.x * 256 + threadIdx.x;
    if (tid >= 64 * 192) return;
    const int col = tid / 192, k = tid % 192;
    const int srcrow = (k < 128) ? k : (k - 64);
    dst[tid] = (f16)ee_w[(size_t)srcrow * 64 + col];
}

__global__ __launch_bounds__(256) void cvt_kernel(
    const float* __restrict__ src, f16* __restrict__ dst, int n2)
{
    const int i = blockIdx.x * 256 + threadIdx.x;
    if (i >= n2) return;
    const float2 v = ((const float2*)src)[i];
    ((unsigned int*)dst)[i] = pk2(v.x, v.y);
}

extern "C" void kernel_launch(void* const* d_in, const int* in_sizes, int n_in,
                              void* d_out, int out_size, void* d_ws, size_t ws_size,
                              hipStream_t stream) {
    const float* data_nodes = (const float*)d_in[0];
    const float* data_tE    = (const float*)d_in[1];
    const float* data_sE    = (const float*)d_in[2];
    const float* h_n0 = (const float*)d_in[3];
    const float* c_n0 = (const float*)d_in[4];
    const float* h_t0 = (const float*)d_in[5];
    const float* c_t0 = (const float*)d_in[6];
    const float* h_s0 = (const float*)d_in[7];
    const float* c_s0 = (const float*)d_in[8];
    const int*   inc  = (const int*)d_in[9];
    const float* t_enc_w = (const float*)d_in[10];
    const float* t_enc_b = (const float*)d_in[11];
    const float* t_Wih   = (const float*)d_in[12];
    const float* t_Whh   = (const float*)d_in[13];
    const float* t_b     = (const float*)d_in[14];
    const float* s_enc_w = (const float*)d_in[15];
    const float* s_enc_b = (const float*)d_in[16];
    const float* s_Wih   = (const float*)d_in[17];
    const float* s_Whh   = (const float*)d_in[18];
    const float* s_b     = (const float*)d_in[19];
    const float* n_enc_w = (const float*)d_in[20];
    const float* n_enc_b = (const float*)d_in[21];
    const float* ee_w    = (const float*)d_in[22];
    const float* ee_b    = (const float*)d_in[23];
    const float* n_Wih   = (const float*)d_in[24];
    const float* n_Whh   = (const float*)d_in[25];
    const float* n_b     = (const float*)d_in[26];
    const float* out_w   = (const float*)d_in[27];
    const float* out_b   = (const float*)d_in[28];
    float* out = (float*)d_out;

    // ---- workspace layout ----
    char* p = (char*)d_ws;
    f16*  ht16    = (f16*)p;  p += (size_t)NN * 64 * 2;
    f16*  hs16    = (f16*)p;  p += (size_t)EE * 64 * 2;
    f16*  hn16    = (f16*)p;  p += (size_t)NN * 128 * 2;
    f16*  xnode16 = (f16*)p;  p += (size_t)NN * 128 * 2;
    float* ct     = (float*)p; p += (size_t)NN * 64 * 4;
    float* cs     = (float*)p; p += (size_t)EE * 64 * 4;
    float* cn     = (float*)p; p += (size_t)NN * 128 * 4;
    f16*  Wt_t    = (f16*)p;  p += (size_t)256 * 128 * 2;
    f16*  Wt_s    = (f16*)p;  p += (size_t)256 * 128 * 2;
    f16*  Wt_n    = (f16*)p;  p += (size_t)512 * 256 * 2;
    f16*  Wt_ee2  = (f16*)p;  p += (size_t)64 * 192 * 2;
    int*  csr_ptr = (int*)p;  p += (size_t)(NN + 8) * 4;
    int*  csr_row = (int*)p;  p += (size_t)2 * EE * 4;
    int*  cnt     = (int*)p;  p += (size_t)NN * 4;
    int*  cur     = (int*)p;  p += (size_t)NN * 4;

    // ---- one-time: state init, weight conversion, CSR ----
    cvt_kernel<<<(NN * 64 / 2 + 255) / 256, 256, 0, stream>>>(h_t0, ht16, NN * 64 / 2);
    cvt_kernel<<<(EE * 64 / 2 + 255) / 256, 256, 0, stream>>>(h_s0, hs16, EE * 64 / 2);
    cvt_kernel<<<(NN * 128 / 2 + 255) / 256, 256, 0, stream>>>(h_n0, hn16, NN * 128 / 2);
    hipMemcpyAsync(ct, c_t0, (size_t)NN * 64 * 4, hipMemcpyDeviceToDevice, stream);
    hipMemcpyAsync(cs, c_s0, (size_t)EE * 64 * 4, hipMemcpyDeviceToDevice, stream);
    hipMemcpyAsync(cn, c_n0, (size_t)NN * 128 * 4, hipMemcpyDeviceToDevice, stream);

    transpose_w_kernel<<<(256 * 128 + 255) / 256, 256, 0, stream>>>(t_Wih, t_Whh, Wt_t, 64, 128, 256);
    transpose_w_kernel<<<(256 * 128 + 255) / 256, 256, 0, stream>>>(s_Wih, s_Whh, Wt_s, 64, 128, 256);
    transpose_w_kernel<<<(512 * 256 + 255) / 256, 256, 0, stream>>>(n_Wih, n_Whh, Wt_n, 128, 256, 512);
    transpose_ee2_kernel<<<(64 * 192 + 255) / 256, 256, 0, stream>>>(ee_w, Wt_ee2);

    hipMemsetAsync(cnt, 0, NN * sizeof(int), stream);
    hipMemsetAsync(cur, 0, NN * sizeof(int), stream);
    count_kernel<<<(2 * EE) / 256, 256, 0, stream>>>(inc, cnt);
    scan_kernel<<<1, 1024, 0, stream>>>(cnt, csr_ptr);
    fill_kernel<<<(2 * EE) / 256, 256, 0, stream>>>(inc, csr_ptr, cur, csr_row);
    sort_csr_kernel<<<NN / 256, 256, 0, stream>>>(csr_ptr, csr_row);

    // ---- pipeline: edge(0); then per step: gather(t); fused[node(t)+edge(t+1)]
    edge_lstm_fused<<<NN / 64 + EE / 64, 256, 0, stream>>>(
        data_tE, data_sE, t_enc_w, t_enc_b, s_enc_w, s_enc_b,
        Wt_t, Wt_s, t_b, s_b, ht16, ct, hs16, cs);

    const int nNode = NN / 128;               // 256
    const int nEdge = (NN + EE) / 128;        // 1280

    for (int st = 0; st < S_LEN; ++st) {
        const float* xn  = data_nodes + (size_t)st * NN;
        const float* xt1 = data_tE + (size_t)(st + 1) * NN * 2;
        const float* xs1 = data_sE + (size_t)(st + 1) * EE * 2;

        gather_embed<<<NN / 64, 256, 0, stream>>>(
            xn, ht16, hs16, csr_ptr, csr_row,
            n_enc_w, n_enc_b, Wt_ee2, ee_b, xnode16);

        const int grid = (st < S_LEN - 1) ? (nNode + nEdge) : nNode;
        node_edge_fused<<<grid, 512, 0, stream>>>(
            xnode16, Wt_n, n_b, out_w, out_b, hn16, cn, out + (size_t)st * NN,
            xt1, xs1, t_enc_w, t_enc_b, s_enc_w, s_enc_b,
            Wt_t, Wt_s, t_b, s_b, ht16, ct, hs16, cs, nNode);
    }
}

// Round 12
// 1371.399 us; speedup vs baseline: 1.3159x; 1.3159x over previous
//
#include <hip/hip_runtime.h>
#include <math.h>

// SRNN: S=16 steps, N=32768 nodes, E=131072 spatial edges.
// f16 MFMA gate GEMMs, B-resident weights. Numerics (kept, 8/8 stable):
//  - edge per-thread arithmetic = TR=64 form (absmax attractor 3.9e-3)
//  - CSR sorted ascending; agg as hi/lo f16 pair (K=192)
// NEW: edge LSTMs are row-independent recurrences -> run CH steps per
// dispatch with c resident in LDS and h recycled through LDS; per-step h
// written to slot buffers consumed by gather. CH chosen to fit ws_size.

#define S_LEN 16
#define NN 32768
#define EE 131072

typedef _Float16 f16;
typedef _Float16 f16x8 __attribute__((ext_vector_type(8)));
typedef float f32x4 __attribute__((ext_vector_type(4)));

__device__ __forceinline__ float fsigmoid(float x) {
    return __builtin_amdgcn_rcpf(1.0f + __builtin_amdgcn_exp2f(-1.44269504f * x));
}
__device__ __forceinline__ float ftanh(float x) {
    const float e = __builtin_amdgcn_exp2f(2.88539008f * x);
    return 1.0f - 2.0f * __builtin_amdgcn_rcpf(e + 1.0f);
}

__device__ __forceinline__ unsigned int pk2(float a, float b) {
    union { f16 h[2]; unsigned int u; } x;
    x.h[0] = (f16)a; x.h[1] = (f16)b;
    return x.u;
}

__device__ __forceinline__ f16x8 ld_frag16(const void* p) {
    union { uint4 v; f16x8 f; } x;
    x.v = *(const uint4*)p;
    return x.f;
}

// ---------------- multi-step edge LSTM (temporal + spatial), H=64, TR=64 ----
// Each block owns 64 rows for nsteps steps. c: LDS-resident across steps.
// h: recycled through LDS panel; per-step value flushed to hAll slot s.
// Per-thread per-step arithmetic IDENTICAL to the verified TR=64 kernel.
__global__ __launch_bounds__(256) void edge_mega(
    const float* __restrict__ xT, const float* __restrict__ xS,   // chunk-start x
    const float* __restrict__ t_enc_w, const float* __restrict__ t_enc_b,
    const float* __restrict__ s_enc_w, const float* __restrict__ s_enc_b,
    const f16* __restrict__ WtT, const f16* __restrict__ WtS,
    const float* __restrict__ biasT, const float* __restrict__ biasS,
    f16* __restrict__ htAll, f16* __restrict__ hsAll,   // slot-strided h outputs
    const float* __restrict__ cInT, const float* __restrict__ cInS,
    float* __restrict__ cOutT, float* __restrict__ cOutS,
    const int nsteps, const int writeC)
{
    constexpr int H = 64, K = 128, KSTEPS = 4, ROWB = 256, TR = 64;
    constexpr int RTN = TR / 16;   // 4
    __shared__ __align__(16) char Xls[TR * ROWB];   // 16 KB  [xenc | h] panel
    __shared__ __align__(16) float cls[TR * H];     // 16 KB  c-state (resident)
    __shared__ __align__(16) f16 hnx[TR * H];       // 8 KB   h produced this step

    const int bT = NN / TR;   // 512
    const bool isT = (int)blockIdx.x < bT;
    const int row0 = (isT ? blockIdx.x : blockIdx.x - bT) * TR;
    const float* xbase = isT ? xT : xS;
    const size_t xstep = (size_t)(isT ? NN : EE) * 2;
    const float* enc_w = isT ? t_enc_w : s_enc_w;
    const float* enc_b = isT ? t_enc_b : s_enc_b;
    const f16*   Wt    = isT ? WtT : WtS;
    const float* bias  = isT ? biasT : biasS;
    f16* hAll = isT ? htAll : hsAll;
    const size_t hstep = (size_t)(isT ? NN : EE) * 64;
    const float* cIn  = (isT ? cInT : cInS) + (size_t)row0 * H;
    float*       cOut = (isT ? cOutT : cOutS) + (size_t)row0 * H;

    const int t = threadIdx.x;
    const int wv = t >> 6, l = t & 63;
    const int lane15 = l & 15, kgrp = l >> 4;
    const int col = wv * 16 + lane15;

    // B fragments: resident in VGPRs for the whole chunk
    f16x8 bfrag[4][KSTEPS];
    #pragma unroll
    for (int q = 0; q < 4; ++q) {
        const int colq = q * H + col;
        const f16* bp = Wt + (size_t)colq * K + kgrp * 8;
        #pragma unroll
        for (int ks = 0; ks < KSTEPS; ++ks)
            bfrag[q][ks] = ld_frag16(bp + ks * 32);
    }

    // chunk start: stage c (coalesced) and h-init (slot nsteps-1) into panel
    for (int i = t; i < TR * H; i += 256) cls[i] = cIn[i];
    {
        const f16* hInit = hAll + (size_t)(nsteps - 1) * hstep + (size_t)row0 * H;
        for (int i = t; i < TR * (H / 4); i += 256) {
            const int r = i / (H / 4), j4 = (i % (H / 4)) * 4;
            const uint2 v = *(const uint2*)&hInit[(size_t)r * H + j4];
            const int byte = r * ROWB + ((H * 2 + j4 * 2) ^ ((r & 7) << 4));
            *(uint2*)(Xls + byte) = v;
        }
    }

    const float bi = bias[0 * H + col];
    const float bf = bias[1 * H + col];
    const float bg = bias[2 * H + col];
    const float bo = bias[3 * H + col];

    for (int s = 0; s < nsteps; ++s) {
        // stage x-enc for step s (panel cols 0..63)
        const float* xf = xbase + (size_t)s * xstep;
        for (int i = t; i < TR * (H / 2); i += 256) {
            const int r = i / (H / 2), j2 = (i % (H / 2)) * 2;
            const int grow = row0 + r;
            const float x0 = xf[grow * 2 + 0];
            const float x1 = xf[grow * 2 + 1];
            const float e0 = fmaxf(0.f, fmaf(x0, enc_w[j2],     fmaf(x1, enc_w[H + j2],     enc_b[j2])));
            const float e1 = fmaxf(0.f, fmaf(x0, enc_w[j2 + 1], fmaf(x1, enc_w[H + j2 + 1], enc_b[j2 + 1])));
            const int byte = r * ROWB + ((j2 * 2) ^ ((r & 7) << 4));
            *(unsigned int*)(Xls + byte) = pk2(e0, e1);
        }
        __syncthreads();

        #pragma unroll
        for (int rt = 0; rt < RTN; ++rt) {
            const int arow = rt * 16 + lane15;
            const char* abase = Xls + arow * ROWB;
            f16x8 afrag[KSTEPS];
            #pragma unroll
            for (int ks = 0; ks < KSTEPS; ++ks) {
                const int byte = (ks * 64 + kgrp * 16) ^ ((arow & 7) << 4);
                afrag[ks] = ld_frag16(abase + byte);
            }
            f32x4 acc[4];
            #pragma unroll
            for (int q = 0; q < 4; ++q)
                #pragma unroll
                for (int r = 0; r < 4; ++r) acc[q][r] = 0.f;
            #pragma unroll
            for (int ks = 0; ks < KSTEPS; ++ks)
                #pragma unroll
                for (int q = 0; q < 4; ++q)
                    acc[q] = __builtin_amdgcn_mfma_f32_16x16x32_f16(
                        afrag[ks], bfrag[q][ks], acc[q], 0, 0, 0);
            #pragma unroll
            for (int reg = 0; reg < 4; ++reg) {
                const int rl = rt * 16 + kgrp * 4 + reg;
                const float ig = fsigmoid(acc[0][reg] + bi);
                const float fg = fsigmoid(acc[1][reg] + bf);
                const float gg = ftanh(acc[2][reg] + bg);
                const float og = fsigmoid(acc[3][reg] + bo);
                const float c2 = fmaf(fg, cls[rl * H + col], ig * gg);
                cls[rl * H + col] = c2;
                hnx[rl * H + col] = (f16)(og * ftanh(c2));
            }
        }
        __syncthreads();

        // flush h: hnx -> global slot s (coalesced) AND panel h-half (next step)
        f16* hOut = hAll + (size_t)s * hstep + (size_t)row0 * H;
        for (int i = t; i < TR * (H / 4); i += 256) {
            const int r = i / (H / 4), j4 = (i % (H / 4)) * 4;
            const uint2 v = *(const uint2*)&hnx[r * H + j4];
            *(uint2*)&hOut[(size_t)r * H + j4] = v;
            const int byte = r * ROWB + ((H * 2 + j4 * 2) ^ ((r & 7) << 4));
            *(uint2*)(Xls + byte) = v;
        }
    }

    if (writeC) {
        for (int i = t; i < TR * H; i += 256) cOut[i] = cls[i];
    }
}

// ---------------- gather + embed fused (K=192: ht | agg_hi | agg_lo) --------
__global__ __launch_bounds__(256) void gather_embed(
    const float* __restrict__ xn,
    const f16* __restrict__ ht, const f16* __restrict__ hs,
    const int* __restrict__ ptr, const int* __restrict__ rowidx,
    const float* __restrict__ n_enc_w, const float* __restrict__ n_enc_b,
    const f16* __restrict__ Wt_ee2,  // [64][192]
    const float* __restrict__ ee_b,
    f16* __restrict__ xnode)
{
    constexpr int TR = 64, K = 192, KSTEPS = 6, ROWB = 384;
    __shared__ __align__(16) char Xls[TR * ROWB];   // 24 KB
    const int row0 = blockIdx.x * TR;
    const int t = threadIdx.x;
    const int wv = t >> 6, l = t & 63;
    const int lane15 = l & 15, kgrp = l >> 4;

    const int col = wv * 16 + lane15;
    f16x8 bfrag[KSTEPS];
    {
        const f16* bp = Wt_ee2 + (size_t)col * K + kgrp * 8;
        #pragma unroll
        for (int ks = 0; ks < KSTEPS; ++ks) bfrag[ks] = ld_frag16(bp + ks * 32);
    }

    // stage ht -> K cols 0..63
    for (int i = t; i < TR * 16; i += 256) {
        const int r = i / 16, j4 = (i % 16) * 4;
        const uint2 v = *(const uint2*)&ht[(size_t)(row0 + r) * 64 + j4];
        const int byte = r * ROWB + ((j4 * 2) ^ ((r & 7) << 4));
        *(uint2*)(Xls + byte) = v;
    }

    // CSR gather -> K cols 64..127 (hi) and 128..191 (lo), sorted edge order.
    {
        const int r = t >> 2, q = t & 3;
        const int n = row0 + r;
        const int beg = ptr[n], end = ptr[n + 1];
        const unsigned int* hs32 = (const unsigned int*)hs;
        float acc[16];
        #pragma unroll
        for (int j = 0; j < 16; ++j) acc[j] = 0.f;
        for (int i = beg; i < end; ++i) {
            const int e = rowidx[i];
            const unsigned int* ep = hs32 + (size_t)e * 32 + q * 8;
            #pragma unroll
            for (int j = 0; j < 8; ++j) {
                union { unsigned int u; f16 h[2]; } v;
                v.u = ep[j];
                acc[2 * j]     += (float)v.h[0];
                acc[2 * j + 1] += (float)v.h[1];
            }
        }
        #pragma unroll
        for (int j = 0; j < 8; ++j) {
            const float a0 = acc[2 * j], a1 = acc[2 * j + 1];
            const f16 h0 = (f16)a0, h1 = (f16)a1;
            const f16 l0 = (f16)(a0 - (float)h0), l1 = (f16)(a1 - (float)h1);
            union { f16 h[2]; unsigned int u; } hi, lo;
            hi.h[0] = h0; hi.h[1] = h1;
            lo.h[0] = l0; lo.h[1] = l1;
            const int bhi = r * ROWB + ((128 + q * 32 + j * 4) ^ ((r & 7) << 4));
            const int blo = r * ROWB + ((256 + q * 32 + j * 4) ^ ((r & 7) << 4));
            *(unsigned int*)(Xls + bhi) = hi.u;
            *(unsigned int*)(Xls + blo) = lo.u;
        }
    }
    __syncthreads();

    const float bb = ee_b[col];
    #pragma unroll
    for (int rt = 0; rt < TR / 16; ++rt) {
        const int arow = rt * 16 + lane15;
        const char* abase = Xls + arow * ROWB;
        f16x8 afrag[KSTEPS];
        #pragma unroll
        for (int ks = 0; ks < KSTEPS; ++ks) {
            const int byte = (ks * 64 + kgrp * 16) ^ ((arow & 7) << 4);
            afrag[ks] = ld_frag16(abase + byte);
        }
        f32x4 acc;
        #pragma unroll
        for (int r = 0; r < 4; ++r) acc[r] = 0.f;
        #pragma unroll
        for (int ks = 0; ks < KSTEPS; ++ks)
            acc = __builtin_amdgcn_mfma_f32_16x16x32_f16(afrag[ks], bfrag[ks], acc, 0, 0, 0);
        #pragma unroll
        for (int reg = 0; reg < 4; ++reg) {
            const int grow = row0 + rt * 16 + kgrp * 4 + reg;
            xnode[(size_t)grow * 128 + 64 + col] = (f16)fmaxf(0.f, acc[reg] + bb);
        }
    }

    // encoder half: cols 0..63
    for (int i = t; i < TR * 32; i += 256) {
        const int r = i >> 5, j2 = (i & 31) * 2;
        const int grow = row0 + r;
        const float x = xn[grow];
        const float e0 = fmaxf(0.f, fmaf(x, n_enc_w[j2],     n_enc_b[j2]));
        const float e1 = fmaxf(0.f, fmaf(x, n_enc_w[j2 + 1], n_enc_b[j2 + 1]));
        *(unsigned int*)&xnode[(size_t)grow * 128 + j2] = pk2(e0, e1);
    }
}

// ---------------- node LSTM (H=128) + fused output projection ----------------
__global__ __launch_bounds__(512) void node_lstm(
    const f16* __restrict__ xin,
    const f16* __restrict__ Wt,     // [512][256]
    const float* __restrict__ bias, // [512]
    const float* __restrict__ out_w, const float* __restrict__ out_b,
    f16* __restrict__ h, float* __restrict__ c, float* __restrict__ outp)
{
    constexpr int H = 128, K = 256, KSTEPS = 8, ROWB = 512, TR = 128;
    constexpr int RTN = TR / 16;   // 8
    __shared__ __align__(16) char Xls[TR * ROWB];   // 64 KB
    __shared__ float out_part[TR][8];               // 4 KB

    const int row0 = blockIdx.x * TR;
    const int t = threadIdx.x;
    const int wv = t >> 6, l = t & 63;
    const int lane15 = l & 15, kgrp = l >> 4;
    const int col = wv * 16 + lane15;

    f16x8 bfrag[4][KSTEPS];
    #pragma unroll
    for (int q = 0; q < 4; ++q) {
        const int colq = q * H + col;
        const f16* bp = Wt + (size_t)colq * K + kgrp * 8;
        #pragma unroll
        for (int ks = 0; ks < KSTEPS; ++ks)
            bfrag[q][ks] = ld_frag16(bp + ks * 32);
    }

    for (int i = t; i < TR * (H / 4); i += 512) {
        const int r = i / (H / 4), j4 = (i % (H / 4)) * 4;
        const uint2 v = *(const uint2*)&xin[(size_t)(row0 + r) * H + j4];
        const int byte = r * ROWB + ((j4 * 2) ^ ((r & 7) << 4));
        *(uint2*)(Xls + byte) = v;
    }
    for (int i = t; i < TR * (H / 4); i += 512) {
        const int r = i / (H / 4), j4 = (i % (H / 4)) * 4;
        const uint2 v = *(const uint2*)&h[(size_t)(row0 + r) * H + j4];
        const int byte = r * ROWB + ((H * 2 + j4 * 2) ^ ((r & 7) << 4));
        *(uint2*)(Xls + byte) = v;
    }
    __syncthreads();

    const float bi = bias[0 * H + col];
    const float bf = bias[1 * H + col];
    const float bg = bias[2 * H + col];
    const float bo = bias[3 * H + col];
    const float wout = out_w[col];

    #pragma unroll
    for (int rt = 0; rt < RTN; ++rt) {
        const int arow = rt * 16 + lane15;
        const char* abase = Xls + arow * ROWB;
        f16x8 afrag[KSTEPS];
        #pragma unroll
        for (int ks = 0; ks < KSTEPS; ++ks) {
            const int byte = (ks * 64 + kgrp * 16) ^ ((arow & 7) << 4);
            afrag[ks] = ld_frag16(abase + byte);
        }
        f32x4 acc[4];
        #pragma unroll
        for (int q = 0; q < 4; ++q)
            #pragma unroll
            for (int r = 0; r < 4; ++r) acc[q][r] = 0.f;
        #pragma unroll
        for (int ks = 0; ks < KSTEPS; ++ks)
            #pragma unroll
            for (int q = 0; q < 4; ++q)
                acc[q] = __builtin_amdgcn_mfma_f32_16x16x32_f16(
                    afrag[ks], bfrag[q][ks], acc[q], 0, 0, 0);
        #pragma unroll
        for (int reg = 0; reg < 4; ++reg) {
            const int rl = rt * 16 + kgrp * 4 + reg;
            const int grow = row0 + rl;
            const size_t off = (size_t)grow * H + col;
            const float ig = fsigmoid(acc[0][reg] + bi);
            const float fg = fsigmoid(acc[1][reg] + bf);
            const float gg = ftanh(acc[2][reg] + bg);
            const float og = fsigmoid(acc[3][reg] + bo);
            const float c2 = fmaf(fg, c[off], ig * gg);
            const float h2 = og * ftanh(c2);
            c[off] = c2;
            h[off] = (f16)h2;
            float pv = h2 * wout;
            pv += __shfl_xor(pv, 1);
            pv += __shfl_xor(pv, 2);
            pv += __shfl_xor(pv, 4);
            pv += __shfl_xor(pv, 8);
            if (lane15 == 0) out_part[rl][wv] = pv;
        }
    }
    __syncthreads();
    if (t < TR) {
        float s = out_part[t][0];
        #pragma unroll
        for (int w = 1; w < 8; ++w) s += out_part[t][w];
        outp[row0 + t] = s + out_b[0];
    }
}

// ---------------- CSR build (once; inc is step-invariant) ----------------
__global__ __launch_bounds__(256) void count_kernel(
    const int* __restrict__ inc, int* __restrict__ cnt)
{
    const int slot = blockIdx.x * 256 + threadIdx.x;
    atomicAdd(&cnt[inc[slot]], 1);
}

__global__ __launch_bounds__(1024) void scan_kernel(
    const int* __restrict__ cnt, int* __restrict__ ptr)
{
    __shared__ int sums[1024];
    const int t = threadIdx.x;
    const int base = t * 32;
    int local[32];
    int s = 0;
    #pragma unroll
    for (int i = 0; i < 32; ++i) { local[i] = s; s += cnt[base + i]; }
    sums[t] = s;
    __syncthreads();
    for (int off = 1; off < 1024; off <<= 1) {
        int v = 0;
        if (t >= off) v = sums[t - off];
        __syncthreads();
        sums[t] += v;
        __syncthreads();
    }
    const int excl = sums[t] - s;
    #pragma unroll
    for (int i = 0; i < 32; ++i) ptr[base + i] = excl + local[i];
    if (t == 1023) ptr[NN] = sums[1023];
}

__global__ __launch_bounds__(256) void fill_kernel(
    const int* __restrict__ inc, const int* __restrict__ ptr,
    int* __restrict__ cur, int* __restrict__ rowidx)
{
    const int slot = blockIdx.x * 256 + threadIdx.x;
    const int n = inc[slot];
    const int pos = atomicAdd(&cur[n], 1);
    rowidx[ptr[n] + pos] = slot >> 1;
}

// Sort each node's edge list ascending (deterministic; matches segment_sum).
__global__ __launch_bounds__(256) void sort_csr_kernel(
    const int* __restrict__ ptr, int* __restrict__ rowidx)
{
    const int n = blockIdx.x * 256 + threadIdx.x;
    if (n >= NN) return;
    const int beg = ptr[n], end = ptr[n + 1];
    for (int i = beg; i < end - 1; ++i) {
        int mi = i, mv = rowidx[i];
        for (int j = i + 1; j < end; ++j) {
            const int v = rowidx[j];
            if (v < mv) { mv = v; mi = j; }
        }
        if (mi != i) { rowidx[mi] = rowidx[i]; rowidx[i] = mv; }
    }
}

// ---------------- weight transpose+convert (once) ----------------
__global__ __launch_bounds__(256) void transpose_w_kernel(
    const float* __restrict__ Wih, const float* __restrict__ Whh,
    f16* __restrict__ dst, int Hk, int K, int fourH)
{
    const int tid = blockIdx.x * 256 + threadIdx.x;
    if (tid >= K * fourH) return;
    const int col = tid / K, k = tid % K;
    const float v = (k < Hk) ? Wih[(size_t)k * fourH + col]
                             : Whh[(size_t)(k - Hk) * fourH + col];
    dst[tid] = (f16)v;
}

// ee_w (128,64) -> Wt_ee2 [64][192]: k<128 -> row k; k>=128 -> row k-64.
__global__ __launch_bounds__(256) void transpose_ee2_kernel(
    const float* __restrict__ ee_w, f16* __restrict__ dst)
{
    const int tid = blockIdx.x * 256 + threadIdx.x;
    if (tid >= 64 * 192) return;
    const int col = tid / 192, k = tid % 192;
    const int srcrow = (k < 128) ? k : (k - 64);
    dst[tid] = (f16)ee_w[(size_t)srcrow * 64 + col];
}

__global__ __launch_bounds__(256) void cvt_kernel(
    const float* __restrict__ src, f16* __restrict__ dst, int n2)
{
    const int i = blockIdx.x * 256 + threadIdx.x;
    if (i >= n2) return;
    const float2 v = ((const float2*)src)[i];
    ((unsigned int*)dst)[i] = pk2(v.x, v.y);
}

extern "C" void kernel_launch(void* const* d_in, const int* in_sizes, int n_in,
                              void* d_out, int out_size, void* d_ws, size_t ws_size,
                              hipStream_t stream) {
    const float* data_nodes = (const float*)d_in[0];
    const float* data_tE    = (const float*)d_in[1];
    const float* data_sE    = (const float*)d_in[2];
    const float* h_n0 = (const float*)d_in[3];
    const float* c_n0 = (const float*)d_in[4];
    const float* h_t0 = (const float*)d_in[5];
    const float* c_t0 = (const float*)d_in[6];
    const float* h_s0 = (const float*)d_in[7];
    const float* c_s0 = (const float*)d_in[8];
    const int*   inc  = (const int*)d_in[9];
    const float* t_enc_w = (const float*)d_in[10];
    const float* t_enc_b = (const float*)d_in[11];
    const float* t_Wih   = (const float*)d_in[12];
    const float* t_Whh   = (const float*)d_in[13];
    const float* t_b     = (const float*)d_in[14];
    const float* s_enc_w = (const float*)d_in[15];
    const float* s_enc_b = (const float*)d_in[16];
    const float* s_Wih   = (const float*)d_in[17];
    const float* s_Whh   = (const float*)d_in[18];
    const float* s_b     = (const float*)d_in[19];
    const float* n_enc_w = (const float*)d_in[20];
    const float* n_enc_b = (const float*)d_in[21];
    const float* ee_w    = (const float*)d_in[22];
    const float* ee_b    = (const float*)d_in[23];
    const float* n_Wih   = (const float*)d_in[24];
    const float* n_Whh   = (const float*)d_in[25];
    const float* n_b     = (const float*)d_in[26];
    const float* out_w   = (const float*)d_in[27];
    const float* out_b   = (const float*)d_in[28];
    float* out = (float*)d_out;

    // ---- chunk-size selection: largest CH in {16,8,4,2,1} fitting ws_size --
    const size_t slotT = (size_t)NN * 64 * 2;     // 4 MB
    const size_t slotS = (size_t)EE * 64 * 2;     // 16 MB
    const size_t fixedB =
        (size_t)NN * 128 * 2 +          // xnode16
        (size_t)NN * 128 * 2 +          // hn16
        (size_t)NN * 128 * 4 +          // cn
        (size_t)NN * 64 * 4 +           // ct
        (size_t)EE * 64 * 4 +           // cs
        ((size_t)256 * 128 + 256 * 128 + 512 * 256 + 64 * 192) * 2 +  // weights
        ((size_t)(NN + 8) + 2 * (size_t)EE + NN + NN) * 4 +           // csr
        65536;                                                         // slack
    int CH = 16;
    while (CH > 1 && fixedB + (size_t)CH * (slotT + slotS) > ws_size) CH >>= 1;

    // ---- workspace layout ----
    char* p = (char*)d_ws;
    f16*  htAll   = (f16*)p;  p += (size_t)CH * slotT;
    f16*  hsAll   = (f16*)p;  p += (size_t)CH * slotS;
    f16*  xnode16 = (f16*)p;  p += (size_t)NN * 128 * 2;
    f16*  hn16    = (f16*)p;  p += (size_t)NN * 128 * 2;
    float* cn     = (float*)p; p += (size_t)NN * 128 * 4;
    float* ct     = (float*)p; p += (size_t)NN * 64 * 4;
    float* cs     = (float*)p; p += (size_t)EE * 64 * 4;
    f16*  Wt_t    = (f16*)p;  p += (size_t)256 * 128 * 2;
    f16*  Wt_s    = (f16*)p;  p += (size_t)256 * 128 * 2;
    f16*  Wt_n    = (f16*)p;  p += (size_t)512 * 256 * 2;
    f16*  Wt_ee2  = (f16*)p;  p += (size_t)64 * 192 * 2;
    int*  csr_ptr = (int*)p;  p += (size_t)(NN + 8) * 4;
    int*  csr_row = (int*)p;  p += (size_t)2 * EE * 4;
    int*  cnt     = (int*)p;  p += (size_t)NN * 4;
    int*  cur     = (int*)p;  p += (size_t)NN * 4;

    // ---- one-time: state init, weight conversion, CSR ----
    // initial h goes into slot CH-1 (edge_mega reads chunk-start h from there)
    cvt_kernel<<<(NN * 64 / 2 + 255) / 256, 256, 0, stream>>>(
        h_t0, htAll + (size_t)(CH - 1) * NN * 64, NN * 64 / 2);
    cvt_kernel<<<(EE * 64 / 2 + 255) / 256, 256, 0, stream>>>(
        h_s0, hsAll + (size_t)(CH - 1) * EE * 64, EE * 64 / 2);
    cvt_kernel<<<(NN * 128 / 2 + 255) / 256, 256, 0, stream>>>(h_n0, hn16, NN * 128 / 2);
    hipMemcpyAsync(cn, c_n0, (size_t)NN * 128 * 4, hipMemcpyDeviceToDevice, stream);
    // ct/cs need no init: chunk 0 reads c from the input buffers directly.

    transpose_w_kernel<<<(256 * 128 + 255) / 256, 256, 0, stream>>>(t_Wih, t_Whh, Wt_t, 64, 128, 256);
    transpose_w_kernel<<<(256 * 128 + 255) / 256, 256, 0, stream>>>(s_Wih, s_Whh, Wt_s, 64, 128, 256);
    transpose_w_kernel<<<(512 * 256 + 255) / 256, 256, 0, stream>>>(n_Wih, n_Whh, Wt_n, 128, 256, 512);
    transpose_ee2_kernel<<<(64 * 192 + 255) / 256, 256, 0, stream>>>(ee_w, Wt_ee2);

    hipMemsetAsync(cnt, 0, NN * sizeof(int), stream);
    hipMemsetAsync(cur, 0, NN * sizeof(int), stream);
    count_kernel<<<(2 * EE) / 256, 256, 0, stream>>>(inc, cnt);
    scan_kernel<<<1, 1024, 0, stream>>>(cnt, csr_ptr);
    fill_kernel<<<(2 * EE) / 256, 256, 0, stream>>>(inc, csr_ptr, cur, csr_row);
    sort_csr_kernel<<<NN / 256, 256, 0, stream>>>(csr_ptr, csr_row);

    const int edgeGrid = NN / 64 + EE / 64;   // 2560

    for (int c0 = 0; c0 < S_LEN; c0 += CH) {
        // edge recurrence for CH steps in one dispatch
        edge_mega<<<edgeGrid, 256, 0, stream>>>(
            data_tE + (size_t)c0 * NN * 2, data_sE + (size_t)c0 * EE * 2,
            t_enc_w, t_enc_b, s_enc_w, s_enc_b,
            Wt_t, Wt_s, t_b, s_b,
            htAll, hsAll,
            (c0 == 0) ? c_t0 : ct, (c0 == 0) ? c_s0 : cs, ct, cs,
            CH, (c0 + CH < S_LEN) ? 1 : 0);

        for (int k2 = 0; k2 < CH; ++k2) {
            const int st = c0 + k2;
            gather_embed<<<NN / 64, 256, 0, stream>>>(
                data_nodes + (size_t)st * NN,
                htAll + (size_t)k2 * NN * 64, hsAll + (size_t)k2 * EE * 64,
                csr_ptr, csr_row, n_enc_w, n_enc_b, Wt_ee2, ee_b, xnode16);
            node_lstm<<<NN / 128, 512, 0, stream>>>(
                xnode16, Wt_n, n_b, out_w, out_b, hn16, cn,
                out + (size_t)st * NN);
        }
    }
}

// Round 13
// 1222.988 us; speedup vs baseline: 1.4756x; 1.1214x over previous
//
#include <hip/hip_runtime.h>
#include <math.h>

// SRNN: S=16 steps, N=32768 nodes, E=131072 spatial edges.
// f16 MFMA gate GEMMs, B-resident weights. Numerics (kept, 9/9 stable):
//  - edge/node per-thread arithmetic = verified forms (absmax 3.9e-3)
//  - CSR sorted ascending; agg as hi/lo f16 pair (K=192)
// Structure: edge_mega (CH steps/dispatch, c in LDS, h recycled via LDS) +
// per-step gather + NEW node_mega (CH steps/dispatch, h in LDS panel across
// steps, weights loaded once). xnode slot s>0 aliases the dead hsAll[s-1]
// region -> total memory identical to r12 (fits; CH=8 on this box).

#define S_LEN 16
#define NN 32768
#define EE 131072

typedef _Float16 f16;
typedef _Float16 f16x8 __attribute__((ext_vector_type(8)));
typedef float f32x4 __attribute__((ext_vector_type(4)));

__device__ __forceinline__ float fsigmoid(float x) {
    return __builtin_amdgcn_rcpf(1.0f + __builtin_amdgcn_exp2f(-1.44269504f * x));
}
__device__ __forceinline__ float ftanh(float x) {
    const float e = __builtin_amdgcn_exp2f(2.88539008f * x);
    return 1.0f - 2.0f * __builtin_amdgcn_rcpf(e + 1.0f);
}

__device__ __forceinline__ unsigned int pk2(float a, float b) {
    union { f16 h[2]; unsigned int u; } x;
    x.h[0] = (f16)a; x.h[1] = (f16)b;
    return x.u;
}

__device__ __forceinline__ f16x8 ld_frag16(const void* p) {
    union { uint4 v; f16x8 f; } x;
    x.v = *(const uint4*)p;
    return x.f;
}

// ---------------- multi-step edge LSTM (temporal + spatial), H=64, TR=64 ----
// UNCHANGED from r12 (verified: 31.6 us/step, absmax attractor preserved).
__global__ __launch_bounds__(256) void edge_mega(
    const float* __restrict__ xT, const float* __restrict__ xS,
    const float* __restrict__ t_enc_w, const float* __restrict__ t_enc_b,
    const float* __restrict__ s_enc_w, const float* __restrict__ s_enc_b,
    const f16* __restrict__ WtT, const f16* __restrict__ WtS,
    const float* __restrict__ biasT, const float* __restrict__ biasS,
    f16* __restrict__ htAll, f16* __restrict__ hsAll,
    const float* __restrict__ cInT, const float* __restrict__ cInS,
    float* __restrict__ cOutT, float* __restrict__ cOutS,
    const int nsteps, const int writeC)
{
    constexpr int H = 64, K = 128, KSTEPS = 4, ROWB = 256, TR = 64;
    constexpr int RTN = TR / 16;
    __shared__ __align__(16) char Xls[TR * ROWB];
    __shared__ __align__(16) float cls[TR * H];
    __shared__ __align__(16) f16 hnx[TR * H];

    const int bT = NN / TR;
    const bool isT = (int)blockIdx.x < bT;
    const int row0 = (isT ? blockIdx.x : blockIdx.x - bT) * TR;
    const float* xbase = isT ? xT : xS;
    const size_t xstep = (size_t)(isT ? NN : EE) * 2;
    const float* enc_w = isT ? t_enc_w : s_enc_w;
    const float* enc_b = isT ? t_enc_b : s_enc_b;
    const f16*   Wt    = isT ? WtT : WtS;
    const float* bias  = isT ? biasT : biasS;
    f16* hAll = isT ? htAll : hsAll;
    const size_t hstep = (size_t)(isT ? NN : EE) * 64;
    const float* cIn  = (isT ? cInT : cInS) + (size_t)row0 * H;
    float*       cOut = (isT ? cOutT : cOutS) + (size_t)row0 * H;

    const int t = threadIdx.x;
    const int wv = t >> 6, l = t & 63;
    const int lane15 = l & 15, kgrp = l >> 4;
    const int col = wv * 16 + lane15;

    f16x8 bfrag[4][KSTEPS];
    #pragma unroll
    for (int q = 0; q < 4; ++q) {
        const int colq = q * H + col;
        const f16* bp = Wt + (size_t)colq * K + kgrp * 8;
        #pragma unroll
        for (int ks = 0; ks < KSTEPS; ++ks)
            bfrag[q][ks] = ld_frag16(bp + ks * 32);
    }

    for (int i = t; i < TR * H; i += 256) cls[i] = cIn[i];
    {
        const f16* hInit = hAll + (size_t)(nsteps - 1) * hstep + (size_t)row0 * H;
        for (int i = t; i < TR * (H / 4); i += 256) {
            const int r = i / (H / 4), j4 = (i % (H / 4)) * 4;
            const uint2 v = *(const uint2*)&hInit[(size_t)r * H + j4];
            const int byte = r * ROWB + ((H * 2 + j4 * 2) ^ ((r & 7) << 4));
            *(uint2*)(Xls + byte) = v;
        }
    }

    const float bi = bias[0 * H + col];
    const float bf = bias[1 * H + col];
    const float bg = bias[2 * H + col];
    const float bo = bias[3 * H + col];

    for (int s = 0; s < nsteps; ++s) {
        const float* xf = xbase + (size_t)s * xstep;
        for (int i = t; i < TR * (H / 2); i += 256) {
            const int r = i / (H / 2), j2 = (i % (H / 2)) * 2;
            const int grow = row0 + r;
            const float x0 = xf[grow * 2 + 0];
            const float x1 = xf[grow * 2 + 1];
            const float e0 = fmaxf(0.f, fmaf(x0, enc_w[j2],     fmaf(x1, enc_w[H + j2],     enc_b[j2])));
            const float e1 = fmaxf(0.f, fmaf(x0, enc_w[j2 + 1], fmaf(x1, enc_w[H + j2 + 1], enc_b[j2 + 1])));
            const int byte = r * ROWB + ((j2 * 2) ^ ((r & 7) << 4));
            *(unsigned int*)(Xls + byte) = pk2(e0, e1);
        }
        __syncthreads();

        #pragma unroll
        for (int rt = 0; rt < RTN; ++rt) {
            const int arow = rt * 16 + lane15;
            const char* abase = Xls + arow * ROWB;
            f16x8 afrag[KSTEPS];
            #pragma unroll
            for (int ks = 0; ks < KSTEPS; ++ks) {
                const int byte = (ks * 64 + kgrp * 16) ^ ((arow & 7) << 4);
                afrag[ks] = ld_frag16(abase + byte);
            }
            f32x4 acc[4];
            #pragma unroll
            for (int q = 0; q < 4; ++q)
                #pragma unroll
                for (int r = 0; r < 4; ++r) acc[q][r] = 0.f;
            #pragma unroll
            for (int ks = 0; ks < KSTEPS; ++ks)
                #pragma unroll
                for (int q = 0; q < 4; ++q)
                    acc[q] = __builtin_amdgcn_mfma_f32_16x16x32_f16(
                        afrag[ks], bfrag[q][ks], acc[q], 0, 0, 0);
            #pragma unroll
            for (int reg = 0; reg < 4; ++reg) {
                const int rl = rt * 16 + kgrp * 4 + reg;
                const float ig = fsigmoid(acc[0][reg] + bi);
                const float fg = fsigmoid(acc[1][reg] + bf);
                const float gg = ftanh(acc[2][reg] + bg);
                const float og = fsigmoid(acc[3][reg] + bo);
                const float c2 = fmaf(fg, cls[rl * H + col], ig * gg);
                cls[rl * H + col] = c2;
                hnx[rl * H + col] = (f16)(og * ftanh(c2));
            }
        }
        __syncthreads();

        f16* hOut = hAll + (size_t)s * hstep + (size_t)row0 * H;
        for (int i = t; i < TR * (H / 4); i += 256) {
            const int r = i / (H / 4), j4 = (i % (H / 4)) * 4;
            const uint2 v = *(const uint2*)&hnx[r * H + j4];
            *(uint2*)&hOut[(size_t)r * H + j4] = v;
            const int byte = r * ROWB + ((H * 2 + j4 * 2) ^ ((r & 7) << 4));
            *(uint2*)(Xls + byte) = v;
        }
    }

    if (writeC) {
        for (int i = t; i < TR * H; i += 256) cOut[i] = cls[i];
    }
}

// ---------------- gather + embed fused (K=192: ht | agg_hi | agg_lo) --------
// UNCHANGED arithmetic; xnode output pointer may alias a dead hsAll slot.
__global__ __launch_bounds__(256) void gather_embed(
    const float* __restrict__ xn,
    const f16* __restrict__ ht, const f16* __restrict__ hs,
    const int* __restrict__ ptr, const int* __restrict__ rowidx,
    const float* __restrict__ n_enc_w, const float* __restrict__ n_enc_b,
    const f16* __restrict__ Wt_ee2,  // [64][192]
    const float* __restrict__ ee_b,
    f16* __restrict__ xnode)
{
    constexpr int TR = 64, K = 192, KSTEPS = 6, ROWB = 384;
    __shared__ __align__(16) char Xls[TR * ROWB];
    const int row0 = blockIdx.x * TR;
    const int t = threadIdx.x;
    const int wv = t >> 6, l = t & 63;
    const int lane15 = l & 15, kgrp = l >> 4;

    const int col = wv * 16 + lane15;
    f16x8 bfrag[KSTEPS];
    {
        const f16* bp = Wt_ee2 + (size_t)col * K + kgrp * 8;
        #pragma unroll
        for (int ks = 0; ks < KSTEPS; ++ks) bfrag[ks] = ld_frag16(bp + ks * 32);
    }

    for (int i = t; i < TR * 16; i += 256) {
        const int r = i / 16, j4 = (i % 16) * 4;
        const uint2 v = *(const uint2*)&ht[(size_t)(row0 + r) * 64 + j4];
        const int byte = r * ROWB + ((j4 * 2) ^ ((r & 7) << 4));
        *(uint2*)(Xls + byte) = v;
    }

    {
        const int r = t >> 2, q = t & 3;
        const int n = row0 + r;
        const int beg = ptr[n], end = ptr[n + 1];
        const unsigned int* hs32 = (const unsigned int*)hs;
        float acc[16];
        #pragma unroll
        for (int j = 0; j < 16; ++j) acc[j] = 0.f;
        for (int i = beg; i < end; ++i) {
            const int e = rowidx[i];
            const unsigned int* ep = hs32 + (size_t)e * 32 + q * 8;
            #pragma unroll
            for (int j = 0; j < 8; ++j) {
                union { unsigned int u; f16 h[2]; } v;
                v.u = ep[j];
                acc[2 * j]     += (float)v.h[0];
                acc[2 * j + 1] += (float)v.h[1];
            }
        }
        #pragma unroll
        for (int j = 0; j < 8; ++j) {
            const float a0 = acc[2 * j], a1 = acc[2 * j + 1];
            const f16 h0 = (f16)a0, h1 = (f16)a1;
            const f16 l0 = (f16)(a0 - (float)h0), l1 = (f16)(a1 - (float)h1);
            union { f16 h[2]; unsigned int u; } hi, lo;
            hi.h[0] = h0; hi.h[1] = h1;
            lo.h[0] = l0; lo.h[1] = l1;
            const int bhi = r * ROWB + ((128 + q * 32 + j * 4) ^ ((r & 7) << 4));
            const int blo = r * ROWB + ((256 + q * 32 + j * 4) ^ ((r & 7) << 4));
            *(unsigned int*)(Xls + bhi) = hi.u;
            *(unsigned int*)(Xls + blo) = lo.u;
        }
    }
    __syncthreads();

    const float bb = ee_b[col];
    #pragma unroll
    for (int rt = 0; rt < TR / 16; ++rt) {
        const int arow = rt * 16 + lane15;
        const char* abase = Xls + arow * ROWB;
        f16x8 afrag[KSTEPS];
        #pragma unroll
        for (int ks = 0; ks < KSTEPS; ++ks) {
            const int byte = (ks * 64 + kgrp * 16) ^ ((arow & 7) << 4);
            afrag[ks] = ld_frag16(abase + byte);
        }
        f32x4 acc;
        #pragma unroll
        for (int r = 0; r < 4; ++r) acc[r] = 0.f;
        #pragma unroll
        for (int ks = 0; ks < KSTEPS; ++ks)
            acc = __builtin_amdgcn_mfma_f32_16x16x32_f16(afrag[ks], bfrag[ks], acc, 0, 0, 0);
        #pragma unroll
        for (int reg = 0; reg < 4; ++reg) {
            const int grow = row0 + rt * 16 + kgrp * 4 + reg;
            xnode[(size_t)grow * 128 + 64 + col] = (f16)fmaxf(0.f, acc[reg] + bb);
        }
    }

    for (int i = t; i < TR * 32; i += 256) {
        const int r = i >> 5, j2 = (i & 31) * 2;
        const int grow = row0 + r;
        const float x = xn[grow];
        const float e0 = fmaxf(0.f, fmaf(x, n_enc_w[j2],     n_enc_b[j2]));
        const float e1 = fmaxf(0.f, fmaf(x, n_enc_w[j2 + 1], n_enc_b[j2 + 1]));
        *(unsigned int*)&xnode[(size_t)grow * 128 + j2] = pk2(e0, e1);
    }
}

// ---------------- multi-step node LSTM + fused output projection ------------
// One dispatch per chunk. h lives in the LDS panel across steps (epilogue
// writes h back to swizzled panel slot); weights load once. Per-rt barrier
// orders all waves' afrag reads of a 16-row band before its h overwrite.
// Per-thread arithmetic identical to the verified node_lstm.
__global__ __launch_bounds__(512) void node_mega(
    const f16* __restrict__ xnode0,     // xnode slot 0 (X0)
    const f16* __restrict__ hsAllBase,  // xnode slot s>0 = hsAllBase+(s-1)*EE*64
    const f16* __restrict__ Wt,         // [512][256]
    const float* __restrict__ bias,     // [512]
    const float* __restrict__ out_w, const float* __restrict__ out_b,
    f16* __restrict__ hIO,              // read at chunk start, write at end
    float* __restrict__ c,
    float* __restrict__ outp,           // out + chunkStart*NN
    const int nsteps)
{
    constexpr int H = 128, K = 256, KSTEPS = 8, ROWB = 512, TR = 128;
    constexpr int RTN = TR / 16;   // 8
    __shared__ __align__(16) char Xls[TR * ROWB];   // 64 KB
    __shared__ float out_part[TR][8];               // 4 KB

    const int row0 = blockIdx.x * TR;
    const int t = threadIdx.x;
    const int wv = t >> 6, l = t & 63;
    const int lane15 = l & 15, kgrp = l >> 4;
    const int col = wv * 16 + lane15;

    f16x8 bfrag[4][KSTEPS];
    #pragma unroll
    for (int q = 0; q < 4; ++q) {
        const int colq = q * H + col;
        const f16* bp = Wt + (size_t)colq * K + kgrp * 8;
        #pragma unroll
        for (int ks = 0; ks < KSTEPS; ++ks)
            bfrag[q][ks] = ld_frag16(bp + ks * 32);
    }

    // stage h (K cols 128..255) from global once; recycled thereafter
    for (int i = t; i < TR * (H / 4); i += 512) {
        const int r = i / (H / 4), j4 = (i % (H / 4)) * 4;
        const uint2 v = *(const uint2*)&hIO[(size_t)(row0 + r) * H + j4];
        const int byte = r * ROWB + ((H * 2 + j4 * 2) ^ ((r & 7) << 4));
        *(uint2*)(Xls + byte) = v;
    }

    const float bi = bias[0 * H + col];
    const float bf = bias[1 * H + col];
    const float bg = bias[2 * H + col];
    const float bo = bias[3 * H + col];
    const float wout = out_w[col];

    for (int s = 0; s < nsteps; ++s) {
        const f16* xin = (s == 0) ? xnode0
                                  : (hsAllBase + (size_t)(s - 1) * EE * 64);
        // stage x (K cols 0..127)
        for (int i = t; i < TR * (H / 4); i += 512) {
            const int r = i / (H / 4), j4 = (i % (H / 4)) * 4;
            const uint2 v = *(const uint2*)&xin[(size_t)(row0 + r) * H + j4];
            const int byte = r * ROWB + ((j4 * 2) ^ ((r & 7) << 4));
            *(uint2*)(Xls + byte) = v;
        }
        __syncthreads();   // x staged; h panel ready (initial or prev epilogue)

        const bool lastStep = (s == nsteps - 1);
        #pragma unroll 1
        for (int rt = 0; rt < RTN; ++rt) {
            const int arow = rt * 16 + lane15;
            const char* abase = Xls + arow * ROWB;
            f16x8 afrag[KSTEPS];
            #pragma unroll
            for (int ks = 0; ks < KSTEPS; ++ks) {
                const int byte = (ks * 64 + kgrp * 16) ^ ((arow & 7) << 4);
                afrag[ks] = ld_frag16(abase + byte);
            }
            __syncthreads();   // all waves read band rt before its h overwrite
            f32x4 acc[4];
            #pragma unroll
            for (int q = 0; q < 4; ++q)
                #pragma unroll
                for (int r = 0; r < 4; ++r) acc[q][r] = 0.f;
            #pragma unroll
            for (int ks = 0; ks < KSTEPS; ++ks)
                #pragma unroll
                for (int q = 0; q < 4; ++q)
                    acc[q] = __builtin_amdgcn_mfma_f32_16x16x32_f16(
                        afrag[ks], bfrag[q][ks], acc[q], 0, 0, 0);
            #pragma unroll
            for (int reg = 0; reg < 4; ++reg) {
                const int rl = rt * 16 + kgrp * 4 + reg;
                const int grow = row0 + rl;
                const size_t off = (size_t)grow * H + col;
                const float ig = fsigmoid(acc[0][reg] + bi);
                const float fg = fsigmoid(acc[1][reg] + bf);
                const float gg = ftanh(acc[2][reg] + bg);
                const float og = fsigmoid(acc[3][reg] + bo);
                const float c2 = fmaf(fg, c[off], ig * gg);
                const float h2 = og * ftanh(c2);
                c[off] = c2;
                const f16 h16 = (f16)h2;
                // write h into panel (feeds step s+1)
                const int hbyte = rl * ROWB + ((2 * (H + col)) ^ ((rl & 7) << 4));
                *(f16*)(Xls + hbyte) = h16;
                if (lastStep) hIO[off] = h16;
                float pv = h2 * wout;
                pv += __shfl_xor(pv, 1);
                pv += __shfl_xor(pv, 2);
                pv += __shfl_xor(pv, 4);
                pv += __shfl_xor(pv, 8);
                if (lane15 == 0) out_part[rl][wv] = pv;
            }
        }
        __syncthreads();
        if (t < TR) {
            float sum = out_part[t][0];
            #pragma unroll
            for (int w = 1; w < 8; ++w) sum += out_part[t][w];
            outp[(size_t)s * NN + row0 + t] = sum + out_b[0];
        }
    }
}

// ---------------- CSR build (once; inc is step-invariant) ----------------
__global__ __launch_bounds__(256) void count_kernel(
    const int* __restrict__ inc, int* __restrict__ cnt)
{
    const int slot = blockIdx.x * 256 + threadIdx.x;
    atomicAdd(&cnt[inc[slot]], 1);
}

__global__ __launch_bounds__(1024) void scan_kernel(
    const int* __restrict__ cnt, int* __restrict__ ptr)
{
    __shared__ int sums[1024];
    const int t = threadIdx.x;
    const int base = t * 32;
    int local[32];
    int s = 0;
    #pragma unroll
    for (int i = 0; i < 32; ++i) { local[i] = s; s += cnt[base + i]; }
    sums[t] = s;
    __syncthreads();
    for (int off = 1; off < 1024; off <<= 1) {
        int v = 0;
        if (t >= off) v = sums[t - off];
        __syncthreads();
        sums[t] += v;
        __syncthreads();
    }
    const int excl = sums[t] - s;
    #pragma unroll
    for (int i = 0; i < 32; ++i) ptr[base + i] = excl + local[i];
    if (t == 1023) ptr[NN] = sums[1023];
}

__global__ __launch_bounds__(256) void fill_kernel(
    const int* __restrict__ inc, const int* __restrict__ ptr,
    int* __restrict__ cur, int* __restrict__ rowidx)
{
    const int slot = blockIdx.x * 256 + threadIdx.x;
    const int n = inc[slot];
    const int pos = atomicAdd(&cur[n], 1);
    rowidx[ptr[n] + pos] = slot >> 1;
}

__global__ __launch_bounds__(256) void sort_csr_kernel(
    const int* __restrict__ ptr, int* __restrict__ rowidx)
{
    const int n = blockIdx.x * 256 + threadIdx.x;
    if (n >= NN) return;
    const int beg = ptr[n], end = ptr[n + 1];
    for (int i = beg; i < end - 1; ++i) {
        int mi = i, mv = rowidx[i];
        for (int j = i + 1; j < end; ++j) {
            const int v = rowidx[j];
            if (v < mv) { mv = v; mi = j; }
        }
        if (mi != i) { rowidx[mi] = rowidx[i]; rowidx[i] = mv; }
    }
}

// ---------------- weight transpose+convert (once) ----------------
__global__ __launch_bounds__(256) void transpose_w_kernel(
    const float* __restrict__ Wih, const float* __restrict__ Whh,
    f16* __restrict__ dst, int Hk, int K, int fourH)
{
    const int tid = blockIdx.x * 256 + threadIdx.x;
    if (tid >= K * fourH) return;
    const int col = tid / K, k = tid % K;
    const float v = (k < Hk) ? Wih[(size_t)k * fourH + col]
                             : Whh[(size_t)(k - Hk) * fourH + col];
    dst[tid] = (f16)v;
}

__global__ __launch_bounds__(256) void transpose_ee2_kernel(
    const float* __restrict__ ee_w, f16* __restrict__ dst)
{
    const int tid = blockIdx.x * 256 + threadIdx.x;
    if (tid >= 64 * 192) return;
    const int col = tid / 192, k = tid % 192;
    const int srcrow = (k < 128) ? k : (k - 64);
    dst[tid] = (f16)ee_w[(size_t)srcrow * 64 + col];
}

__global__ __launch_bounds__(256) void cvt_kernel(
    const float* __restrict__ src, f16* __restrict__ dst, int n2)
{
    const int i = blockIdx.x * 256 + threadIdx.x;
    if (i >= n2) return;
    const float2 v = ((const float2*)src)[i];
    ((unsigned int*)dst)[i] = pk2(v.x, v.y);
}

extern "C" void kernel_launch(void* const* d_in, const int* in_sizes, int n_in,
                              void* d_out, int out_size, void* d_ws, size_t ws_size,
                              hipStream_t stream) {
    const float* data_nodes = (const float*)d_in[0];
    const float* data_tE    = (const float*)d_in[1];
    const float* data_sE    = (const float*)d_in[2];
    const float* h_n0 = (const float*)d_in[3];
    const float* c_n0 = (const float*)d_in[4];
    const float* h_t0 = (const float*)d_in[5];
    const float* c_t0 = (const float*)d_in[6];
    const float* h_s0 = (const float*)d_in[7];
    const float* c_s0 = (const float*)d_in[8];
    const int*   inc  = (const int*)d_in[9];
    const float* t_enc_w = (const float*)d_in[10];
    const float* t_enc_b = (const float*)d_in[11];
    const float* t_Wih   = (const float*)d_in[12];
    const float* t_Whh   = (const float*)d_in[13];
    const float* t_b     = (const float*)d_in[14];
    const float* s_enc_w = (const float*)d_in[15];
    const float* s_enc_b = (const float*)d_in[16];
    const float* s_Wih   = (const float*)d_in[17];
    const float* s_Whh   = (const float*)d_in[18];
    const float* s_b     = (const float*)d_in[19];
    const float* n_enc_w = (const float*)d_in[20];
    const float* n_enc_b = (const float*)d_in[21];
    const float* ee_w    = (const float*)d_in[22];
    const float* ee_b    = (const float*)d_in[23];
    const float* n_Wih   = (const float*)d_in[24];
    const float* n_Whh   = (const float*)d_in[25];
    const float* n_b     = (const float*)d_in[26];
    const float* out_w   = (const float*)d_in[27];
    const float* out_b   = (const float*)d_in[28];
    float* out = (float*)d_out;

    // ---- chunk-size selection (same arithmetic as r12 -> same CH) ----
    const size_t slotT = (size_t)NN * 64 * 2;     // 4 MB
    const size_t slotS = (size_t)EE * 64 * 2;     // 16 MB
    const size_t fixedB =
        (size_t)NN * 128 * 2 +          // X0 (xnode slot 0)
        (size_t)NN * 128 * 2 +          // hn16
        (size_t)NN * 128 * 4 +          // cn
        (size_t)NN * 64 * 4 +           // ct
        (size_t)EE * 64 * 4 +           // cs
        ((size_t)256 * 128 + 256 * 128 + 512 * 256 + 64 * 192) * 2 +
        ((size_t)(NN + 8) + 2 * (size_t)EE + NN + NN) * 4 +
        65536;
    int CH = 16;
    while (CH > 1 && fixedB + (size_t)CH * (slotT + slotS) > ws_size) CH >>= 1;

    // ---- workspace layout ----
    char* p = (char*)d_ws;
    f16*  htAll   = (f16*)p;  p += (size_t)CH * slotT;
    f16*  hsAll   = (f16*)p;  p += (size_t)CH * slotS;
    f16*  X0      = (f16*)p;  p += (size_t)NN * 128 * 2;
    f16*  hn16    = (f16*)p;  p += (size_t)NN * 128 * 2;
    float* cn     = (float*)p; p += (size_t)NN * 128 * 4;
    float* ct     = (float*)p; p += (size_t)NN * 64 * 4;
    float* cs     = (float*)p; p += (size_t)EE * 64 * 4;
    f16*  Wt_t    = (f16*)p;  p += (size_t)256 * 128 * 2;
    f16*  Wt_s    = (f16*)p;  p += (size_t)256 * 128 * 2;
    f16*  Wt_n    = (f16*)p;  p += (size_t)512 * 256 * 2;
    f16*  Wt_ee2  = (f16*)p;  p += (size_t)64 * 192 * 2;
    int*  csr_ptr = (int*)p;  p += (size_t)(NN + 8) * 4;
    int*  csr_row = (int*)p;  p += (size_t)2 * EE * 4;
    int*  cnt     = (int*)p;  p += (size_t)NN * 4;
    int*  cur     = (int*)p;  p += (size_t)NN * 4;

    // ---- one-time: state init, weight conversion, CSR ----
    cvt_kernel<<<(NN * 64 / 2 + 255) / 256, 256, 0, stream>>>(
        h_t0, htAll + (size_t)(CH - 1) * NN * 64, NN * 64 / 2);
    cvt_kernel<<<(EE * 64 / 2 + 255) / 256, 256, 0, stream>>>(
        h_s0, hsAll + (size_t)(CH - 1) * EE * 64, EE * 64 / 2);
    cvt_kernel<<<(NN * 128 / 2 + 255) / 256, 256, 0, stream>>>(h_n0, hn16, NN * 128 / 2);
    hipMemcpyAsync(cn, c_n0, (size_t)NN * 128 * 4, hipMemcpyDeviceToDevice, stream);

    transpose_w_kernel<<<(256 * 128 + 255) / 256, 256, 0, stream>>>(t_Wih, t_Whh, Wt_t, 64, 128, 256);
    transpose_w_kernel<<<(256 * 128 + 255) / 256, 256, 0, stream>>>(s_Wih, s_Whh, Wt_s, 64, 128, 256);
    transpose_w_kernel<<<(512 * 256 + 255) / 256, 256, 0, stream>>>(n_Wih, n_Whh, Wt_n, 128, 256, 512);
    transpose_ee2_kernel<<<(64 * 192 + 255) / 256, 256, 0, stream>>>(ee_w, Wt_ee2);

    hipMemsetAsync(cnt, 0, NN * sizeof(int), stream);
    hipMemsetAsync(cur, 0, NN * sizeof(int), stream);
    count_kernel<<<(2 * EE) / 256, 256, 0, stream>>>(inc, cnt);
    scan_kernel<<<1, 1024, 0, stream>>>(cnt, csr_ptr);
    fill_kernel<<<(2 * EE) / 256, 256, 0, stream>>>(inc, csr_ptr, cur, csr_row);
    sort_csr_kernel<<<NN / 256, 256, 0, stream>>>(csr_ptr, csr_row);

    const int edgeGrid = NN / 64 + EE / 64;   // 2560

    for (int c0 = 0; c0 < S_LEN; c0 += CH) {
        // 1) edge recurrence for CH steps
        edge_mega<<<edgeGrid, 256, 0, stream>>>(
            data_tE + (size_t)c0 * NN * 2, data_sE + (size_t)c0 * EE * 2,
            t_enc_w, t_enc_b, s_enc_w, s_enc_b,
            Wt_t, Wt_s, t_b, s_b,
            htAll, hsAll,
            (c0 == 0) ? c_t0 : ct, (c0 == 0) ? c_s0 : cs, ct, cs,
            CH, (c0 + CH < S_LEN) ? 1 : 0);

        // 2) per-step gather; xnode slot s>0 aliases dead hsAll[s-1]
        //    (dispatch boundary makes the alias race-free: gather(s) reads
        //     slot s, writes slot s-1's region)
        for (int k2 = 0; k2 < CH; ++k2) {
            const int st = c0 + k2;
            f16* xnode_s = (k2 == 0) ? X0 : (hsAll + (size_t)(k2 - 1) * EE * 64);
            gather_embed<<<NN / 64, 256, 0, stream>>>(
                data_nodes + (size_t)st * NN,
                htAll + (size_t)k2 * NN * 64, hsAll + (size_t)k2 * EE * 64,
                csr_ptr, csr_row, n_enc_w, n_enc_b, Wt_ee2, ee_b, xnode_s);
        }

        // 3) node recurrence for CH steps (h in LDS panel, weights loaded once)
        node_mega<<<NN / 128, 512, 0, stream>>>(
            X0, hsAll, Wt_n, n_b, out_w, out_b, hn16, cn,
            out + (size_t)c0 * NN, CH);
    }
}

// Round 14
// 1146.096 us; speedup vs baseline: 1.5746x; 1.0671x over previous
//
#include <hip/hip_runtime.h>
#include <math.h>

// SRNN: S=16 steps, N=32768 nodes, E=131072 spatial edges.
// f16 MFMA gate GEMMs, B-resident weights. Numerics (kept, 10/10 stable):
//  - edge/node per-thread arithmetic = verified forms (absmax 3.90625e-3)
//  - CSR sorted ascending; agg as hi/lo f16 pair (K=192)
// Structure: edge_mega / per-step gather (alias-safe via dispatch boundary) /
// node_mega. THIS ROUND (edge_mega only): cls/hnx XOR bank-swizzle (kills the
// 4-way epilogue LDS conflicts, 1.3e7/dispatch) + x-register prefetch
// (hides next-step global x latency under MFMA). Values bit-identical.

#define S_LEN 16
#define NN 32768
#define EE 131072

typedef _Float16 f16;
typedef _Float16 f16x8 __attribute__((ext_vector_type(8)));
typedef float f32x4 __attribute__((ext_vector_type(4)));

__device__ __forceinline__ float fsigmoid(float x) {
    return __builtin_amdgcn_rcpf(1.0f + __builtin_amdgcn_exp2f(-1.44269504f * x));
}
__device__ __forceinline__ float ftanh(float x) {
    const float e = __builtin_amdgcn_exp2f(2.88539008f * x);
    return 1.0f - 2.0f * __builtin_amdgcn_rcpf(e + 1.0f);
}

__device__ __forceinline__ unsigned int pk2(float a, float b) {
    union { f16 h[2]; unsigned int u; } x;
    x.h[0] = (f16)a; x.h[1] = (f16)b;
    return x.u;
}

__device__ __forceinline__ f16x8 ld_frag16(const void* p) {
    union { uint4 v; f16x8 f; } x;
    x.v = *(const uint4*)p;
    return x.f;
}

// bank swizzle for cls/hnx: spread kgrp row-groups across bank windows.
// bits 4-5 XOR only -> 4-aligned groups stay contiguous.
#define CSWZ(rl) ((((rl) >> 2) & 3) << 4)

// ---------------- multi-step edge LSTM (temporal + spatial), H=64, TR=64 ----
// Each block owns 64 rows for nsteps steps. c: LDS-resident (XOR-swizzled).
// h: recycled through LDS panel; per-step value flushed to hAll slot s.
// Next-step x prefetched into registers during MFMA. Per-thread per-step
// arithmetic IDENTICAL to the verified form (addresses/schedule only).
__global__ __launch_bounds__(256) void edge_mega(
    const float* __restrict__ xT, const float* __restrict__ xS,
    const float* __restrict__ t_enc_w, const float* __restrict__ t_enc_b,
    const float* __restrict__ s_enc_w, const float* __restrict__ s_enc_b,
    const f16* __restrict__ WtT, const f16* __restrict__ WtS,
    const float* __restrict__ biasT, const float* __restrict__ biasS,
    f16* __restrict__ htAll, f16* __restrict__ hsAll,
    const float* __restrict__ cInT, const float* __restrict__ cInS,
    float* __restrict__ cOutT, float* __restrict__ cOutS,
    const int nsteps, const int writeC)
{
    constexpr int H = 64, K = 128, KSTEPS = 4, ROWB = 256, TR = 64;
    constexpr int RTN = TR / 16;
    __shared__ __align__(16) char Xls[TR * ROWB];   // 16 KB
    __shared__ __align__(16) float cls[TR * H];     // 16 KB (swizzled)
    __shared__ __align__(16) f16 hnx[TR * H];       // 8 KB  (swizzled)

    const int bT = NN / TR;
    const bool isT = (int)blockIdx.x < bT;
    const int row0 = (isT ? blockIdx.x : blockIdx.x - bT) * TR;
    const float* xbase = isT ? xT : xS;
    const size_t xstep = (size_t)(isT ? NN : EE) * 2;
    const float* enc_w = isT ? t_enc_w : s_enc_w;
    const float* enc_b = isT ? t_enc_b : s_enc_b;
    const f16*   Wt    = isT ? WtT : WtS;
    const float* bias  = isT ? biasT : biasS;
    f16* hAll = isT ? htAll : hsAll;
    const size_t hstep = (size_t)(isT ? NN : EE) * 64;
    const float* cIn  = (isT ? cInT : cInS) + (size_t)row0 * H;
    float*       cOut = (isT ? cOutT : cOutS) + (size_t)row0 * H;

    const int t = threadIdx.x;
    const int wv = t >> 6, l = t & 63;
    const int lane15 = l & 15, kgrp = l >> 4;
    const int col = wv * 16 + lane15;

    f16x8 bfrag[4][KSTEPS];
    #pragma unroll
    for (int q = 0; q < 4; ++q) {
        const int colq = q * H + col;
        const f16* bp = Wt + (size_t)colq * K + kgrp * 8;
        #pragma unroll
        for (int ks = 0; ks < KSTEPS; ++ks)
            bfrag[q][ks] = ld_frag16(bp + ks * 32);
    }

    // stage c (swizzled) and h-init (slot nsteps-1) into panel
    for (int i = t; i < TR * H; i += 256) {
        const int r = i >> 6, j = i & 63;
        cls[(r << 6) + (j ^ CSWZ(r))] = cIn[i];
    }
    {
        const f16* hInit = hAll + (size_t)(nsteps - 1) * hstep + (size_t)row0 * H;
        for (int i = t; i < TR * (H / 4); i += 256) {
            const int r = i / (H / 4), j4 = (i % (H / 4)) * 4;
            const uint2 v = *(const uint2*)&hInit[(size_t)r * H + j4];
            const int byte = r * ROWB + ((H * 2 + j4 * 2) ^ ((r & 7) << 4));
            *(uint2*)(Xls + byte) = v;
        }
    }

    const float bi = bias[0 * H + col];
    const float bf = bias[1 * H + col];
    const float bg = bias[2 * H + col];
    const float bo = bias[3 * H + col];

    // x prefetch registers for the 8 staging iterations of this thread
    float xr0[8], xr1[8];
    {
        const float* xf = xbase;
        #pragma unroll
        for (int k2 = 0; k2 < 8; ++k2) {
            const int r = (t + k2 * 256) >> 5;
            xr0[k2] = xf[(size_t)(row0 + r) * 2 + 0];
            xr1[k2] = xf[(size_t)(row0 + r) * 2 + 1];
        }
    }

    for (int s = 0; s < nsteps; ++s) {
        // stage x-enc for step s from prefetched regs (panel cols 0..63)
        #pragma unroll
        for (int k2 = 0; k2 < 8; ++k2) {
            const int i = t + k2 * 256;
            const int r = i >> 5, j2 = (i & 31) * 2;
            const float x0 = xr0[k2];
            const float x1 = xr1[k2];
            const float e0 = fmaxf(0.f, fmaf(x0, enc_w[j2],     fmaf(x1, enc_w[H + j2],     enc_b[j2])));
            const float e1 = fmaxf(0.f, fmaf(x0, enc_w[j2 + 1], fmaf(x1, enc_w[H + j2 + 1], enc_b[j2 + 1])));
            const int byte = r * ROWB + ((j2 * 2) ^ ((r & 7) << 4));
            *(unsigned int*)(Xls + byte) = pk2(e0, e1);
        }
        __syncthreads();

        // prefetch next step's x (latency hides under MFMA/epilogue)
        if (s + 1 < nsteps) {
            const float* xf = xbase + (size_t)(s + 1) * xstep;
            #pragma unroll
            for (int k2 = 0; k2 < 8; ++k2) {
                const int r = (t + k2 * 256) >> 5;
                xr0[k2] = xf[(size_t)(row0 + r) * 2 + 0];
                xr1[k2] = xf[(size_t)(row0 + r) * 2 + 1];
            }
        }

        #pragma unroll
        for (int rt = 0; rt < RTN; ++rt) {
            const int arow = rt * 16 + lane15;
            const char* abase = Xls + arow * ROWB;
            f16x8 afrag[KSTEPS];
            #pragma unroll
            for (int ks = 0; ks < KSTEPS; ++ks) {
                const int byte = (ks * 64 + kgrp * 16) ^ ((arow & 7) << 4);
                afrag[ks] = ld_frag16(abase + byte);
            }
            f32x4 acc[4];
            #pragma unroll
            for (int q = 0; q < 4; ++q)
                #pragma unroll
                for (int r = 0; r < 4; ++r) acc[q][r] = 0.f;
            #pragma unroll
            for (int ks = 0; ks < KSTEPS; ++ks)
                #pragma unroll
                for (int q = 0; q < 4; ++q)
                    acc[q] = __builtin_amdgcn_mfma_f32_16x16x32_f16(
                        afrag[ks], bfrag[q][ks], acc[q], 0, 0, 0);
            #pragma unroll
            for (int reg = 0; reg < 4; ++reg) {
                const int rl = rt * 16 + kgrp * 4 + reg;
                const int sc = (rl << 6) + (col ^ CSWZ(rl));
                const float ig = fsigmoid(acc[0][reg] + bi);
                const float fg = fsigmoid(acc[1][reg] + bf);
                const float gg = ftanh(acc[2][reg] + bg);
                const float og = fsigmoid(acc[3][reg] + bo);
                const float c2 = fmaf(fg, cls[sc], ig * gg);
                cls[sc] = c2;
                hnx[sc] = (f16)(og * ftanh(c2));
            }
        }
        __syncthreads();

        // flush h: hnx (swizzled) -> global slot s (coalesced) AND panel h-half
        f16* hOut = hAll + (size_t)s * hstep + (size_t)row0 * H;
        for (int i = t; i < TR * (H / 4); i += 256) {
            const int r = i / (H / 4), j4 = (i % (H / 4)) * 4;
            const uint2 v = *(const uint2*)&hnx[(r << 6) + (j4 ^ CSWZ(r))];
            *(uint2*)&hOut[(size_t)r * H + j4] = v;
            const int byte = r * ROWB + ((H * 2 + j4 * 2) ^ ((r & 7) << 4));
            *(uint2*)(Xls + byte) = v;
        }
    }

    if (writeC) {
        for (int i = t; i < TR * H; i += 256) {
            const int r = i >> 6, j = i & 63;
            cOut[i] = cls[(r << 6) + (j ^ CSWZ(r))];
        }
    }
}

// ---------------- gather + embed fused (K=192: ht | agg_hi | agg_lo) --------
// UNCHANGED from r13 (alias-safe: one dispatch per step).
__global__ __launch_bounds__(256) void gather_embed(
    const float* __restrict__ xn,
    const f16* __restrict__ ht, const f16* __restrict__ hs,
    const int* __restrict__ ptr, const int* __restrict__ rowidx,
    const float* __restrict__ n_enc_w, const float* __restrict__ n_enc_b,
    const f16* __restrict__ Wt_ee2,  // [64][192]
    const float* __restrict__ ee_b,
    f16* __restrict__ xnode)
{
    constexpr int TR = 64, K = 192, KSTEPS = 6, ROWB = 384;
    __shared__ __align__(16) char Xls[TR * ROWB];
    const int row0 = blockIdx.x * TR;
    const int t = threadIdx.x;
    const int wv = t >> 6, l = t & 63;
    const int lane15 = l & 15, kgrp = l >> 4;

    const int col = wv * 16 + lane15;
    f16x8 bfrag[KSTEPS];
    {
        const f16* bp = Wt_ee2 + (size_t)col * K + kgrp * 8;
        #pragma unroll
        for (int ks = 0; ks < KSTEPS; ++ks) bfrag[ks] = ld_frag16(bp + ks * 32);
    }

    for (int i = t; i < TR * 16; i += 256) {
        const int r = i / 16, j4 = (i % 16) * 4;
        const uint2 v = *(const uint2*)&ht[(size_t)(row0 + r) * 64 + j4];
        const int byte = r * ROWB + ((j4 * 2) ^ ((r & 7) << 4));
        *(uint2*)(Xls + byte) = v;
    }

    {
        const int r = t >> 2, q = t & 3;
        const int n = row0 + r;
        const int beg = ptr[n], end = ptr[n + 1];
        const unsigned int* hs32 = (const unsigned int*)hs;
        float acc[16];
        #pragma unroll
        for (int j = 0; j < 16; ++j) acc[j] = 0.f;
        for (int i = beg; i < end; ++i) {
            const int e = rowidx[i];
            const unsigned int* ep = hs32 + (size_t)e * 32 + q * 8;
            #pragma unroll
            for (int j = 0; j < 8; ++j) {
                union { unsigned int u; f16 h[2]; } v;
                v.u = ep[j];
                acc[2 * j]     += (float)v.h[0];
                acc[2 * j + 1] += (float)v.h[1];
            }
        }
        #pragma unroll
        for (int j = 0; j < 8; ++j) {
            const float a0 = acc[2 * j], a1 = acc[2 * j + 1];
            const f16 h0 = (f16)a0, h1 = (f16)a1;
            const f16 l0 = (f16)(a0 - (float)h0), l1 = (f16)(a1 - (float)h1);
            union { f16 h[2]; unsigned int u; } hi, lo;
            hi.h[0] = h0; hi.h[1] = h1;
            lo.h[0] = l0; lo.h[1] = l1;
            const int bhi = r * ROWB + ((128 + q * 32 + j * 4) ^ ((r & 7) << 4));
            const int blo = r * ROWB + ((256 + q * 32 + j * 4) ^ ((r & 7) << 4));
            *(unsigned int*)(Xls + bhi) = hi.u;
            *(unsigned int*)(Xls + blo) = lo.u;
        }
    }
    __syncthreads();

    const float bb = ee_b[col];
    #pragma unroll
    for (int rt = 0; rt < TR / 16; ++rt) {
        const int arow = rt * 16 + lane15;
        const char* abase = Xls + arow * ROWB;
        f16x8 afrag[KSTEPS];
        #pragma unroll
        for (int ks = 0; ks < KSTEPS; ++ks) {
            const int byte = (ks * 64 + kgrp * 16) ^ ((arow & 7) << 4);
            afrag[ks] = ld_frag16(abase + byte);
        }
        f32x4 acc;
        #pragma unroll
        for (int r = 0; r < 4; ++r) acc[r] = 0.f;
        #pragma unroll
        for (int ks = 0; ks < KSTEPS; ++ks)
            acc = __builtin_amdgcn_mfma_f32_16x16x32_f16(afrag[ks], bfrag[ks], acc, 0, 0, 0);
        #pragma unroll
        for (int reg = 0; reg < 4; ++reg) {
            const int grow = row0 + rt * 16 + kgrp * 4 + reg;
            xnode[(size_t)grow * 128 + 64 + col] = (f16)fmaxf(0.f, acc[reg] + bb);
        }
    }

    for (int i = t; i < TR * 32; i += 256) {
        const int r = i >> 5, j2 = (i & 31) * 2;
        const int grow = row0 + r;
        const float x = xn[grow];
        const float e0 = fmaxf(0.f, fmaf(x, n_enc_w[j2],     n_enc_b[j2]));
        const float e1 = fmaxf(0.f, fmaf(x, n_enc_w[j2 + 1], n_enc_b[j2 + 1]));
        *(unsigned int*)&xnode[(size_t)grow * 128 + j2] = pk2(e0, e1);
    }
}

// ---------------- multi-step node LSTM + fused output projection ------------
// UNCHANGED from r13 (verified).
__global__ __launch_bounds__(512) void node_mega(
    const f16* __restrict__ xnode0,
    const f16* __restrict__ hsAllBase,
    const f16* __restrict__ Wt,
    const float* __restrict__ bias,
    const float* __restrict__ out_w, const float* __restrict__ out_b,
    f16* __restrict__ hIO,
    float* __restrict__ c,
    float* __restrict__ outp,
    const int nsteps)
{
    constexpr int H = 128, K = 256, KSTEPS = 8, ROWB = 512, TR = 128;
    constexpr int RTN = TR / 16;
    __shared__ __align__(16) char Xls[TR * ROWB];
    __shared__ float out_part[TR][8];

    const int row0 = blockIdx.x * TR;
    const int t = threadIdx.x;
    const int wv = t >> 6, l = t & 63;
    const int lane15 = l & 15, kgrp = l >> 4;
    const int col = wv * 16 + lane15;

    f16x8 bfrag[4][KSTEPS];
    #pragma unroll
    for (int q = 0; q < 4; ++q) {
        const int colq = q * H + col;
        const f16* bp = Wt + (size_t)colq * K + kgrp * 8;
        #pragma unroll
        for (int ks = 0; ks < KSTEPS; ++ks)
            bfrag[q][ks] = ld_frag16(bp + ks * 32);
    }

    for (int i = t; i < TR * (H / 4); i += 512) {
        const int r = i / (H / 4), j4 = (i % (H / 4)) * 4;
        const uint2 v = *(const uint2*)&hIO[(size_t)(row0 + r) * H + j4];
        const int byte = r * ROWB + ((H * 2 + j4 * 2) ^ ((r & 7) << 4));
        *(uint2*)(Xls + byte) = v;
    }

    const float bi = bias[0 * H + col];
    const float bf = bias[1 * H + col];
    const float bg = bias[2 * H + col];
    const float bo = bias[3 * H + col];
    const float wout = out_w[col];

    for (int s = 0; s < nsteps; ++s) {
        const f16* xin = (s == 0) ? xnode0
                                  : (hsAllBase + (size_t)(s - 1) * EE * 64);
        for (int i = t; i < TR * (H / 4); i += 512) {
            const int r = i / (H / 4), j4 = (i % (H / 4)) * 4;
            const uint2 v = *(const uint2*)&xin[(size_t)(row0 + r) * H + j4];
            const int byte = r * ROWB + ((j4 * 2) ^ ((r & 7) << 4));
            *(uint2*)(Xls + byte) = v;
        }
        __syncthreads();

        const bool lastStep = (s == nsteps - 1);
        #pragma unroll 1
        for (int rt = 0; rt < RTN; ++rt) {
            const int arow = rt * 16 + lane15;
            const char* abase = Xls + arow * ROWB;
            f16x8 afrag[KSTEPS];
            #pragma unroll
            for (int ks = 0; ks < KSTEPS; ++ks) {
                const int byte = (ks * 64 + kgrp * 16) ^ ((arow & 7) << 4);
                afrag[ks] = ld_frag16(abase + byte);
            }
            __syncthreads();
            f32x4 acc[4];
            #pragma unroll
            for (int q = 0; q < 4; ++q)
                #pragma unroll
                for (int r = 0; r < 4; ++r) acc[q][r] = 0.f;
            #pragma unroll
            for (int ks = 0; ks < KSTEPS; ++ks)
                #pragma unroll
                for (int q = 0; q < 4; ++q)
                    acc[q] = __builtin_amdgcn_mfma_f32_16x16x32_f16(
                        afrag[ks], bfrag[q][ks], acc[q], 0, 0, 0);
            #pragma unroll
            for (int reg = 0; reg < 4; ++reg) {
                const int rl = rt * 16 + kgrp * 4 + reg;
                const int grow = row0 + rl;
                const size_t off = (size_t)grow * H + col;
                const float ig = fsigmoid(acc[0][reg] + bi);
                const float fg = fsigmoid(acc[1][reg] + bf);
                const float gg = ftanh(acc[2][reg] + bg);
                const float og = fsigmoid(acc[3][reg] + bo);
                const float c2 = fmaf(fg, c[off], ig * gg);
                const float h2 = og * ftanh(c2);
                c[off] = c2;
                const f16 h16 = (f16)h2;
                const int hbyte = rl * ROWB + ((2 * (H + col)) ^ ((rl & 7) << 4));
                *(f16*)(Xls + hbyte) = h16;
                if (lastStep) hIO[off] = h16;
                float pv = h2 * wout;
                pv += __shfl_xor(pv, 1);
                pv += __shfl_xor(pv, 2);
                pv += __shfl_xor(pv, 4);
                pv += __shfl_xor(pv, 8);
                if (lane15 == 0) out_part[rl][wv] = pv;
            }
        }
        __syncthreads();
        if (t < TR) {
            float sum = out_part[t][0];
            #pragma unroll
            for (int w = 1; w < 8; ++w) sum += out_part[t][w];
            outp[(size_t)s * NN + row0 + t] = sum + out_b[0];
        }
    }
}

// ---------------- CSR build (once; inc is step-invariant) ----------------
__global__ __launch_bounds__(256) void count_kernel(
    const int* __restrict__ inc, int* __restrict__ cnt)
{
    const int slot = blockIdx.x * 256 + threadIdx.x;
    atomicAdd(&cnt[inc[slot]], 1);
}

__global__ __launch_bounds__(1024) void scan_kernel(
    const int* __restrict__ cnt, int* __restrict__ ptr)
{
    __shared__ int sums[1024];
    const int t = threadIdx.x;
    const int base = t * 32;
    int local[32];
    int s = 0;
    #pragma unroll
    for (int i = 0; i < 32; ++i) { local[i] = s; s += cnt[base + i]; }
    sums[t] = s;
    __syncthreads();
    for (int off = 1; off < 1024; off <<= 1) {
        int v = 0;
        if (t >= off) v = sums[t - off];
        __syncthreads();
        sums[t] += v;
        __syncthreads();
    }
    const int excl = sums[t] - s;
    #pragma unroll
    for (int i = 0; i < 32; ++i) ptr[base + i] = excl + local[i];
    if (t == 1023) ptr[NN] = sums[1023];
}

__global__ __launch_bounds__(256) void fill_kernel(
    const int* __restrict__ inc, const int* __restrict__ ptr,
    int* __restrict__ cur, int* __restrict__ rowidx)
{
    const int slot = blockIdx.x * 256 + threadIdx.x;
    const int n = inc[slot];
    const int pos = atomicAdd(&cur[n], 1);
    rowidx[ptr[n] + pos] = slot >> 1;
}

__global__ __launch_bounds__(256) void sort_csr_kernel(
    const int* __restrict__ ptr, int* __restrict__ rowidx)
{
    const int n = blockIdx.x * 256 + threadIdx.x;
    if (n >= NN) return;
    const int beg = ptr[n], end = ptr[n + 1];
    for (int i = beg; i < end - 1; ++i) {
        int mi = i, mv = rowidx[i];
        for (int j = i + 1; j < end; ++j) {
            const int v = rowidx[j];
            if (v < mv) { mv = v; mi = j; }
        }
        if (mi != i) { rowidx[mi] = rowidx[i]; rowidx[i] = mv; }
    }
}

// ---------------- weight transpose+convert (once) ----------------
__global__ __launch_bounds__(256) void transpose_w_kernel(
    const float* __restrict__ Wih, const float* __restrict__ Whh,
    f16* __restrict__ dst, int Hk, int K, int fourH)
{
    const int tid = blockIdx.x * 256 + threadIdx.x;
    if (tid >= K * fourH) return;
    const int col = tid / K, k = tid % K;
    const float v = (k < Hk) ? Wih[(size_t)k * fourH + col]
                             : Whh[(size_t)(k - Hk) * fourH + col];
    dst[tid] = (f16)v;
}

__global__ __launch_bounds__(256) void transpose_ee2_kernel(
    const float* __restrict__ ee_w, f16* __restrict__ dst)
{
    const int tid = blockIdx.x * 256 + threadIdx.x;
    if (tid >= 64 * 192) return;
    const int col = tid / 192, k = tid % 192;
    const int srcrow = (k < 128) ? k : (k - 64);
    dst[tid] = (f16)ee_w[(size_t)srcrow * 64 + col];
}

__global__ __launch_bounds__(256) void cvt_kernel(
    const float* __restrict__ src, f16* __restrict__ dst, int n2)
{
    const int i = blockIdx.x * 256 + threadIdx.x;
    if (i >= n2) return;
    const float2 v = ((const float2*)src)[i];
    ((unsigned int*)dst)[i] = pk2(v.x, v.y);
}

extern "C" void kernel_launch(void* const* d_in, const int* in_sizes, int n_in,
                              void* d_out, int out_size, void* d_ws, size_t ws_size,
                              hipStream_t stream) {
    const float* data_nodes = (const float*)d_in[0];
    const float* data_tE    = (const float*)d_in[1];
    const float* data_sE    = (const float*)d_in[2];
    const float* h_n0 = (const float*)d_in[3];
    const float* c_n0 = (const float*)d_in[4];
    const float* h_t0 = (const float*)d_in[5];
    const float* c_t0 = (const float*)d_in[6];
    const float* h_s0 = (const float*)d_in[7];
    const float* c_s0 = (const float*)d_in[8];
    const int*   inc  = (const int*)d_in[9];
    const float* t_enc_w = (const float*)d_in[10];
    const float* t_enc_b = (const float*)d_in[11];
    const float* t_Wih   = (const float*)d_in[12];
    const float* t_Whh   = (const float*)d_in[13];
    const float* t_b     = (const float*)d_in[14];
    const float* s_enc_w = (const float*)d_in[15];
    const float* s_enc_b = (const float*)d_in[16];
    const float* s_Wih   = (const float*)d_in[17];
    const float* s_Whh   = (const float*)d_in[18];
    const float* s_b     = (const float*)d_in[19];
    const float* n_enc_w = (const float*)d_in[20];
    const float* n_enc_b = (const float*)d_in[21];
    const float* ee_w    = (const float*)d_in[22];
    const float* ee_b    = (const float*)d_in[23];
    const float* n_Wih   = (const float*)d_in[24];
    const float* n_Whh   = (const float*)d_in[25];
    const float* n_b     = (const float*)d_in[26];
    const float* out_w   = (const float*)d_in[27];
    const float* out_b   = (const float*)d_in[28];
    float* out = (float*)d_out;

    // ---- chunk-size selection (same arithmetic as r12/r13 -> same CH) ----
    const size_t slotT = (size_t)NN * 64 * 2;
    const size_t slotS = (size_t)EE * 64 * 2;
    const size_t fixedB =
        (size_t)NN * 128 * 2 +
        (size_t)NN * 128 * 2 +
        (size_t)NN * 128 * 4 +
        (size_t)NN * 64 * 4 +
        (size_t)EE * 64 * 4 +
        ((size_t)256 * 128 + 256 * 128 + 512 * 256 + 64 * 192) * 2 +
        ((size_t)(NN + 8) + 2 * (size_t)EE + NN + NN) * 4 +
        65536;
    int CH = 16;
    while (CH > 1 && fixedB + (size_t)CH * (slotT + slotS) > ws_size) CH >>= 1;

    // ---- workspace layout ----
    char* p = (char*)d_ws;
    f16*  htAll   = (f16*)p;  p += (size_t)CH * slotT;
    f16*  hsAll   = (f16*)p;  p += (size_t)CH * slotS;
    f16*  X0      = (f16*)p;  p += (size_t)NN * 128 * 2;
    f16*  hn16    = (f16*)p;  p += (size_t)NN * 128 * 2;
    float* cn     = (float*)p; p += (size_t)NN * 128 * 4;
    float* ct     = (float*)p; p += (size_t)NN * 64 * 4;
    float* cs     = (float*)p; p += (size_t)EE * 64 * 4;
    f16*  Wt_t    = (f16*)p;  p += (size_t)256 * 128 * 2;
    f16*  Wt_s    = (f16*)p;  p += (size_t)256 * 128 * 2;
    f16*  Wt_n    = (f16*)p;  p += (size_t)512 * 256 * 2;
    f16*  Wt_ee2  = (f16*)p;  p += (size_t)64 * 192 * 2;
    int*  csr_ptr = (int*)p;  p += (size_t)(NN + 8) * 4;
    int*  csr_row = (int*)p;  p += (size_t)2 * EE * 4;
    int*  cnt     = (int*)p;  p += (size_t)NN * 4;
    int*  cur     = (int*)p;  p += (size_t)NN * 4;

    // ---- one-time: state init, weight conversion, CSR ----
    cvt_kernel<<<(NN * 64 / 2 + 255) / 256, 256, 0, stream>>>(
        h_t0, htAll + (size_t)(CH - 1) * NN * 64, NN * 64 / 2);
    cvt_kernel<<<(EE * 64 / 2 + 255) / 256, 256, 0, stream>>>(
        h_s0, hsAll + (size_t)(CH - 1) * EE * 64, EE * 64 / 2);
    cvt_kernel<<<(NN * 128 / 2 + 255) / 256, 256, 0, stream>>>(h_n0, hn16, NN * 128 / 2);
    hipMemcpyAsync(cn, c_n0, (size_t)NN * 128 * 4, hipMemcpyDeviceToDevice, stream);

    transpose_w_kernel<<<(256 * 128 + 255) / 256, 256, 0, stream>>>(t_Wih, t_Whh, Wt_t, 64, 128, 256);
    transpose_w_kernel<<<(256 * 128 + 255) / 256, 256, 0, stream>>>(s_Wih, s_Whh, Wt_s, 64, 128, 256);
    transpose_w_kernel<<<(512 * 256 + 255) / 256, 256, 0, stream>>>(n_Wih, n_Whh, Wt_n, 128, 256, 512);
    transpose_ee2_kernel<<<(64 * 192 + 255) / 256, 256, 0, stream>>>(ee_w, Wt_ee2);

    hipMemsetAsync(cnt, 0, NN * sizeof(int), stream);
    hipMemsetAsync(cur, 0, NN * sizeof(int), stream);
    count_kernel<<<(2 * EE) / 256, 256, 0, stream>>>(inc, cnt);
    scan_kernel<<<1, 1024, 0, stream>>>(cnt, csr_ptr);
    fill_kernel<<<(2 * EE) / 256, 256, 0, stream>>>(inc, csr_ptr, cur, csr_row);
    sort_csr_kernel<<<NN / 256, 256, 0, stream>>>(csr_ptr, csr_row);

    const int edgeGrid = NN / 64 + EE / 64;   // 2560

    for (int c0 = 0; c0 < S_LEN; c0 += CH) {
        edge_mega<<<edgeGrid, 256, 0, stream>>>(
            data_tE + (size_t)c0 * NN * 2, data_sE + (size_t)c0 * EE * 2,
            t_enc_w, t_enc_b, s_enc_w, s_enc_b,
            Wt_t, Wt_s, t_b, s_b,
            htAll, hsAll,
            (c0 == 0) ? c_t0 : ct, (c0 == 0) ? c_s0 : cs, ct, cs,
            CH, (c0 + CH < S_LEN) ? 1 : 0);

        for (int k2 = 0; k2 < CH; ++k2) {
            const int st = c0 + k2;
            f16* xnode_s = (k2 == 0) ? X0 : (hsAll + (size_t)(k2 - 1) * EE * 64);
            gather_embed<<<NN / 64, 256, 0, stream>>>(
                data_nodes + (size_t)st * NN,
                htAll + (size_t)k2 * NN * 64, hsAll + (size_t)k2 * EE * 64,
                csr_ptr, csr_row, n_enc_w, n_enc_b, Wt_ee2, ee_b, xnode_s);
        }

        node_mega<<<NN / 128, 512, 0, stream>>>(
            X0, hsAll, Wt_n, n_b, out_w, out_b, hn16, cn,
            out + (size_t)c0 * NN, CH);
    }
}

// Round 15
// 1069.831 us; speedup vs baseline: 1.6868x; 1.0713x over previous
//
#include <hip/hip_runtime.h>
#include <math.h>

// SRNN: S=16 steps, N=32768 nodes, E=131072 spatial edges.
// f16 MFMA gate GEMMs, B-resident weights. Numerics (kept, 11/11 stable):
//  - edge/node per-thread arithmetic = verified forms (absmax 3.90625e-3)
//  - CSR sorted ascending; agg as hi/lo f16 pair (K=192)
// Structure: edge_mega / per-step gather (alias-safe) / node_mega.
// THIS ROUND: (1) edge CSWZ fixed to spread BOTH epilogue (rl>>2) and
// h-flush (rl&3) access patterns; (2) node_mega c-state LDS-resident across
// the chunk (kills 33.6 MB/step of c traffic; 132 KB LDS, 1 block/CU, all
// 256 blocks co-resident). Values bit-identical.

#define S_LEN 16
#define NN 32768
#define EE 131072

typedef _Float16 f16;
typedef _Float16 f16x8 __attribute__((ext_vector_type(8)));
typedef float f32x4 __attribute__((ext_vector_type(4)));

__device__ __forceinline__ float fsigmoid(float x) {
    return __builtin_amdgcn_rcpf(1.0f + __builtin_amdgcn_exp2f(-1.44269504f * x));
}
__device__ __forceinline__ float ftanh(float x) {
    const float e = __builtin_amdgcn_exp2f(2.88539008f * x);
    return 1.0f - 2.0f * __builtin_amdgcn_rcpf(e + 1.0f);
}

__device__ __forceinline__ unsigned int pk2(float a, float b) {
    union { f16 h[2]; unsigned int u; } x;
    x.h[0] = (f16)a; x.h[1] = (f16)b;
    return x.u;
}

__device__ __forceinline__ f16x8 ld_frag16(const void* p) {
    union { uint4 v; f16x8 f; } x;
    x.v = *(const uint4*)p;
    return x.f;
}

// bank swizzle for LDS-resident state: XOR bits 4-5 with a value distinct
// across BOTH (rl>>2)&3 (epilogue: kgrp) and rl&3 (flush: row low bits).
#define CSWZ(rl) (((((rl) >> 2) & 3) ^ ((rl) & 3)) << 4)

// ---------------- multi-step edge LSTM (temporal + spatial), H=64, TR=64 ----
__global__ __launch_bounds__(256) void edge_mega(
    const float* __restrict__ xT, const float* __restrict__ xS,
    const float* __restrict__ t_enc_w, const float* __restrict__ t_enc_b,
    const float* __restrict__ s_enc_w, const float* __restrict__ s_enc_b,
    const f16* __restrict__ WtT, const f16* __restrict__ WtS,
    const float* __restrict__ biasT, const float* __restrict__ biasS,
    f16* __restrict__ htAll, f16* __restrict__ hsAll,
    const float* __restrict__ cInT, const float* __restrict__ cInS,
    float* __restrict__ cOutT, float* __restrict__ cOutS,
    const int nsteps, const int writeC)
{
    constexpr int H = 64, K = 128, KSTEPS = 4, ROWB = 256, TR = 64;
    constexpr int RTN = TR / 16;
    __shared__ __align__(16) char Xls[TR * ROWB];   // 16 KB
    __shared__ __align__(16) float cls[TR * H];     // 16 KB (swizzled)
    __shared__ __align__(16) f16 hnx[TR * H];       // 8 KB  (swizzled)

    const int bT = NN / TR;
    const bool isT = (int)blockIdx.x < bT;
    const int row0 = (isT ? blockIdx.x : blockIdx.x - bT) * TR;
    const float* xbase = isT ? xT : xS;
    const size_t xstep = (size_t)(isT ? NN : EE) * 2;
    const float* enc_w = isT ? t_enc_w : s_enc_w;
    const float* enc_b = isT ? t_enc_b : s_enc_b;
    const f16*   Wt    = isT ? WtT : WtS;
    const float* bias  = isT ? biasT : biasS;
    f16* hAll = isT ? htAll : hsAll;
    const size_t hstep = (size_t)(isT ? NN : EE) * 64;
    const float* cIn  = (isT ? cInT : cInS) + (size_t)row0 * H;
    float*       cOut = (isT ? cOutT : cOutS) + (size_t)row0 * H;

    const int t = threadIdx.x;
    const int wv = t >> 6, l = t & 63;
    const int lane15 = l & 15, kgrp = l >> 4;
    const int col = wv * 16 + lane15;

    f16x8 bfrag[4][KSTEPS];
    #pragma unroll
    for (int q = 0; q < 4; ++q) {
        const int colq = q * H + col;
        const f16* bp = Wt + (size_t)colq * K + kgrp * 8;
        #pragma unroll
        for (int ks = 0; ks < KSTEPS; ++ks)
            bfrag[q][ks] = ld_frag16(bp + ks * 32);
    }

    // stage c (swizzled) and h-init (slot nsteps-1) into panel
    for (int i = t; i < TR * H; i += 256) {
        const int r = i >> 6, j = i & 63;
        cls[(r << 6) + (j ^ CSWZ(r))] = cIn[i];
    }
    {
        const f16* hInit = hAll + (size_t)(nsteps - 1) * hstep + (size_t)row0 * H;
        for (int i = t; i < TR * (H / 4); i += 256) {
            const int r = i / (H / 4), j4 = (i % (H / 4)) * 4;
            const uint2 v = *(const uint2*)&hInit[(size_t)r * H + j4];
            const int byte = r * ROWB + ((H * 2 + j4 * 2) ^ ((r & 7) << 4));
            *(uint2*)(Xls + byte) = v;
        }
    }

    const float bi = bias[0 * H + col];
    const float bf = bias[1 * H + col];
    const float bg = bias[2 * H + col];
    const float bo = bias[3 * H + col];

    // x prefetch registers for the 8 staging iterations of this thread
    float xr0[8], xr1[8];
    {
        const float* xf = xbase;
        #pragma unroll
        for (int k2 = 0; k2 < 8; ++k2) {
            const int r = (t + k2 * 256) >> 5;
            xr0[k2] = xf[(size_t)(row0 + r) * 2 + 0];
            xr1[k2] = xf[(size_t)(row0 + r) * 2 + 1];
        }
    }

    for (int s = 0; s < nsteps; ++s) {
        // stage x-enc for step s from prefetched regs (panel cols 0..63)
        #pragma unroll
        for (int k2 = 0; k2 < 8; ++k2) {
            const int i = t + k2 * 256;
            const int r = i >> 5, j2 = (i & 31) * 2;
            const float x0 = xr0[k2];
            const float x1 = xr1[k2];
            const float e0 = fmaxf(0.f, fmaf(x0, enc_w[j2],     fmaf(x1, enc_w[H + j2],     enc_b[j2])));
            const float e1 = fmaxf(0.f, fmaf(x0, enc_w[j2 + 1], fmaf(x1, enc_w[H + j2 + 1], enc_b[j2 + 1])));
            const int byte = r * ROWB + ((j2 * 2) ^ ((r & 7) << 4));
            *(unsigned int*)(Xls + byte) = pk2(e0, e1);
        }
        __syncthreads();

        // prefetch next step's x (latency hides under MFMA/epilogue)
        if (s + 1 < nsteps) {
            const float* xf = xbase + (size_t)(s + 1) * xstep;
            #pragma unroll
            for (int k2 = 0; k2 < 8; ++k2) {
                const int r = (t + k2 * 256) >> 5;
                xr0[k2] = xf[(size_t)(row0 + r) * 2 + 0];
                xr1[k2] = xf[(size_t)(row0 + r) * 2 + 1];
            }
        }

        #pragma unroll
        for (int rt = 0; rt < RTN; ++rt) {
            const int arow = rt * 16 + lane15;
            const char* abase = Xls + arow * ROWB;
            f16x8 afrag[KSTEPS];
            #pragma unroll
            for (int ks = 0; ks < KSTEPS; ++ks) {
                const int byte = (ks * 64 + kgrp * 16) ^ ((arow & 7) << 4);
                afrag[ks] = ld_frag16(abase + byte);
            }
            f32x4 acc[4];
            #pragma unroll
            for (int q = 0; q < 4; ++q)
                #pragma unroll
                for (int r = 0; r < 4; ++r) acc[q][r] = 0.f;
            #pragma unroll
            for (int ks = 0; ks < KSTEPS; ++ks)
                #pragma unroll
                for (int q = 0; q < 4; ++q)
                    acc[q] = __builtin_amdgcn_mfma_f32_16x16x32_f16(
                        afrag[ks], bfrag[q][ks], acc[q], 0, 0, 0);
            #pragma unroll
            for (int reg = 0; reg < 4; ++reg) {
                const int rl = rt * 16 + kgrp * 4 + reg;
                const int sc = (rl << 6) + (col ^ CSWZ(rl));
                const float ig = fsigmoid(acc[0][reg] + bi);
                const float fg = fsigmoid(acc[1][reg] + bf);
                const float gg = ftanh(acc[2][reg] + bg);
                const float og = fsigmoid(acc[3][reg] + bo);
                const float c2 = fmaf(fg, cls[sc], ig * gg);
                cls[sc] = c2;
                hnx[sc] = (f16)(og * ftanh(c2));
            }
        }
        __syncthreads();

        // flush h: hnx (swizzled) -> global slot s (coalesced) AND panel h-half
        f16* hOut = hAll + (size_t)s * hstep + (size_t)row0 * H;
        for (int i = t; i < TR * (H / 4); i += 256) {
            const int r = i / (H / 4), j4 = (i % (H / 4)) * 4;
            const uint2 v = *(const uint2*)&hnx[(r << 6) + (j4 ^ CSWZ(r))];
            *(uint2*)&hOut[(size_t)r * H + j4] = v;
            const int byte = r * ROWB + ((H * 2 + j4 * 2) ^ ((r & 7) << 4));
            *(uint2*)(Xls + byte) = v;
        }
    }

    if (writeC) {
        for (int i = t; i < TR * H; i += 256) {
            const int r = i >> 6, j = i & 63;
            cOut[i] = cls[(r << 6) + (j ^ CSWZ(r))];
        }
    }
}

// ---------------- gather + embed fused (K=192: ht | agg_hi | agg_lo) --------
// UNCHANGED (alias-safe: one dispatch per step).
__global__ __launch_bounds__(256) void gather_embed(
    const float* __restrict__ xn,
    const f16* __restrict__ ht, const f16* __restrict__ hs,
    const int* __restrict__ ptr, const int* __restrict__ rowidx,
    const float* __restrict__ n_enc_w, const float* __restrict__ n_enc_b,
    const f16* __restrict__ Wt_ee2,  // [64][192]
    const float* __restrict__ ee_b,
    f16* __restrict__ xnode)
{
    constexpr int TR = 64, K = 192, KSTEPS = 6, ROWB = 384;
    __shared__ __align__(16) char Xls[TR * ROWB];
    const int row0 = blockIdx.x * TR;
    const int t = threadIdx.x;
    const int wv = t >> 6, l = t & 63;
    const int lane15 = l & 15, kgrp = l >> 4;

    const int col = wv * 16 + lane15;
    f16x8 bfrag[KSTEPS];
    {
        const f16* bp = Wt_ee2 + (size_t)col * K + kgrp * 8;
        #pragma unroll
        for (int ks = 0; ks < KSTEPS; ++ks) bfrag[ks] = ld_frag16(bp + ks * 32);
    }

    for (int i = t; i < TR * 16; i += 256) {
        const int r = i / 16, j4 = (i % 16) * 4;
        const uint2 v = *(const uint2*)&ht[(size_t)(row0 + r) * 64 + j4];
        const int byte = r * ROWB + ((j4 * 2) ^ ((r & 7) << 4));
        *(uint2*)(Xls + byte) = v;
    }

    {
        const int r = t >> 2, q = t & 3;
        const int n = row0 + r;
        const int beg = ptr[n], end = ptr[n + 1];
        const unsigned int* hs32 = (const unsigned int*)hs;
        float acc[16];
        #pragma unroll
        for (int j = 0; j < 16; ++j) acc[j] = 0.f;
        for (int i = beg; i < end; ++i) {
            const int e = rowidx[i];
            const unsigned int* ep = hs32 + (size_t)e * 32 + q * 8;
            #pragma unroll
            for (int j = 0; j < 8; ++j) {
                union { unsigned int u; f16 h[2]; } v;
                v.u = ep[j];
                acc[2 * j]     += (float)v.h[0];
                acc[2 * j + 1] += (float)v.h[1];
            }
        }
        #pragma unroll
        for (int j = 0; j < 8; ++j) {
            const float a0 = acc[2 * j], a1 = acc[2 * j + 1];
            const f16 h0 = (f16)a0, h1 = (f16)a1;
            const f16 l0 = (f16)(a0 - (float)h0), l1 = (f16)(a1 - (float)h1);
            union { f16 h[2]; unsigned int u; } hi, lo;
            hi.h[0] = h0; hi.h[1] = h1;
            lo.h[0] = l0; lo.h[1] = l1;
            const int bhi = r * ROWB + ((128 + q * 32 + j * 4) ^ ((r & 7) << 4));
            const int blo = r * ROWB + ((256 + q * 32 + j * 4) ^ ((r & 7) << 4));
            *(unsigned int*)(Xls + bhi) = hi.u;
            *(unsigned int*)(Xls + blo) = lo.u;
        }
    }
    __syncthreads();

    const float bb = ee_b[col];
    #pragma unroll
    for (int rt = 0; rt < TR / 16; ++rt) {
        const int arow = rt * 16 + lane15;
        const char* abase = Xls + arow * ROWB;
        f16x8 afrag[KSTEPS];
        #pragma unroll
        for (int ks = 0; ks < KSTEPS; ++ks) {
            const int byte = (ks * 64 + kgrp * 16) ^ ((arow & 7) << 4);
            afrag[ks] = ld_frag16(abase + byte);
        }
        f32x4 acc;
        #pragma unroll
        for (int r = 0; r < 4; ++r) acc[r] = 0.f;
        #pragma unroll
        for (int ks = 0; ks < KSTEPS; ++ks)
            acc = __builtin_amdgcn_mfma_f32_16x16x32_f16(afrag[ks], bfrag[ks], acc, 0, 0, 0);
        #pragma unroll
        for (int reg = 0; reg < 4; ++reg) {
            const int grow = row0 + rt * 16 + kgrp * 4 + reg;
            xnode[(size_t)grow * 128 + 64 + col] = (f16)fmaxf(0.f, acc[reg] + bb);
        }
    }

    for (int i = t; i < TR * 32; i += 256) {
        const int r = i >> 5, j2 = (i & 31) * 2;
        const int grow = row0 + r;
        const float x = xn[grow];
        const float e0 = fmaxf(0.f, fmaf(x, n_enc_w[j2],     n_enc_b[j2]));
        const float e1 = fmaxf(0.f, fmaf(x, n_enc_w[j2 + 1], n_enc_b[j2 + 1]));
        *(unsigned int*)&xnode[(size_t)grow * 128 + j2] = pk2(e0, e1);
    }
}

// ---------------- multi-step node LSTM + fused output projection ------------
// NEW: c-state LDS-resident (swizzled) across the chunk; global c touched
// only at chunk boundaries. 132 KB LDS -> 1 block/CU, 256 blocks co-resident.
__global__ __launch_bounds__(512) void node_mega(
    const f16* __restrict__ xnode0,
    const f16* __restrict__ hsAllBase,
    const f16* __restrict__ Wt,
    const float* __restrict__ bias,
    const float* __restrict__ out_w, const float* __restrict__ out_b,
    f16* __restrict__ hIO,
    float* __restrict__ c,
    float* __restrict__ outp,
    const int nsteps)
{
    constexpr int H = 128, K = 256, KSTEPS = 8, ROWB = 512, TR = 128;
    constexpr int RTN = TR / 16;
    __shared__ __align__(16) char Xls[TR * ROWB];   // 64 KB
    __shared__ __align__(16) float clsN[TR * H];    // 64 KB (swizzled)
    __shared__ float out_part[TR][8];               // 4 KB

    const int row0 = blockIdx.x * TR;
    const int t = threadIdx.x;
    const int wv = t >> 6, l = t & 63;
    const int lane15 = l & 15, kgrp = l >> 4;
    const int col = wv * 16 + lane15;

    f16x8 bfrag[4][KSTEPS];
    #pragma unroll
    for (int q = 0; q < 4; ++q) {
        const int colq = q * H + col;
        const f16* bp = Wt + (size_t)colq * K + kgrp * 8;
        #pragma unroll
        for (int ks = 0; ks < KSTEPS; ++ks)
            bfrag[q][ks] = ld_frag16(bp + ks * 32);
    }

    // stage h (K cols 128..255) and c (swizzled) from global once
    for (int i = t; i < TR * (H / 4); i += 512) {
        const int r = i >> 5, j4 = (i & 31) * 4;
        const uint2 v = *(const uint2*)&hIO[(size_t)(row0 + r) * H + j4];
        const int byte = r * ROWB + ((H * 2 + j4 * 2) ^ ((r & 7) << 4));
        *(uint2*)(Xls + byte) = v;
        const float4 cv = *(const float4*)&c[(size_t)(row0 + r) * H + j4];
        *(float4*)&clsN[r * H + (j4 ^ CSWZ(r))] = cv;
    }

    const float bi = bias[0 * H + col];
    const float bf = bias[1 * H + col];
    const float bg = bias[2 * H + col];
    const float bo = bias[3 * H + col];
    const float wout = out_w[col];

    for (int s = 0; s < nsteps; ++s) {
        const f16* xin = (s == 0) ? xnode0
                                  : (hsAllBase + (size_t)(s - 1) * EE * 64);
        for (int i = t; i < TR * (H / 4); i += 512) {
            const int r = i >> 5, j4 = (i & 31) * 4;
            const uint2 v = *(const uint2*)&xin[(size_t)(row0 + r) * H + j4];
            const int byte = r * ROWB + ((j4 * 2) ^ ((r & 7) << 4));
            *(uint2*)(Xls + byte) = v;
        }
        __syncthreads();

        const bool lastStep = (s == nsteps - 1);
        #pragma unroll 1
        for (int rt = 0; rt < RTN; ++rt) {
            const int arow = rt * 16 + lane15;
            const char* abase = Xls + arow * ROWB;
            f16x8 afrag[KSTEPS];
            #pragma unroll
            for (int ks = 0; ks < KSTEPS; ++ks) {
                const int byte = (ks * 64 + kgrp * 16) ^ ((arow & 7) << 4);
                afrag[ks] = ld_frag16(abase + byte);
            }
            __syncthreads();
            f32x4 acc[4];
            #pragma unroll
            for (int q = 0; q < 4; ++q)
                #pragma unroll
                for (int r = 0; r < 4; ++r) acc[q][r] = 0.f;
            #pragma unroll
            for (int ks = 0; ks < KSTEPS; ++ks)
                #pragma unroll
                for (int q = 0; q < 4; ++q)
                    acc[q] = __builtin_amdgcn_mfma_f32_16x16x32_f16(
                        afrag[ks], bfrag[q][ks], acc[q], 0, 0, 0);
            #pragma unroll
            for (int reg = 0; reg < 4; ++reg) {
                const int rl = rt * 16 + kgrp * 4 + reg;
                const int grow = row0 + rl;
                const size_t off = (size_t)grow * H + col;
                const int scn = rl * H + (col ^ CSWZ(rl));
                const float ig = fsigmoid(acc[0][reg] + bi);
                const float fg = fsigmoid(acc[1][reg] + bf);
                const float gg = ftanh(acc[2][reg] + bg);
                const float og = fsigmoid(acc[3][reg] + bo);
                const float c2 = fmaf(fg, clsN[scn], ig * gg);
                const float h2 = og * ftanh(c2);
                clsN[scn] = c2;
                const f16 h16 = (f16)h2;
                const int hbyte = rl * ROWB + ((2 * (H + col)) ^ ((rl & 7) << 4));
                *(f16*)(Xls + hbyte) = h16;
                if (lastStep) hIO[off] = h16;
                float pv = h2 * wout;
                pv += __shfl_xor(pv, 1);
                pv += __shfl_xor(pv, 2);
                pv += __shfl_xor(pv, 4);
                pv += __shfl_xor(pv, 8);
                if (lane15 == 0) out_part[rl][wv] = pv;
            }
        }
        __syncthreads();
        if (t < TR) {
            float sum = out_part[t][0];
            #pragma unroll
            for (int w = 1; w < 8; ++w) sum += out_part[t][w];
            outp[(size_t)s * NN + row0 + t] = sum + out_b[0];
        }
    }

    // write c back once per chunk (clsN stable after the final barrier above)
    for (int i = t; i < TR * (H / 4); i += 512) {
        const int r = i >> 5, j4 = (i & 31) * 4;
        *(float4*)&c[(size_t)(row0 + r) * H + j4] =
            *(const float4*)&clsN[r * H + (j4 ^ CSWZ(r))];
    }
}

// ---------------- CSR build (once; inc is step-invariant) ----------------
__global__ __launch_bounds__(256) void count_kernel(
    const int* __restrict__ inc, int* __restrict__ cnt)
{
    const int slot = blockIdx.x * 256 + threadIdx.x;
    atomicAdd(&cnt[inc[slot]], 1);
}

__global__ __launch_bounds__(1024) void scan_kernel(
    const int* __restrict__ cnt, int* __restrict__ ptr)
{
    __shared__ int sums[1024];
    const int t = threadIdx.x;
    const int base = t * 32;
    int local[32];
    int s = 0;
    #pragma unroll
    for (int i = 0; i < 32; ++i) { local[i] = s; s += cnt[base + i]; }
    sums[t] = s;
    __syncthreads();
    for (int off = 1; off < 1024; off <<= 1) {
        int v = 0;
        if (t >= off) v = sums[t - off];
        __syncthreads();
        sums[t] += v;
        __syncthreads();
    }
    const int excl = sums[t] - s;
    #pragma unroll
    for (int i = 0; i < 32; ++i) ptr[base + i] = excl + local[i];
    if (t == 1023) ptr[NN] = sums[1023];
}

__global__ __launch_bounds__(256) void fill_kernel(
    const int* __restrict__ inc, const int* __restrict__ ptr,
    int* __restrict__ cur, int* __restrict__ rowidx)
{
    const int slot = blockIdx.x * 256 + threadIdx.x;
    const int n = inc[slot];
    const int pos = atomicAdd(&cur[n], 1);
    rowidx[ptr[n] + pos] = slot >> 1;
}

__global__ __launch_bounds__(256) void sort_csr_kernel(
    const int* __restrict__ ptr, int* __restrict__ rowidx)
{
    const int n = blockIdx.x * 256 + threadIdx.x;
    if (n >= NN) return;
    const int beg = ptr[n], end = ptr[n + 1];
    for (int i = beg; i < end - 1; ++i) {
        int mi = i, mv = rowidx[i];
        for (int j = i + 1; j < end; ++j) {
            const int v = rowidx[j];
            if (v < mv) { mv = v; mi = j; }
        }
        if (mi != i) { rowidx[mi] = rowidx[i]; rowidx[i] = mv; }
    }
}

// ---------------- weight transpose+convert (once) ----------------
__global__ __launch_bounds__(256) void transpose_w_kernel(
    const float* __restrict__ Wih, const float* __restrict__ Whh,
    f16* __restrict__ dst, int Hk, int K, int fourH)
{
    const int tid = blockIdx.x * 256 + threadIdx.x;
    if (tid >= K * fourH) return;
    const int col = tid / K, k = tid % K;
    const float v = (k < Hk) ? Wih[(size_t)k * fourH + col]
                             : Whh[(size_t)(k - Hk) * fourH + col];
    dst[tid] = (f16)v;
}

__global__ __launch_bounds__(256) void transpose_ee2_kernel(
    const float* __restrict__ ee_w, f16* __restrict__ dst)
{
    const int tid = blockIdx.x * 256 + threadIdx.x;
    if (tid >= 64 * 192) return;
    const int col = tid / 192, k = tid % 192;
    const int srcrow = (k < 128) ? k : (k - 64);
    dst[tid] = (f16)ee_w[(size_t)srcrow * 64 + col];
}

__global__ __launch_bounds__(256) void cvt_kernel(
    const float* __restrict__ src, f16* __restrict__ dst, int n2)
{
    const int i = blockIdx.x * 256 + threadIdx.x;
    if (i >= n2) return;
    const float2 v = ((const float2*)src)[i];
    ((unsigned int*)dst)[i] = pk2(v.x, v.y);
}

extern "C" void kernel_launch(void* const* d_in, const int* in_sizes, int n_in,
                              void* d_out, int out_size, void* d_ws, size_t ws_size,
                              hipStream_t stream) {
    const float* data_nodes = (const float*)d_in[0];
    const float* data_tE    = (const float*)d_in[1];
    const float* data_sE    = (const float*)d_in[2];
    const float* h_n0 = (const float*)d_in[3];
    const float* c_n0 = (const float*)d_in[4];
    const float* h_t0 = (const float*)d_in[5];
    const float* c_t0 = (const float*)d_in[6];
    const float* h_s0 = (const float*)d_in[7];
    const float* c_s0 = (const float*)d_in[8];
    const int*   inc  = (const int*)d_in[9];
    const float* t_enc_w = (const float*)d_in[10];
    const float* t_enc_b = (const float*)d_in[11];
    const float* t_Wih   = (const float*)d_in[12];
    const float* t_Whh   = (const float*)d_in[13];
    const float* t_b     = (const float*)d_in[14];
    const float* s_enc_w = (const float*)d_in[15];
    const float* s_enc_b = (const float*)d_in[16];
    const float* s_Wih   = (const float*)d_in[17];
    const float* s_Whh   = (const float*)d_in[18];
    const float* s_b     = (const float*)d_in[19];
    const float* n_enc_w = (const float*)d_in[20];
    const float* n_enc_b = (const float*)d_in[21];
    const float* ee_w    = (const float*)d_in[22];
    const float* ee_b    = (const float*)d_in[23];
    const float* n_Wih   = (const float*)d_in[24];
    const float* n_Whh   = (const float*)d_in[25];
    const float* n_b     = (const float*)d_in[26];
    const float* out_w   = (const float*)d_in[27];
    const float* out_b   = (const float*)d_in[28];
    float* out = (float*)d_out;

    // ---- chunk-size selection (same arithmetic as r12-r14 -> same CH) ----
    const size_t slotT = (size_t)NN * 64 * 2;
    const size_t slotS = (size_t)EE * 64 * 2;
    const size_t fixedB =
        (size_t)NN * 128 * 2 +
        (size_t)NN * 128 * 2 +
        (size_t)NN * 128 * 4 +
        (size_t)NN * 64 * 4 +
        (size_t)EE * 64 * 4 +
        ((size_t)256 * 128 + 256 * 128 + 512 * 256 + 64 * 192) * 2 +
        ((size_t)(NN + 8) + 2 * (size_t)EE + NN + NN) * 4 +
        65536;
    int CH = 16;
    while (CH > 1 && fixedB + (size_t)CH * (slotT + slotS) > ws_size) CH >>= 1;

    // ---- workspace layout ----
    char* p = (char*)d_ws;
    f16*  htAll   = (f16*)p;  p += (size_t)CH * slotT;
    f16*  hsAll   = (f16*)p;  p += (size_t)CH * slotS;
    f16*  X0      = (f16*)p;  p += (size_t)NN * 128 * 2;
    f16*  hn16    = (f16*)p;  p += (size_t)NN * 128 * 2;
    float* cn     = (float*)p; p += (size_t)NN * 128 * 4;
    float* ct     = (float*)p; p += (size_t)NN * 64 * 4;
    float* cs     = (float*)p; p += (size_t)EE * 64 * 4;
    f16*  Wt_t    = (f16*)p;  p += (size_t)256 * 128 * 2;
    f16*  Wt_s    = (f16*)p;  p += (size_t)256 * 128 * 2;
    f16*  Wt_n    = (f16*)p;  p += (size_t)512 * 256 * 2;
    f16*  Wt_ee2  = (f16*)p;  p += (size_t)64 * 192 * 2;
    int*  csr_ptr = (int*)p;  p += (size_t)(NN + 8) * 4;
    int*  csr_row = (int*)p;  p += (size_t)2 * EE * 4;
    int*  cnt     = (int*)p;  p += (size_t)NN * 4;
    int*  cur     = (int*)p;  p += (size_t)NN * 4;

    // ---- one-time: state init, weight conversion, CSR ----
    cvt_kernel<<<(NN * 64 / 2 + 255) / 256, 256, 0, stream>>>(
        h_t0, htAll + (size_t)(CH - 1) * NN * 64, NN * 64 / 2);
    cvt_kernel<<<(EE * 64 / 2 + 255) / 256, 256, 0, stream>>>(
        h_s0, hsAll + (size_t)(CH - 1) * EE * 64, EE * 64 / 2);
    cvt_kernel<<<(NN * 128 / 2 + 255) / 256, 256, 0, stream>>>(h_n0, hn16, NN * 128 / 2);
    hipMemcpyAsync(cn, c_n0, (size_t)NN * 128 * 4, hipMemcpyDeviceToDevice, stream);

    transpose_w_kernel<<<(256 * 128 + 255) / 256, 256, 0, stream>>>(t_Wih, t_Whh, Wt_t, 64, 128, 256);
    transpose_w_kernel<<<(256 * 128 + 255) / 256, 256, 0, stream>>>(s_Wih, s_Whh, Wt_s, 64, 128, 256);
    transpose_w_kernel<<<(512 * 256 + 255) / 256, 256, 0, stream>>>(n_Wih, n_Whh, Wt_n, 128, 256, 512);
    transpose_ee2_kernel<<<(64 * 192 + 255) / 256, 256, 0, stream>>>(ee_w, Wt_ee2);

    hipMemsetAsync(cnt, 0, NN * sizeof(int), stream);
    hipMemsetAsync(cur, 0, NN * sizeof(int), stream);
    count_kernel<<<(2 * EE) / 256, 256, 0, stream>>>(inc, cnt);
    scan_kernel<<<1, 1024, 0, stream>>>(cnt, csr_ptr);
    fill_kernel<<<(2 * EE) / 256, 256, 0, stream>>>(inc, csr_ptr, cur, csr_row);
    sort_csr_kernel<<<NN / 256, 256, 0, stream>>>(csr_ptr, csr_row);

    const int edgeGrid = NN / 64 + EE / 64;   // 2560

    for (int c0 = 0; c0 < S_LEN; c0 += CH) {
        edge_mega<<<edgeGrid, 256, 0, stream>>>(
            data_tE + (size_t)c0 * NN * 2, data_sE + (size_t)c0 * EE * 2,
            t_enc_w, t_enc_b, s_enc_w, s_enc_b,
            Wt_t, Wt_s, t_b, s_b,
            htAll, hsAll,
            (c0 == 0) ? c_t0 : ct, (c0 == 0) ? c_s0 : cs, ct, cs,
            CH, (c0 + CH < S_LEN) ? 1 : 0);

        for (int k2 = 0; k2 < CH; ++k2) {
            const int st = c0 + k2;
            f16* xnode_s = (k2 == 0) ? X0 : (hsAll + (size_t)(k2 - 1) * EE * 64);
            gather_embed<<<NN / 64, 256, 0, stream>>>(
                data_nodes + (size_t)st * NN,
                htAll + (size_t)k2 * NN * 64, hsAll + (size_t)k2 * EE * 64,
                csr_ptr, csr_row, n_enc_w, n_enc_b, Wt_ee2, ee_b, xnode_s);
        }

        node_mega<<<NN / 128, 512, 0, stream>>>(
            X0, hsAll, Wt_n, n_b, out_w, out_b, hn16, cn,
            out + (size_t)c0 * NN, CH);
    }
}

// Round 16
// 1064.983 us; speedup vs baseline: 1.6945x; 1.0046x over previous
//
#include <hip/hip_runtime.h>
#include <math.h>

// SRNN: S=16 steps, N=32768 nodes, E=131072 spatial edges.
// f16 MFMA gate GEMMs, B-resident weights. Numerics (kept, 12/12 stable):
//  - edge/node per-thread arithmetic = verified forms (absmax 3.90625e-3)
//  - CSR sorted ascending; agg as hi/lo f16 pair (K=192, MFMA order ks 0..5)
// Structure: edge_mega / per-step gather (alias-safe) / node_mega (c in LDS).
// THIS ROUND: (1) gather_embed reads ht A-frags DIRECT from global (L2-hot),
// panel 24->16 KB -> 10 blocks/CU for the latency-bound CSR loop;
// (2) node_mega x register-prefetch (hides 8MB/step staging under MFMA).
// Values bit-identical.

#define S_LEN 16
#define NN 32768
#define EE 131072

typedef _Float16 f16;
typedef _Float16 f16x8 __attribute__((ext_vector_type(8)));
typedef float f32x4 __attribute__((ext_vector_type(4)));

__device__ __forceinline__ float fsigmoid(float x) {
    return __builtin_amdgcn_rcpf(1.0f + __builtin_amdgcn_exp2f(-1.44269504f * x));
}
__device__ __forceinline__ float ftanh(float x) {
    const float e = __builtin_amdgcn_exp2f(2.88539008f * x);
    return 1.0f - 2.0f * __builtin_amdgcn_rcpf(e + 1.0f);
}

__device__ __forceinline__ unsigned int pk2(float a, float b) {
    union { f16 h[2]; unsigned int u; } x;
    x.h[0] = (f16)a; x.h[1] = (f16)b;
    return x.u;
}

__device__ __forceinline__ f16x8 ld_frag16(const void* p) {
    union { uint4 v; f16x8 f; } x;
    x.v = *(const uint4*)p;
    return x.f;
}

#define CSWZ(rl) (((((rl) >> 2) & 3) ^ ((rl) & 3)) << 4)

// ---------------- multi-step edge LSTM (temporal + spatial), H=64, TR=64 ----
// UNCHANGED from r15 (verified).
__global__ __launch_bounds__(256) void edge_mega(
    const float* __restrict__ xT, const float* __restrict__ xS,
    const float* __restrict__ t_enc_w, const float* __restrict__ t_enc_b,
    const float* __restrict__ s_enc_w, const float* __restrict__ s_enc_b,
    const f16* __restrict__ WtT, const f16* __restrict__ WtS,
    const float* __restrict__ biasT, const float* __restrict__ biasS,
    f16* __restrict__ htAll, f16* __restrict__ hsAll,
    const float* __restrict__ cInT, const float* __restrict__ cInS,
    float* __restrict__ cOutT, float* __restrict__ cOutS,
    const int nsteps, const int writeC)
{
    constexpr int H = 64, K = 128, KSTEPS = 4, ROWB = 256, TR = 64;
    constexpr int RTN = TR / 16;
    __shared__ __align__(16) char Xls[TR * ROWB];
    __shared__ __align__(16) float cls[TR * H];
    __shared__ __align__(16) f16 hnx[TR * H];

    const int bT = NN / TR;
    const bool isT = (int)blockIdx.x < bT;
    const int row0 = (isT ? blockIdx.x : blockIdx.x - bT) * TR;
    const float* xbase = isT ? xT : xS;
    const size_t xstep = (size_t)(isT ? NN : EE) * 2;
    const float* enc_w = isT ? t_enc_w : s_enc_w;
    const float* enc_b = isT ? t_enc_b : s_enc_b;
    const f16*   Wt    = isT ? WtT : WtS;
    const float* bias  = isT ? biasT : biasS;
    f16* hAll = isT ? htAll : hsAll;
    const size_t hstep = (size_t)(isT ? NN : EE) * 64;
    const float* cIn  = (isT ? cInT : cInS) + (size_t)row0 * H;
    float*       cOut = (isT ? cOutT : cOutS) + (size_t)row0 * H;

    const int t = threadIdx.x;
    const int wv = t >> 6, l = t & 63;
    const int lane15 = l & 15, kgrp = l >> 4;
    const int col = wv * 16 + lane15;

    f16x8 bfrag[4][KSTEPS];
    #pragma unroll
    for (int q = 0; q < 4; ++q) {
        const int colq = q * H + col;
        const f16* bp = Wt + (size_t)colq * K + kgrp * 8;
        #pragma unroll
        for (int ks = 0; ks < KSTEPS; ++ks)
            bfrag[q][ks] = ld_frag16(bp + ks * 32);
    }

    for (int i = t; i < TR * H; i += 256) {
        const int r = i >> 6, j = i & 63;
        cls[(r << 6) + (j ^ CSWZ(r))] = cIn[i];
    }
    {
        const f16* hInit = hAll + (size_t)(nsteps - 1) * hstep + (size_t)row0 * H;
        for (int i = t; i < TR * (H / 4); i += 256) {
            const int r = i / (H / 4), j4 = (i % (H / 4)) * 4;
            const uint2 v = *(const uint2*)&hInit[(size_t)r * H + j4];
            const int byte = r * ROWB + ((H * 2 + j4 * 2) ^ ((r & 7) << 4));
            *(uint2*)(Xls + byte) = v;
        }
    }

    const float bi = bias[0 * H + col];
    const float bf = bias[1 * H + col];
    const float bg = bias[2 * H + col];
    const float bo = bias[3 * H + col];

    float xr0[8], xr1[8];
    {
        const float* xf = xbase;
        #pragma unroll
        for (int k2 = 0; k2 < 8; ++k2) {
            const int r = (t + k2 * 256) >> 5;
            xr0[k2] = xf[(size_t)(row0 + r) * 2 + 0];
            xr1[k2] = xf[(size_t)(row0 + r) * 2 + 1];
        }
    }

    for (int s = 0; s < nsteps; ++s) {
        #pragma unroll
        for (int k2 = 0; k2 < 8; ++k2) {
            const int i = t + k2 * 256;
            const int r = i >> 5, j2 = (i & 31) * 2;
            const float x0 = xr0[k2];
            const float x1 = xr1[k2];
            const float e0 = fmaxf(0.f, fmaf(x0, enc_w[j2],     fmaf(x1, enc_w[H + j2],     enc_b[j2])));
            const float e1 = fmaxf(0.f, fmaf(x0, enc_w[j2 + 1], fmaf(x1, enc_w[H + j2 + 1], enc_b[j2 + 1])));
            const int byte = r * ROWB + ((j2 * 2) ^ ((r & 7) << 4));
            *(unsigned int*)(Xls + byte) = pk2(e0, e1);
        }
        __syncthreads();

        if (s + 1 < nsteps) {
            const float* xf = xbase + (size_t)(s + 1) * xstep;
            #pragma unroll
            for (int k2 = 0; k2 < 8; ++k2) {
                const int r = (t + k2 * 256) >> 5;
                xr0[k2] = xf[(size_t)(row0 + r) * 2 + 0];
                xr1[k2] = xf[(size_t)(row0 + r) * 2 + 1];
            }
        }

        #pragma unroll
        for (int rt = 0; rt < RTN; ++rt) {
            const int arow = rt * 16 + lane15;
            const char* abase = Xls + arow * ROWB;
            f16x8 afrag[KSTEPS];
            #pragma unroll
            for (int ks = 0; ks < KSTEPS; ++ks) {
                const int byte = (ks * 64 + kgrp * 16) ^ ((arow & 7) << 4);
                afrag[ks] = ld_frag16(abase + byte);
            }
            f32x4 acc[4];
            #pragma unroll
            for (int q = 0; q < 4; ++q)
                #pragma unroll
                for (int r = 0; r < 4; ++r) acc[q][r] = 0.f;
            #pragma unroll
            for (int ks = 0; ks < KSTEPS; ++ks)
                #pragma unroll
                for (int q = 0; q < 4; ++q)
                    acc[q] = __builtin_amdgcn_mfma_f32_16x16x32_f16(
                        afrag[ks], bfrag[q][ks], acc[q], 0, 0, 0);
            #pragma unroll
            for (int reg = 0; reg < 4; ++reg) {
                const int rl = rt * 16 + kgrp * 4 + reg;
                const int sc = (rl << 6) + (col ^ CSWZ(rl));
                const float ig = fsigmoid(acc[0][reg] + bi);
                const float fg = fsigmoid(acc[1][reg] + bf);
                const float gg = ftanh(acc[2][reg] + bg);
                const float og = fsigmoid(acc[3][reg] + bo);
                const float c2 = fmaf(fg, cls[sc], ig * gg);
                cls[sc] = c2;
                hnx[sc] = (f16)(og * ftanh(c2));
            }
        }
        __syncthreads();

        f16* hOut = hAll + (size_t)s * hstep + (size_t)row0 * H;
        for (int i = t; i < TR * (H / 4); i += 256) {
            const int r = i / (H / 4), j4 = (i % (H / 4)) * 4;
            const uint2 v = *(const uint2*)&hnx[(r << 6) + (j4 ^ CSWZ(r))];
            *(uint2*)&hOut[(size_t)r * H + j4] = v;
            const int byte = r * ROWB + ((H * 2 + j4 * 2) ^ ((r & 7) << 4));
            *(uint2*)(Xls + byte) = v;
        }
    }

    if (writeC) {
        for (int i = t; i < TR * H; i += 256) {
            const int r = i >> 6, j = i & 63;
            cOut[i] = cls[(r << 6) + (j ^ CSWZ(r))];
        }
    }
}

// ---------------- gather + embed fused (K=192: ht | agg_hi | agg_lo) --------
// ht A-fragments read DIRECT from global (L2-hot); LDS panel holds only
// agg hi/lo (16 KB -> 10 blocks/CU). MFMA accumulation order ks 0..5
// unchanged -> values bit-identical.
__global__ __launch_bounds__(256) void gather_embed(
    const float* __restrict__ xn,
    const f16* __restrict__ ht, const f16* __restrict__ hs,
    const int* __restrict__ ptr, const int* __restrict__ rowidx,
    const float* __restrict__ n_enc_w, const float* __restrict__ n_enc_b,
    const f16* __restrict__ Wt_ee2,  // [64][192]
    const float* __restrict__ ee_b,
    f16* __restrict__ xnode)
{
    constexpr int TR = 64, K = 192, KSTEPS = 6, ROWB = 256;  // agg hi/lo only
    __shared__ __align__(16) char Xls[TR * ROWB];   // 16 KB
    const int row0 = blockIdx.x * TR;
    const int t = threadIdx.x;
    const int wv = t >> 6, l = t & 63;
    const int lane15 = l & 15, kgrp = l >> 4;

    const int col = wv * 16 + lane15;
    f16x8 bfrag[KSTEPS];
    {
        const f16* bp = Wt_ee2 + (size_t)col * K + kgrp * 8;
        #pragma unroll
        for (int ks = 0; ks < KSTEPS; ++ks) bfrag[ks] = ld_frag16(bp + ks * 32);
    }

    // CSR gather -> panel bytes 0..127 (hi, k 64..127) / 128..255 (lo, k 128..191)
    {
        const int r = t >> 2, q = t & 3;
        const int n = row0 + r;
        const int beg = ptr[n], end = ptr[n + 1];
        const unsigned int* hs32 = (const unsigned int*)hs;
        float acc[16];
        #pragma unroll
        for (int j = 0; j < 16; ++j) acc[j] = 0.f;
        for (int i = beg; i < end; ++i) {
            const int e = rowidx[i];
            const unsigned int* ep = hs32 + (size_t)e * 32 + q * 8;
            #pragma unroll
            for (int j = 0; j < 8; ++j) {
                union { unsigned int u; f16 h[2]; } v;
                v.u = ep[j];
                acc[2 * j]     += (float)v.h[0];
                acc[2 * j + 1] += (float)v.h[1];
            }
        }
        #pragma unroll
        for (int j = 0; j < 8; ++j) {
            const float a0 = acc[2 * j], a1 = acc[2 * j + 1];
            const f16 h0 = (f16)a0, h1 = (f16)a1;
            const f16 l0 = (f16)(a0 - (float)h0), l1 = (f16)(a1 - (float)h1);
            union { f16 h[2]; unsigned int u; } hi, lo;
            hi.h[0] = h0; hi.h[1] = h1;
            lo.h[0] = l0; lo.h[1] = l1;
            const int bhi = r * ROWB + ((q * 32 + j * 4) ^ ((r & 7) << 4));
            const int blo = r * ROWB + ((128 + q * 32 + j * 4) ^ ((r & 7) << 4));
            *(unsigned int*)(Xls + bhi) = hi.u;
            *(unsigned int*)(Xls + blo) = lo.u;
        }
    }
    __syncthreads();

    const float bb = ee_b[col];
    #pragma unroll
    for (int rt = 0; rt < TR / 16; ++rt) {
        const int arow = rt * 16 + lane15;
        const char* abase = Xls + arow * ROWB;
        f16x8 afrag[KSTEPS];
        // ks 0..1: ht part direct from global (same fragment values as staged)
        afrag[0] = ld_frag16(&ht[(size_t)(row0 + arow) * 64 + kgrp * 8]);
        afrag[1] = ld_frag16(&ht[(size_t)(row0 + arow) * 64 + 32 + kgrp * 8]);
        // ks 2..5: agg hi/lo from panel
        #pragma unroll
        for (int ks = 2; ks < KSTEPS; ++ks) {
            const int byte = (((ks - 2) * 64) + kgrp * 16) ^ ((arow & 7) << 4);
            afrag[ks] = ld_frag16(abase + byte);
        }
        f32x4 acc;
        #pragma unroll
        for (int r = 0; r < 4; ++r) acc[r] = 0.f;
        #pragma unroll
        for (int ks = 0; ks < KSTEPS; ++ks)
            acc = __builtin_amdgcn_mfma_f32_16x16x32_f16(afrag[ks], bfrag[ks], acc, 0, 0, 0);
        #pragma unroll
        for (int reg = 0; reg < 4; ++reg) {
            const int grow = row0 + rt * 16 + kgrp * 4 + reg;
            xnode[(size_t)grow * 128 + 64 + col] = (f16)fmaxf(0.f, acc[reg] + bb);
        }
    }

    // encoder half: cols 0..63
    for (int i = t; i < TR * 32; i += 256) {
        const int r = i >> 5, j2 = (i & 31) * 2;
        const int grow = row0 + r;
        const float x = xn[grow];
        const float e0 = fmaxf(0.f, fmaf(x, n_enc_w[j2],     n_enc_b[j2]));
        const float e1 = fmaxf(0.f, fmaf(x, n_enc_w[j2 + 1], n_enc_b[j2 + 1]));
        *(unsigned int*)&xnode[(size_t)grow * 128 + j2] = pk2(e0, e1);
    }
}

// ---------------- multi-step node LSTM + fused output projection ------------
// c LDS-resident (r15, verified) + NEW x register prefetch.
__global__ __launch_bounds__(512) void node_mega(
    const f16* __restrict__ xnode0,
    const f16* __restrict__ hsAllBase,
    const f16* __restrict__ Wt,
    const float* __restrict__ bias,
    const float* __restrict__ out_w, const float* __restrict__ out_b,
    f16* __restrict__ hIO,
    float* __restrict__ c,
    float* __restrict__ outp,
    const int nsteps)
{
    constexpr int H = 128, K = 256, KSTEPS = 8, ROWB = 512, TR = 128;
    constexpr int RTN = TR / 16;
    __shared__ __align__(16) char Xls[TR * ROWB];   // 64 KB
    __shared__ __align__(16) float clsN[TR * H];    // 64 KB (swizzled)
    __shared__ float out_part[TR][8];               // 4 KB

    const int row0 = blockIdx.x * TR;
    const int t = threadIdx.x;
    const int wv = t >> 6, l = t & 63;
    const int lane15 = l & 15, kgrp = l >> 4;
    const int col = wv * 16 + lane15;

    f16x8 bfrag[4][KSTEPS];
    #pragma unroll
    for (int q = 0; q < 4; ++q) {
        const int colq = q * H + col;
        const f16* bp = Wt + (size_t)colq * K + kgrp * 8;
        #pragma unroll
        for (int ks = 0; ks < KSTEPS; ++ks)
            bfrag[q][ks] = ld_frag16(bp + ks * 32);
    }

    // stage h (K cols 128..255) and c (swizzled) from global once
    for (int i = t; i < TR * (H / 4); i += 512) {
        const int r = i >> 5, j4 = (i & 31) * 4;
        const uint2 v = *(const uint2*)&hIO[(size_t)(row0 + r) * H + j4];
        const int byte = r * ROWB + ((H * 2 + j4 * 2) ^ ((r & 7) << 4));
        *(uint2*)(Xls + byte) = v;
        const float4 cv = *(const float4*)&c[(size_t)(row0 + r) * H + j4];
        *(float4*)&clsN[r * H + (j4 ^ CSWZ(r))] = cv;
    }

    const float bi = bias[0 * H + col];
    const float bf = bias[1 * H + col];
    const float bg = bias[2 * H + col];
    const float bo = bias[3 * H + col];
    const float wout = out_w[col];

    // x prefetch registers (8 x uint2 per thread)
    uint2 xpr[8];
    {
        #pragma unroll
        for (int k2 = 0; k2 < 8; ++k2) {
            const int i = t + k2 * 512;
            const int r = i >> 5, j4 = (i & 31) * 4;
            xpr[k2] = *(const uint2*)&xnode0[(size_t)(row0 + r) * H + j4];
        }
    }

    for (int s = 0; s < nsteps; ++s) {
        // stage x (K cols 0..127) from prefetched regs
        #pragma unroll
        for (int k2 = 0; k2 < 8; ++k2) {
            const int i = t + k2 * 512;
            const int r = i >> 5, j4 = (i & 31) * 4;
            const int byte = r * ROWB + ((j4 * 2) ^ ((r & 7) << 4));
            *(uint2*)(Xls + byte) = xpr[k2];
        }
        // prefetch next step's x (hides under the rt loop)
        if (s + 1 < nsteps) {
            const f16* xin = hsAllBase + (size_t)s * EE * 64;   // slot (s+1)-1
            #pragma unroll
            for (int k2 = 0; k2 < 8; ++k2) {
                const int i = t + k2 * 512;
                const int r = i >> 5, j4 = (i & 31) * 4;
                xpr[k2] = *(const uint2*)&xin[(size_t)(row0 + r) * H + j4];
            }
        }
        __syncthreads();

        const bool lastStep = (s == nsteps - 1);
        #pragma unroll 1
        for (int rt = 0; rt < RTN; ++rt) {
            const int arow = rt * 16 + lane15;
            const char* abase = Xls + arow * ROWB;
            f16x8 afrag[KSTEPS];
            #pragma unroll
            for (int ks = 0; ks < KSTEPS; ++ks) {
                const int byte = (ks * 64 + kgrp * 16) ^ ((arow & 7) << 4);
                afrag[ks] = ld_frag16(abase + byte);
            }
            __syncthreads();
            f32x4 acc[4];
            #pragma unroll
            for (int q = 0; q < 4; ++q)
                #pragma unroll
                for (int r = 0; r < 4; ++r) acc[q][r] = 0.f;
            #pragma unroll
            for (int ks = 0; ks < KSTEPS; ++ks)
                #pragma unroll
                for (int q = 0; q < 4; ++q)
                    acc[q] = __builtin_amdgcn_mfma_f32_16x16x32_f16(
                        afrag[ks], bfrag[q][ks], acc[q], 0, 0, 0);
            #pragma unroll
            for (int reg = 0; reg < 4; ++reg) {
                const int rl = rt * 16 + kgrp * 4 + reg;
                const int grow = row0 + rl;
                const size_t off = (size_t)grow * H + col;
                const int scn = rl * H + (col ^ CSWZ(rl));
                const float ig = fsigmoid(acc[0][reg] + bi);
                const float fg = fsigmoid(acc[1][reg] + bf);
                const float gg = ftanh(acc[2][reg] + bg);
                const float og = fsigmoid(acc[3][reg] + bo);
                const float c2 = fmaf(fg, clsN[scn], ig * gg);
                const float h2 = og * ftanh(c2);
                clsN[scn] = c2;
                const f16 h16 = (f16)h2;
                const int hbyte = rl * ROWB + ((2 * (H + col)) ^ ((rl & 7) << 4));
                *(f16*)(Xls + hbyte) = h16;
                if (lastStep) hIO[off] = h16;
                float pv = h2 * wout;
                pv += __shfl_xor(pv, 1);
                pv += __shfl_xor(pv, 2);
                pv += __shfl_xor(pv, 4);
                pv += __shfl_xor(pv, 8);
                if (lane15 == 0) out_part[rl][wv] = pv;
            }
        }
        __syncthreads();
        if (t < TR) {
            float sum = out_part[t][0];
            #pragma unroll
            for (int w = 1; w < 8; ++w) sum += out_part[t][w];
            outp[(size_t)s * NN + row0 + t] = sum + out_b[0];
        }
    }

    // write c back once per chunk
    for (int i = t; i < TR * (H / 4); i += 512) {
        const int r = i >> 5, j4 = (i & 31) * 4;
        *(float4*)&c[(size_t)(row0 + r) * H + j4] =
            *(const float4*)&clsN[r * H + (j4 ^ CSWZ(r))];
    }
}

// ---------------- CSR build (once; inc is step-invariant) ----------------
__global__ __launch_bounds__(256) void count_kernel(
    const int* __restrict__ inc, int* __restrict__ cnt)
{
    const int slot = blockIdx.x * 256 + threadIdx.x;
    atomicAdd(&cnt[inc[slot]], 1);
}

__global__ __launch_bounds__(1024) void scan_kernel(
    const int* __restrict__ cnt, int* __restrict__ ptr)
{
    __shared__ int sums[1024];
    const int t = threadIdx.x;
    const int base = t * 32;
    int local[32];
    int s = 0;
    #pragma unroll
    for (int i = 0; i < 32; ++i) { local[i] = s; s += cnt[base + i]; }
    sums[t] = s;
    __syncthreads();
    for (int off = 1; off < 1024; off <<= 1) {
        int v = 0;
        if (t >= off) v = sums[t - off];
        __syncthreads();
        sums[t] += v;
        __syncthreads();
    }
    const int excl = sums[t] - s;
    #pragma unroll
    for (int i = 0; i < 32; ++i) ptr[base + i] = excl + local[i];
    if (t == 1023) ptr[NN] = sums[1023];
}

__global__ __launch_bounds__(256) void fill_kernel(
    const int* __restrict__ inc, const int* __restrict__ ptr,
    int* __restrict__ cur, int* __restrict__ rowidx)
{
    const int slot = blockIdx.x * 256 + threadIdx.x;
    const int n = inc[slot];
    const int pos = atomicAdd(&cur[n], 1);
    rowidx[ptr[n] + pos] = slot >> 1;
}

__global__ __launch_bounds__(256) void sort_csr_kernel(
    const int* __restrict__ ptr, int* __restrict__ rowidx)
{
    const int n = blockIdx.x * 256 + threadIdx.x;
    if (n >= NN) return;
    const int beg = ptr[n], end = ptr[n + 1];
    for (int i = beg; i < end - 1; ++i) {
        int mi = i, mv = rowidx[i];
        for (int j = i + 1; j < end; ++j) {
            const int v = rowidx[j];
            if (v < mv) { mv = v; mi = j; }
        }
        if (mi != i) { rowidx[mi] = rowidx[i]; rowidx[i] = mv; }
    }
}

// ---------------- weight transpose+convert (once) ----------------
__global__ __launch_bounds__(256) void transpose_w_kernel(
    const float* __restrict__ Wih, const float* __restrict__ Whh,
    f16* __restrict__ dst, int Hk, int K, int fourH)
{
    const int tid = blockIdx.x * 256 + threadIdx.x;
    if (tid >= K * fourH) return;
    const int col = tid / K, k = tid % K;
    const float v = (k < Hk) ? Wih[(size_t)k * fourH + col]
                             : Whh[(size_t)(k - Hk) * fourH + col];
    dst[tid] = (f16)v;
}

__global__ __launch_bounds__(256) void transpose_ee2_kernel(
    const float* __restrict__ ee_w, f16* __restrict__ dst)
{
    const int tid = blockIdx.x * 256 + threadIdx.x;
    if (tid >= 64 * 192) return;
    const int col = tid / 192, k = tid % 192;
    const int srcrow = (k < 128) ? k : (k - 64);
    dst[tid] = (f16)ee_w[(size_t)srcrow * 64 + col];
}

__global__ __launch_bounds__(256) void cvt_kernel(
    const float* __restrict__ src, f16* __restrict__ dst, int n2)
{
    const int i = blockIdx.x * 256 + threadIdx.x;
    if (i >= n2) return;
    const float2 v = ((const float2*)src)[i];
    ((unsigned int*)dst)[i] = pk2(v.x, v.y);
}

extern "C" void kernel_launch(void* const* d_in, const int* in_sizes, int n_in,
                              void* d_out, int out_size, void* d_ws, size_t ws_size,
                              hipStream_t stream) {
    const float* data_nodes = (const float*)d_in[0];
    const float* data_tE    = (const float*)d_in[1];
    const float* data_sE    = (const float*)d_in[2];
    const float* h_n0 = (const float*)d_in[3];
    const float* c_n0 = (const float*)d_in[4];
    const float* h_t0 = (const float*)d_in[5];
    const float* c_t0 = (const float*)d_in[6];
    const float* h_s0 = (const float*)d_in[7];
    const float* c_s0 = (const float*)d_in[8];
    const int*   inc  = (const int*)d_in[9];
    const float* t_enc_w = (const float*)d_in[10];
    const float* t_enc_b = (const float*)d_in[11];
    const float* t_Wih   = (const float*)d_in[12];
    const float* t_Whh   = (const float*)d_in[13];
    const float* t_b     = (const float*)d_in[14];
    const float* s_enc_w = (const float*)d_in[15];
    const float* s_enc_b = (const float*)d_in[16];
    const float* s_Wih   = (const float*)d_in[17];
    const float* s_Whh   = (const float*)d_in[18];
    const float* s_b     = (const float*)d_in[19];
    const float* n_enc_w = (const float*)d_in[20];
    const float* n_enc_b = (const float*)d_in[21];
    const float* ee_w    = (const float*)d_in[22];
    const float* ee_b    = (const float*)d_in[23];
    const float* n_Wih   = (const float*)d_in[24];
    const float* n_Whh   = (const float*)d_in[25];
    const float* n_b     = (const float*)d_in[26];
    const float* out_w   = (const float*)d_in[27];
    const float* out_b   = (const float*)d_in[28];
    float* out = (float*)d_out;

    // ---- chunk-size selection (same arithmetic as r12-r15 -> same CH) ----
    const size_t slotT = (size_t)NN * 64 * 2;
    const size_t slotS = (size_t)EE * 64 * 2;
    const size_t fixedB =
        (size_t)NN * 128 * 2 +
        (size_t)NN * 128 * 2 +
        (size_t)NN * 128 * 4 +
        (size_t)NN * 64 * 4 +
        (size_t)EE * 64 * 4 +
        ((size_t)256 * 128 + 256 * 128 + 512 * 256 + 64 * 192) * 2 +
        ((size_t)(NN + 8) + 2 * (size_t)EE + NN + NN) * 4 +
        65536;
    int CH = 16;
    while (CH > 1 && fixedB + (size_t)CH * (slotT + slotS) > ws_size) CH >>= 1;

    // ---- workspace layout ----
    char* p = (char*)d_ws;
    f16*  htAll   = (f16*)p;  p += (size_t)CH * slotT;
    f16*  hsAll   = (f16*)p;  p += (size_t)CH * slotS;
    f16*  X0      = (f16*)p;  p += (size_t)NN * 128 * 2;
    f16*  hn16    = (f16*)p;  p += (size_t)NN * 128 * 2;
    float* cn     = (float*)p; p += (size_t)NN * 128 * 4;
    float* ct     = (float*)p; p += (size_t)NN * 64 * 4;
    float* cs     = (float*)p; p += (size_t)EE * 64 * 4;
    f16*  Wt_t    = (f16*)p;  p += (size_t)256 * 128 * 2;
    f16*  Wt_s    = (f16*)p;  p += (size_t)256 * 128 * 2;
    f16*  Wt_n    = (f16*)p;  p += (size_t)512 * 256 * 2;
    f16*  Wt_ee2  = (f16*)p;  p += (size_t)64 * 192 * 2;
    int*  csr_ptr = (int*)p;  p += (size_t)(NN + 8) * 4;
    int*  csr_row = (int*)p;  p += (size_t)2 * EE * 4;
    int*  cnt     = (int*)p;  p += (size_t)NN * 4;
    int*  cur     = (int*)p;  p += (size_t)NN * 4;

    // ---- one-time: state init, weight conversion, CSR ----
    cvt_kernel<<<(NN * 64 / 2 + 255) / 256, 256, 0, stream>>>(
        h_t0, htAll + (size_t)(CH - 1) * NN * 64, NN * 64 / 2);
    cvt_kernel<<<(EE * 64 / 2 + 255) / 256, 256, 0, stream>>>(
        h_s0, hsAll + (size_t)(CH - 1) * EE * 64, EE * 64 / 2);
    cvt_kernel<<<(NN * 128 / 2 + 255) / 256, 256, 0, stream>>>(h_n0, hn16, NN * 128 / 2);
    hipMemcpyAsync(cn, c_n0, (size_t)NN * 128 * 4, hipMemcpyDeviceToDevice, stream);

    transpose_w_kernel<<<(256 * 128 + 255) / 256, 256, 0, stream>>>(t_Wih, t_Whh, Wt_t, 64, 128, 256);
    transpose_w_kernel<<<(256 * 128 + 255) / 256, 256, 0, stream>>>(s_Wih, s_Whh, Wt_s, 64, 128, 256);
    transpose_w_kernel<<<(512 * 256 + 255) / 256, 256, 0, stream>>>(n_Wih, n_Whh, Wt_n, 128, 256, 512);
    transpose_ee2_kernel<<<(64 * 192 + 255) / 256, 256, 0, stream>>>(ee_w, Wt_ee2);

    hipMemsetAsync(cnt, 0, NN * sizeof(int), stream);
    hipMemsetAsync(cur, 0, NN * sizeof(int), stream);
    count_kernel<<<(2 * EE) / 256, 256, 0, stream>>>(inc, cnt);
    scan_kernel<<<1, 1024, 0, stream>>>(cnt, csr_ptr);
    fill_kernel<<<(2 * EE) / 256, 256, 0, stream>>>(inc, csr_ptr, cur, csr_row);
    sort_csr_kernel<<<NN / 256, 256, 0, stream>>>(csr_ptr, csr_row);

    const int edgeGrid = NN / 64 + EE / 64;   // 2560

    for (int c0 = 0; c0 < S_LEN; c0 += CH) {
        edge_mega<<<edgeGrid, 256, 0, stream>>>(
            data_tE + (size_t)c0 * NN * 2, data_sE + (size_t)c0 * EE * 2,
            t_enc_w, t_enc_b, s_enc_w, s_enc_b,
            Wt_t, Wt_s, t_b, s_b,
            htAll, hsAll,
            (c0 == 0) ? c_t0 : ct, (c0 == 0) ? c_s0 : cs, ct, cs,
            CH, (c0 + CH < S_LEN) ? 1 : 0);

        for (int k2 = 0; k2 < CH; ++k2) {
            const int st = c0 + k2;
            f16* xnode_s = (k2 == 0) ? X0 : (hsAll + (size_t)(k2 - 1) * EE * 64);
            gather_embed<<<NN / 64, 256, 0, stream>>>(
                data_nodes + (size_t)st * NN,
                htAll + (size_t)k2 * NN * 64, hsAll + (size_t)k2 * EE * 64,
                csr_ptr, csr_row, n_enc_w, n_enc_b, Wt_ee2, ee_b, xnode_s);
        }

        node_mega<<<NN / 128, 512, 0, stream>>>(
            X0, hsAll, Wt_n, n_b, out_w, out_b, hn16, cn,
            out + (size_t)c0 * NN, CH);
    }
}

// Round 17
// 932.268 us; speedup vs baseline: 1.9357x; 1.1424x over previous
//
#include <hip/hip_runtime.h>
#include <math.h>

// SRNN: S=16 steps, N=32768 nodes, E=131072 spatial edges.
// f16 MFMA gate GEMMs, B-resident weights. Numerics (kept, 13/13 stable):
//  - edge/node per-thread arithmetic = verified forms (absmax 3.90625e-3)
//  - CSR sorted ascending; agg as hi/lo f16 pair (K=192, MFMA order ks 0..5)
// THIS ROUND: batched gather (1 dispatch/chunk, grid CH*512 — fixes the
// grid-limited 2 blocks/CU): emb half written IN-PLACE into htAll[k2]
// (1:1 rows; ht pre-read into regs, drained at barrier). enc computed
// on-the-fly in node_mega (same expr -> same bits). node x-prefetch
// reverted (r16: 249us regression). htCarry preserves temporal h carry.

#define S_LEN 16
#define NN 32768
#define EE 131072

typedef _Float16 f16;
typedef _Float16 f16x8 __attribute__((ext_vector_type(8)));
typedef float f32x4 __attribute__((ext_vector_type(4)));

__device__ __forceinline__ float fsigmoid(float x) {
    return __builtin_amdgcn_rcpf(1.0f + __builtin_amdgcn_exp2f(-1.44269504f * x));
}
__device__ __forceinline__ float ftanh(float x) {
    const float e = __builtin_amdgcn_exp2f(2.88539008f * x);
    return 1.0f - 2.0f * __builtin_amdgcn_rcpf(e + 1.0f);
}

__device__ __forceinline__ unsigned int pk2(float a, float b) {
    union { f16 h[2]; unsigned int u; } x;
    x.h[0] = (f16)a; x.h[1] = (f16)b;
    return x.u;
}

__device__ __forceinline__ f16x8 ld_frag16(const void* p) {
    union { uint4 v; f16x8 f; } x;
    x.v = *(const uint4*)p;
    return x.f;
}

#define CSWZ(rl) (((((rl) >> 2) & 3) ^ ((rl) & 3)) << 4)

// ---------------- multi-step edge LSTM (temporal + spatial), H=64, TR=64 ----
// r15-verified body. h-init: temporal from htCarry (htAll slots get emb-
// overwritten by gather), spatial from hsAll[nsteps-1] (pristine).
// Last step: temporal h also flushed to htCarry.
__global__ __launch_bounds__(256) void edge_mega(
    const float* __restrict__ xT, const float* __restrict__ xS,
    const float* __restrict__ t_enc_w, const float* __restrict__ t_enc_b,
    const float* __restrict__ s_enc_w, const float* __restrict__ s_enc_b,
    const f16* __restrict__ WtT, const f16* __restrict__ WtS,
    const float* __restrict__ biasT, const float* __restrict__ biasS,
    f16* __restrict__ htAll, f16* __restrict__ hsAll,
    f16* __restrict__ htCarry,
    const float* __restrict__ cInT, const float* __restrict__ cInS,
    float* __restrict__ cOutT, float* __restrict__ cOutS,
    const int nsteps, const int writeC)
{
    constexpr int H = 64, K = 128, KSTEPS = 4, ROWB = 256, TR = 64;
    constexpr int RTN = TR / 16;
    __shared__ __align__(16) char Xls[TR * ROWB];
    __shared__ __align__(16) float cls[TR * H];
    __shared__ __align__(16) f16 hnx[TR * H];

    const int bT = NN / TR;
    const bool isT = (int)blockIdx.x < bT;
    const int row0 = (isT ? blockIdx.x : blockIdx.x - bT) * TR;
    const float* xbase = isT ? xT : xS;
    const size_t xstep = (size_t)(isT ? NN : EE) * 2;
    const float* enc_w = isT ? t_enc_w : s_enc_w;
    const float* enc_b = isT ? t_enc_b : s_enc_b;
    const f16*   Wt    = isT ? WtT : WtS;
    const float* bias  = isT ? biasT : biasS;
    f16* hAll = isT ? htAll : hsAll;
    const size_t hstep = (size_t)(isT ? NN : EE) * 64;
    const float* cIn  = (isT ? cInT : cInS) + (size_t)row0 * H;
    float*       cOut = (isT ? cOutT : cOutS) + (size_t)row0 * H;

    const int t = threadIdx.x;
    const int wv = t >> 6, l = t & 63;
    const int lane15 = l & 15, kgrp = l >> 4;
    const int col = wv * 16 + lane15;

    f16x8 bfrag[4][KSTEPS];
    #pragma unroll
    for (int q = 0; q < 4; ++q) {
        const int colq = q * H + col;
        const f16* bp = Wt + (size_t)colq * K + kgrp * 8;
        #pragma unroll
        for (int ks = 0; ks < KSTEPS; ++ks)
            bfrag[q][ks] = ld_frag16(bp + ks * 32);
    }

    for (int i = t; i < TR * H; i += 256) {
        const int r = i >> 6, j = i & 63;
        cls[(r << 6) + (j ^ CSWZ(r))] = cIn[i];
    }
    {
        const f16* hInit = isT ? (htCarry + (size_t)row0 * H)
                               : (hAll + (size_t)(nsteps - 1) * hstep + (size_t)row0 * H);
        for (int i = t; i < TR * (H / 4); i += 256) {
            const int r = i / (H / 4), j4 = (i % (H / 4)) * 4;
            const uint2 v = *(const uint2*)&hInit[(size_t)r * H + j4];
            const int byte = r * ROWB + ((H * 2 + j4 * 2) ^ ((r & 7) << 4));
            *(uint2*)(Xls + byte) = v;
        }
    }

    const float bi = bias[0 * H + col];
    const float bf = bias[1 * H + col];
    const float bg = bias[2 * H + col];
    const float bo = bias[3 * H + col];

    float xr0[8], xr1[8];
    {
        const float* xf = xbase;
        #pragma unroll
        for (int k2 = 0; k2 < 8; ++k2) {
            const int r = (t + k2 * 256) >> 5;
            xr0[k2] = xf[(size_t)(row0 + r) * 2 + 0];
            xr1[k2] = xf[(size_t)(row0 + r) * 2 + 1];
        }
    }

    for (int s = 0; s < nsteps; ++s) {
        #pragma unroll
        for (int k2 = 0; k2 < 8; ++k2) {
            const int i = t + k2 * 256;
            const int r = i >> 5, j2 = (i & 31) * 2;
            const float x0 = xr0[k2];
            const float x1 = xr1[k2];
            const float e0 = fmaxf(0.f, fmaf(x0, enc_w[j2],     fmaf(x1, enc_w[H + j2],     enc_b[j2])));
            const float e1 = fmaxf(0.f, fmaf(x0, enc_w[j2 + 1], fmaf(x1, enc_w[H + j2 + 1], enc_b[j2 + 1])));
            const int byte = r * ROWB + ((j2 * 2) ^ ((r & 7) << 4));
            *(unsigned int*)(Xls + byte) = pk2(e0, e1);
        }
        __syncthreads();

        if (s + 1 < nsteps) {
            const float* xf = xbase + (size_t)(s + 1) * xstep;
            #pragma unroll
            for (int k2 = 0; k2 < 8; ++k2) {
                const int r = (t + k2 * 256) >> 5;
                xr0[k2] = xf[(size_t)(row0 + r) * 2 + 0];
                xr1[k2] = xf[(size_t)(row0 + r) * 2 + 1];
            }
        }

        #pragma unroll
        for (int rt = 0; rt < RTN; ++rt) {
            const int arow = rt * 16 + lane15;
            const char* abase = Xls + arow * ROWB;
            f16x8 afrag[KSTEPS];
            #pragma unroll
            for (int ks = 0; ks < KSTEPS; ++ks) {
                const int byte = (ks * 64 + kgrp * 16) ^ ((arow & 7) << 4);
                afrag[ks] = ld_frag16(abase + byte);
            }
            f32x4 acc[4];
            #pragma unroll
            for (int q = 0; q < 4; ++q)
                #pragma unroll
                for (int r = 0; r < 4; ++r) acc[q][r] = 0.f;
            #pragma unroll
            for (int ks = 0; ks < KSTEPS; ++ks)
                #pragma unroll
                for (int q = 0; q < 4; ++q)
                    acc[q] = __builtin_amdgcn_mfma_f32_16x16x32_f16(
                        afrag[ks], bfrag[q][ks], acc[q], 0, 0, 0);
            #pragma unroll
            for (int reg = 0; reg < 4; ++reg) {
                const int rl = rt * 16 + kgrp * 4 + reg;
                const int sc = (rl << 6) + (col ^ CSWZ(rl));
                const float ig = fsigmoid(acc[0][reg] + bi);
                const float fg = fsigmoid(acc[1][reg] + bf);
                const float gg = ftanh(acc[2][reg] + bg);
                const float og = fsigmoid(acc[3][reg] + bo);
                const float c2 = fmaf(fg, cls[sc], ig * gg);
                cls[sc] = c2;
                hnx[sc] = (f16)(og * ftanh(c2));
            }
        }
        __syncthreads();

        f16* hOut = hAll + (size_t)s * hstep + (size_t)row0 * H;
        const bool carry = isT && (s == nsteps - 1);
        for (int i = t; i < TR * (H / 4); i += 256) {
            const int r = i / (H / 4), j4 = (i % (H / 4)) * 4;
            const uint2 v = *(const uint2*)&hnx[(r << 6) + (j4 ^ CSWZ(r))];
            *(uint2*)&hOut[(size_t)r * H + j4] = v;
            if (carry) *(uint2*)&htCarry[(size_t)(row0 + r) * H + j4] = v;
            const int byte = r * ROWB + ((H * 2 + j4 * 2) ^ ((r & 7) << 4));
            *(uint2*)(Xls + byte) = v;
        }
    }

    if (writeC) {
        for (int i = t; i < TR * H; i += 256) {
            const int r = i >> 6, j = i & 63;
            cOut[i] = cls[(r << 6) + (j ^ CSWZ(r))];
        }
    }
}

// ---------------- batched gather + embed (all chunk steps, one dispatch) ----
// Block (k2, panel): pre-reads its rows' ht fragments into regs (drained at
// the barrier before any write), CSR-gathers agg hi/lo into LDS, then MFMA
// (ks 0..5 order unchanged) and writes the emb half IN-PLACE into htAll[k2]
// (1:1 rows -> race-free across blocks). enc half is NOT materialized
// (node_mega computes it on the fly).
__global__ __launch_bounds__(256) void gather_embed_mega(
    const f16* __restrict__ htAll, const f16* __restrict__ hsAll,
    const int* __restrict__ ptr, const int* __restrict__ rowidx,
    const f16* __restrict__ Wt_ee2,  // [64][192]
    const float* __restrict__ ee_b)
{
    constexpr int TR = 64, K = 192, KSTEPS = 6, ROWB = 256;
    __shared__ __align__(16) char Xls[TR * ROWB];   // 16 KB (agg hi/lo)
    const int k2    = blockIdx.x >> 9;          // step in chunk (NN/64 = 512)
    const int panel = blockIdx.x & 511;
    const int row0 = panel * TR;
    f16* htSlot = (f16*)htAll + (size_t)k2 * NN * 64;   // read ht, write emb
    const f16* hsSlot = hsAll + (size_t)k2 * EE * 64;

    const int t = threadIdx.x;
    const int wv = t >> 6, l = t & 63;
    const int lane15 = l & 15, kgrp = l >> 4;
    const int col = wv * 16 + lane15;

    f16x8 bfrag[KSTEPS];
    {
        const f16* bp = Wt_ee2 + (size_t)col * K + kgrp * 8;
        #pragma unroll
        for (int ks = 0; ks < KSTEPS; ++ks) bfrag[ks] = ld_frag16(bp + ks * 32);
    }

    // pre-read ALL ht A-fragments for this block's rows (before any write;
    // compiler drains vmcnt before the s_barrier below).
    f16x8 af0[4], af1[4];
    #pragma unroll
    for (int rt = 0; rt < 4; ++rt) {
        const int arow = rt * 16 + lane15;
        af0[rt] = ld_frag16(&htSlot[(size_t)(row0 + arow) * 64 + kgrp * 8]);
        af1[rt] = ld_frag16(&htSlot[(size_t)(row0 + arow) * 64 + 32 + kgrp * 8]);
    }

    // CSR gather -> panel bytes 0..127 (hi) / 128..255 (lo)
    {
        const int r = t >> 2, q = t & 3;
        const int n = row0 + r;
        const int beg = ptr[n], end = ptr[n + 1];
        const unsigned int* hs32 = (const unsigned int*)hsSlot;
        float acc[16];
        #pragma unroll
        for (int j = 0; j < 16; ++j) acc[j] = 0.f;
        for (int i = beg; i < end; ++i) {
            const int e = rowidx[i];
            const unsigned int* ep = hs32 + (size_t)e * 32 + q * 8;
            #pragma unroll
            for (int j = 0; j < 8; ++j) {
                union { unsigned int u; f16 h[2]; } v;
                v.u = ep[j];
                acc[2 * j]     += (float)v.h[0];
                acc[2 * j + 1] += (float)v.h[1];
            }
        }
        #pragma unroll
        for (int j = 0; j < 8; ++j) {
            const float a0 = acc[2 * j], a1 = acc[2 * j + 1];
            const f16 h0 = (f16)a0, h1 = (f16)a1;
            const f16 l0 = (f16)(a0 - (float)h0), l1 = (f16)(a1 - (float)h1);
            union { f16 h[2]; unsigned int u; } hi, lo;
            hi.h[0] = h0; hi.h[1] = h1;
            lo.h[0] = l0; lo.h[1] = l1;
            const int bhi = r * ROWB + ((q * 32 + j * 4) ^ ((r & 7) << 4));
            const int blo = r * ROWB + ((128 + q * 32 + j * 4) ^ ((r & 7) << 4));
            *(unsigned int*)(Xls + bhi) = hi.u;
            *(unsigned int*)(Xls + blo) = lo.u;
        }
    }
    __syncthreads();   // drains ht pre-reads; orders panel writes

    const float bb = ee_b[col];
    #pragma unroll
    for (int rt = 0; rt < TR / 16; ++rt) {
        const int arow = rt * 16 + lane15;
        const char* abase = Xls + arow * ROWB;
        f16x8 afrag[KSTEPS];
        afrag[0] = af0[rt];
        afrag[1] = af1[rt];
        #pragma unroll
        for (int ks = 2; ks < KSTEPS; ++ks) {
            const int byte = (((ks - 2) * 64) + kgrp * 16) ^ ((arow & 7) << 4);
            afrag[ks] = ld_frag16(abase + byte);
        }
        f32x4 acc;
        #pragma unroll
        for (int r = 0; r < 4; ++r) acc[r] = 0.f;
        #pragma unroll
        for (int ks = 0; ks < KSTEPS; ++ks)
            acc = __builtin_amdgcn_mfma_f32_16x16x32_f16(afrag[ks], bfrag[ks], acc, 0, 0, 0);
        #pragma unroll
        for (int reg = 0; reg < 4; ++reg) {
            const int grow = row0 + rt * 16 + kgrp * 4 + reg;
            htSlot[(size_t)grow * 64 + col] = (f16)fmaxf(0.f, acc[reg] + bb);
        }
    }
}

// ---------------- multi-step node LSTM + fused output projection ------------
// c LDS-resident (r15); emb read from htAll slots; enc computed on the fly
// from data_nodes (same expression as before -> identical f16 bits).
__global__ __launch_bounds__(512) void node_mega(
    const float* __restrict__ xnBase,        // data_nodes + c0*NN
    const f16* __restrict__ embAll,          // htAll (emb in slots)
    const f16* __restrict__ Wt,
    const float* __restrict__ bias,
    const float* __restrict__ n_enc_w, const float* __restrict__ n_enc_b,
    const float* __restrict__ out_w, const float* __restrict__ out_b,
    f16* __restrict__ hIO,
    float* __restrict__ c,
    float* __restrict__ outp,
    const int nsteps)
{
    constexpr int H = 128, K = 256, KSTEPS = 8, ROWB = 512, TR = 128;
    constexpr int RTN = TR / 16;
    __shared__ __align__(16) char Xls[TR * ROWB];   // 64 KB
    __shared__ __align__(16) float clsN[TR * H];    // 64 KB (swizzled)
    __shared__ float out_part[TR][8];               // 4 KB

    const int row0 = blockIdx.x * TR;
    const int t = threadIdx.x;
    const int wv = t >> 6, l = t & 63;
    const int lane15 = l & 15, kgrp = l >> 4;
    const int col = wv * 16 + lane15;

    f16x8 bfrag[4][KSTEPS];
    #pragma unroll
    for (int q = 0; q < 4; ++q) {
        const int colq = q * H + col;
        const f16* bp = Wt + (size_t)colq * K + kgrp * 8;
        #pragma unroll
        for (int ks = 0; ks < KSTEPS; ++ks)
            bfrag[q][ks] = ld_frag16(bp + ks * 32);
    }

    // stage h (K cols 128..255) and c (swizzled) from global once
    for (int i = t; i < TR * (H / 4); i += 512) {
        const int r = i >> 5, j4 = (i & 31) * 4;
        const uint2 v = *(const uint2*)&hIO[(size_t)(row0 + r) * H + j4];
        const int byte = r * ROWB + ((H * 2 + j4 * 2) ^ ((r & 7) << 4));
        *(uint2*)(Xls + byte) = v;
        const float4 cv = *(const float4*)&c[(size_t)(row0 + r) * H + j4];
        *(float4*)&clsN[r * H + (j4 ^ CSWZ(r))] = cv;
    }

    const float bi = bias[0 * H + col];
    const float bf = bias[1 * H + col];
    const float bg = bias[2 * H + col];
    const float bo = bias[3 * H + col];
    const float wout = out_w[col];

    for (int s = 0; s < nsteps; ++s) {
        // enc half (K cols 0..63): compute from xn on the fly
        const float* xn = xnBase + (size_t)s * NN;
        for (int i = t; i < TR * 32; i += 512) {
            const int r = i >> 5, j2 = (i & 31) * 2;
            const float x = xn[row0 + r];
            const float e0 = fmaxf(0.f, fmaf(x, n_enc_w[j2],     n_enc_b[j2]));
            const float e1 = fmaxf(0.f, fmaf(x, n_enc_w[j2 + 1], n_enc_b[j2 + 1]));
            const int byte = r * ROWB + ((j2 * 2) ^ ((r & 7) << 4));
            *(unsigned int*)(Xls + byte) = pk2(e0, e1);
        }
        // emb half (K cols 64..127): from htAll slot s
        const f16* emb = embAll + (size_t)s * NN * 64;
        for (int i = t; i < TR * 16; i += 512) {
            const int r = i >> 4, j4 = (i & 15) * 4;
            const uint2 v = *(const uint2*)&emb[(size_t)(row0 + r) * 64 + j4];
            const int byte = r * ROWB + ((2 * (64 + j4)) ^ ((r & 7) << 4));
            *(uint2*)(Xls + byte) = v;
        }
        __syncthreads();

        const bool lastStep = (s == nsteps - 1);
        #pragma unroll 1
        for (int rt = 0; rt < RTN; ++rt) {
            const int arow = rt * 16 + lane15;
            const char* abase = Xls + arow * ROWB;
            f16x8 afrag[KSTEPS];
            #pragma unroll
            for (int ks = 0; ks < KSTEPS; ++ks) {
                const int byte = (ks * 64 + kgrp * 16) ^ ((arow & 7) << 4);
                afrag[ks] = ld_frag16(abase + byte);
            }
            __syncthreads();
            f32x4 acc[4];
            #pragma unroll
            for (int q = 0; q < 4; ++q)
                #pragma unroll
                for (int r = 0; r < 4; ++r) acc[q][r] = 0.f;
            #pragma unroll
            for (int ks = 0; ks < KSTEPS; ++ks)
                #pragma unroll
                for (int q = 0; q < 4; ++q)
                    acc[q] = __builtin_amdgcn_mfma_f32_16x16x32_f16(
                        afrag[ks], bfrag[q][ks], acc[q], 0, 0, 0);
            #pragma unroll
            for (int reg = 0; reg < 4; ++reg) {
                const int rl = rt * 16 + kgrp * 4 + reg;
                const int grow = row0 + rl;
                const size_t off = (size_t)grow * H + col;
                const int scn = rl * H + (col ^ CSWZ(rl));
                const float ig = fsigmoid(acc[0][reg] + bi);
                const float fg = fsigmoid(acc[1][reg] + bf);
                const float gg = ftanh(acc[2][reg] + bg);
                const float og = fsigmoid(acc[3][reg] + bo);
                const float c2 = fmaf(fg, clsN[scn], ig * gg);
                const float h2 = og * ftanh(c2);
                clsN[scn] = c2;
                const f16 h16 = (f16)h2;
                const int hbyte = rl * ROWB + ((2 * (H + col)) ^ ((rl & 7) << 4));
                *(f16*)(Xls + hbyte) = h16;
                if (lastStep) hIO[off] = h16;
                float pv = h2 * wout;
                pv += __shfl_xor(pv, 1);
                pv += __shfl_xor(pv, 2);
                pv += __shfl_xor(pv, 4);
                pv += __shfl_xor(pv, 8);
                if (lane15 == 0) out_part[rl][wv] = pv;
            }
        }
        __syncthreads();
        if (t < TR) {
            float sum = out_part[t][0];
            #pragma unroll
            for (int w = 1; w < 8; ++w) sum += out_part[t][w];
            outp[(size_t)s * NN + row0 + t] = sum + out_b[0];
        }
    }

    for (int i = t; i < TR * (H / 4); i += 512) {
        const int r = i >> 5, j4 = (i & 31) * 4;
        *(float4*)&c[(size_t)(row0 + r) * H + j4] =
            *(const float4*)&clsN[r * H + (j4 ^ CSWZ(r))];
    }
}

// ---------------- CSR build (once; inc is step-invariant) ----------------
__global__ __launch_bounds__(256) void count_kernel(
    const int* __restrict__ inc, int* __restrict__ cnt)
{
    const int slot = blockIdx.x * 256 + threadIdx.x;
    atomicAdd(&cnt[inc[slot]], 1);
}

__global__ __launch_bounds__(1024) void scan_kernel(
    const int* __restrict__ cnt, int* __restrict__ ptr)
{
    __shared__ int sums[1024];
    const int t = threadIdx.x;
    const int base = t * 32;
    int local[32];
    int s = 0;
    #pragma unroll
    for (int i = 0; i < 32; ++i) { local[i] = s; s += cnt[base + i]; }
    sums[t] = s;
    __syncthreads();
    for (int off = 1; off < 1024; off <<= 1) {
        int v = 0;
        if (t >= off) v = sums[t - off];
        __syncthreads();
        sums[t] += v;
        __syncthreads();
    }
    const int excl = sums[t] - s;
    #pragma unroll
    for (int i = 0; i < 32; ++i) ptr[base + i] = excl + local[i];
    if (t == 1023) ptr[NN] = sums[1023];
}

__global__ __launch_bounds__(256) void fill_kernel(
    const int* __restrict__ inc, const int* __restrict__ ptr,
    int* __restrict__ cur, int* __restrict__ rowidx)
{
    const int slot = blockIdx.x * 256 + threadIdx.x;
    const int n = inc[slot];
    const int pos = atomicAdd(&cur[n], 1);
    rowidx[ptr[n] + pos] = slot >> 1;
}

__global__ __launch_bounds__(256) void sort_csr_kernel(
    const int* __restrict__ ptr, int* __restrict__ rowidx)
{
    const int n = blockIdx.x * 256 + threadIdx.x;
    if (n >= NN) return;
    const int beg = ptr[n], end = ptr[n + 1];
    for (int i = beg; i < end - 1; ++i) {
        int mi = i, mv = rowidx[i];
        for (int j = i + 1; j < end; ++j) {
            const int v = rowidx[j];
            if (v < mv) { mv = v; mi = j; }
        }
        if (mi != i) { rowidx[mi] = rowidx[i]; rowidx[i] = mv; }
    }
}

// ---------------- weight transpose+convert (once) ----------------
__global__ __launch_bounds__(256) void transpose_w_kernel(
    const float* __restrict__ Wih, const float* __restrict__ Whh,
    f16* __restrict__ dst, int Hk, int K, int fourH)
{
    const int tid = blockIdx.x * 256 + threadIdx.x;
    if (tid >= K * fourH) return;
    const int col = tid / K, k = tid % K;
    const float v = (k < Hk) ? Wih[(size_t)k * fourH + col]
                             : Whh[(size_t)(k - Hk) * fourH + col];
    dst[tid] = (f16)v;
}

__global__ __launch_bounds__(256) void transpose_ee2_kernel(
    const float* __restrict__ ee_w, f16* __restrict__ dst)
{
    const int tid = blockIdx.x * 256 + threadIdx.x;
    if (tid >= 64 * 192) return;
    const int col = tid / 192, k = tid % 192;
    const int srcrow = (k < 128) ? k : (k - 64);
    dst[tid] = (f16)ee_w[(size_t)srcrow * 64 + col];
}

__global__ __launch_bounds__(256) void cvt_kernel(
    const float* __restrict__ src, f16* __restrict__ dst, int n2)
{
    const int i = blockIdx.x * 256 + threadIdx.x;
    if (i >= n2) return;
    const float2 v = ((const float2*)src)[i];
    ((unsigned int*)dst)[i] = pk2(v.x, v.y);
}

extern "C" void kernel_launch(void* const* d_in, const int* in_sizes, int n_in,
                              void* d_out, int out_size, void* d_ws, size_t ws_size,
                              hipStream_t stream) {
    const float* data_nodes = (const float*)d_in[0];
    const float* data_tE    = (const float*)d_in[1];
    const float* data_sE    = (const float*)d_in[2];
    const float* h_n0 = (const float*)d_in[3];
    const float* c_n0 = (const float*)d_in[4];
    const float* h_t0 = (const float*)d_in[5];
    const float* c_t0 = (const float*)d_in[6];
    const float* h_s0 = (const float*)d_in[7];
    const float* c_s0 = (const float*)d_in[8];
    const int*   inc  = (const int*)d_in[9];
    const float* t_enc_w = (const float*)d_in[10];
    const float* t_enc_b = (const float*)d_in[11];
    const float* t_Wih   = (const float*)d_in[12];
    const float* t_Whh   = (const float*)d_in[13];
    const float* t_b     = (const float*)d_in[14];
    const float* s_enc_w = (const float*)d_in[15];
    const float* s_enc_b = (const float*)d_in[16];
    const float* s_Wih   = (const float*)d_in[17];
    const float* s_Whh   = (const float*)d_in[18];
    const float* s_b     = (const float*)d_in[19];
    const float* n_enc_w = (const float*)d_in[20];
    const float* n_enc_b = (const float*)d_in[21];
    const float* ee_w    = (const float*)d_in[22];
    const float* ee_b    = (const float*)d_in[23];
    const float* n_Wih   = (const float*)d_in[24];
    const float* n_Whh   = (const float*)d_in[25];
    const float* n_b     = (const float*)d_in[26];
    const float* out_w   = (const float*)d_in[27];
    const float* out_b   = (const float*)d_in[28];
    float* out = (float*)d_out;

    // ---- chunk-size selection ----
    const size_t slotT = (size_t)NN * 64 * 2;
    const size_t slotS = (size_t)EE * 64 * 2;
    const size_t fixedB =
        (size_t)NN * 64 * 2 +           // htCarry
        (size_t)NN * 128 * 2 +          // hn16
        (size_t)NN * 128 * 4 +          // cn
        (size_t)NN * 64 * 4 +           // ct
        (size_t)EE * 64 * 4 +           // cs
        ((size_t)256 * 128 + 256 * 128 + 512 * 256 + 64 * 192) * 2 +
        ((size_t)(NN + 8) + 2 * (size_t)EE + NN + NN) * 4 +
        65536;
    int CH = 16;
    while (CH > 1 && fixedB + (size_t)CH * (slotT + slotS) > ws_size) CH >>= 1;

    // ---- workspace layout ----
    char* p = (char*)d_ws;
    f16*  htAll   = (f16*)p;  p += (size_t)CH * slotT;
    f16*  hsAll   = (f16*)p;  p += (size_t)CH * slotS;
    f16*  htCarry = (f16*)p;  p += (size_t)NN * 64 * 2;
    f16*  hn16    = (f16*)p;  p += (size_t)NN * 128 * 2;
    float* cn     = (float*)p; p += (size_t)NN * 128 * 4;
    float* ct     = (float*)p; p += (size_t)NN * 64 * 4;
    float* cs     = (float*)p; p += (size_t)EE * 64 * 4;
    f16*  Wt_t    = (f16*)p;  p += (size_t)256 * 128 * 2;
    f16*  Wt_s    = (f16*)p;  p += (size_t)256 * 128 * 2;
    f16*  Wt_n    = (f16*)p;  p += (size_t)512 * 256 * 2;
    f16*  Wt_ee2  = (f16*)p;  p += (size_t)64 * 192 * 2;
    int*  csr_ptr = (int*)p;  p += (size_t)(NN + 8) * 4;
    int*  csr_row = (int*)p;  p += (size_t)2 * EE * 4;
    int*  cnt     = (int*)p;  p += (size_t)NN * 4;
    int*  cur     = (int*)p;  p += (size_t)NN * 4;

    // ---- one-time: state init, weight conversion, CSR ----
    cvt_kernel<<<(NN * 64 / 2 + 255) / 256, 256, 0, stream>>>(h_t0, htCarry, NN * 64 / 2);
    cvt_kernel<<<(EE * 64 / 2 + 255) / 256, 256, 0, stream>>>(
        h_s0, hsAll + (size_t)(CH - 1) * EE * 64, EE * 64 / 2);
    cvt_kernel<<<(NN * 128 / 2 + 255) / 256, 256, 0, stream>>>(h_n0, hn16, NN * 128 / 2);
    hipMemcpyAsync(cn, c_n0, (size_t)NN * 128 * 4, hipMemcpyDeviceToDevice, stream);

    transpose_w_kernel<<<(256 * 128 + 255) / 256, 256, 0, stream>>>(t_Wih, t_Whh, Wt_t, 64, 128, 256);
    transpose_w_kernel<<<(256 * 128 + 255) / 256, 256, 0, stream>>>(s_Wih, s_Whh, Wt_s, 64, 128, 256);
    transpose_w_kernel<<<(512 * 256 + 255) / 256, 256, 0, stream>>>(n_Wih, n_Whh, Wt_n, 128, 256, 512);
    transpose_ee2_kernel<<<(64 * 192 + 255) / 256, 256, 0, stream>>>(ee_w, Wt_ee2);

    hipMemsetAsync(cnt, 0, NN * sizeof(int), stream);
    hipMemsetAsync(cur, 0, NN * sizeof(int), stream);
    count_kernel<<<(2 * EE) / 256, 256, 0, stream>>>(inc, cnt);
    scan_kernel<<<1, 1024, 0, stream>>>(cnt, csr_ptr);
    fill_kernel<<<(2 * EE) / 256, 256, 0, stream>>>(inc, csr_ptr, cur, csr_row);
    sort_csr_kernel<<<NN / 256, 256, 0, stream>>>(csr_ptr, csr_row);

    const int edgeGrid = NN / 64 + EE / 64;   // 2560

    for (int c0 = 0; c0 < S_LEN; c0 += CH) {
        edge_mega<<<edgeGrid, 256, 0, stream>>>(
            data_tE + (size_t)c0 * NN * 2, data_sE + (size_t)c0 * EE * 2,
            t_enc_w, t_enc_b, s_enc_w, s_enc_b,
            Wt_t, Wt_s, t_b, s_b,
            htAll, hsAll, htCarry,
            (c0 == 0) ? c_t0 : ct, (c0 == 0) ? c_s0 : cs, ct, cs,
            CH, (c0 + CH < S_LEN) ? 1 : 0);

        gather_embed_mega<<<CH * (NN / 64), 256, 0, stream>>>(
            htAll, hsAll, csr_ptr, csr_row, Wt_ee2, ee_b);

        node_mega<<<NN / 128, 512, 0, stream>>>(
            data_nodes + (size_t)c0 * NN, htAll, Wt_n, n_b,
            n_enc_w, n_enc_b, out_w, out_b, hn16, cn,
            out + (size_t)c0 * NN, CH);
    }
}